// Round 5
// baseline (563.644 us; speedup 1.0000x reference)
//
#include <hip/hip_runtime.h>

typedef unsigned short u16;
typedef __attribute__((ext_vector_type(8))) short bh8;   // 8 x bf16 (4 VGPRs)
typedef __attribute__((ext_vector_type(4))) float f4;    // MFMA accumulator

#define DI __device__ __forceinline__

DI u16 f2bf(float f){ unsigned u=__float_as_uint(f); u += 0x7fffu + ((u>>16)&1u); return (u16)(u>>16); }
DI float bf2f(u16 u){ return __uint_as_float(((unsigned)u)<<16); }
DI float silu_f(float x){ return x/(1.f+__expf(-x)); }

DI void gld16(const u16* g, u16* l){
  __builtin_amdgcn_global_load_lds((const __attribute__((address_space(1))) void*)g,
                                   (__attribute__((address_space(3))) void*)l, 16, 0, 0);
}

// uniform cubic B-spline bases on grid [-2.2 : 0.4 : 2.2], 8 output bases (branchless,
// used only in the A1 materialization kernel where cost is minor).
DI void bspline8(float x, float* v){
  float u = x*2.5f + 5.5f;           // (x + 2.2)/0.4
  #pragma unroll
  for (int j=0;j<8;j++){
    float a  = fabsf(u - (float)(j+2));
    float t1 = fmaxf(2.f-a, 0.f);
    float t2 = fmaxf(1.f-a, 0.f);
    v[j] = t1*t1*t1*(1.f/6.f) - t2*t2*t2*(2.f/3.f);
  }
}

// ---------------- GEMM (64x128 tile, 2 waves): C = A(MxK) * Bt(NxK)^T ----------------
// 2 waves; wave w owns all 64 rows x cols w*64..w*64+63 with a 4x4 f4 accumulator
// (m97 MFMA:ds_read ratio). BK=64. LDS: one 128B-aligned block: sB(128x64) | sA(64x64)
// | dump. 16B chunks XOR-swizzled: chunk c of row r stored at (c ^ (r&7)).
// KAN_H>0: A generated from h (M x KAN_H bf16): cols [0,KAN_H)=silu(h), rest=spline
// (zero-fill + 4-nonzero-weight scatter).
// OUT_BF16: bf16 output staged via LDS -> 256B-contiguous stores (full cachelines).
// Else f32 direct (+bias/R1); split!=0 -> C += z*M*N.
template<int KAN_H, bool OUT_BF16>
__global__ __launch_bounds__(128, 3)
void gemm2w(const void* __restrict__ Asrc, const u16* __restrict__ Bt,
            void* __restrict__ Cout, int M, int N, int K, int ktiles_per_z,
            int split, const float* __restrict__ bias, const float* __restrict__ R1)
{
  __shared__ __align__(128) u16 smem[12304];  // sB[0..8192) sA[8192..12288) dump[12288..)
  u16* const sB = smem;
  u16* const sA = smem + 8192;
  const int m0 = blockIdx.y * 64;
  const int n0 = blockIdx.x * 128;
  const int ktiles = K >> 6;
  int kt0 = blockIdx.z * ktiles_per_z;
  int kt1 = kt0 + ktiles_per_z; if (kt1 > ktiles) kt1 = ktiles;
  const int t = threadIdx.x;
  const int wave = t >> 6, lane = t & 63;
  const int lr = lane & 15, lq = lane >> 4;
  const int lr8 = lane >> 3, lc8 = lane & 7;
  const int swz8 = lc8 ^ lr8;      // swizzled global chunk for this lane (row&7 == lr8)
  f4 acc[4][4];
  f4 z4 = {0.f,0.f,0.f,0.f};
  #pragma unroll
  for (int i=0;i<4;i++)
    #pragma unroll
    for (int j=0;j<4;j++) acc[i][j]=z4;

  for (int kt = kt0; kt < kt1; ++kt) {
    int k0 = kt << 6;
    // stage Bt tile (128 rows): 8 gld16 per wave, swizzled
    {
      const u16* Bp = Bt + (size_t)n0 * K + k0;
      #pragma unroll
      for (int it=0; it<8; ++it) {
        int r = it*16 + wave*8;
        gld16(Bp + (size_t)(r + lr8) * K + swz8*8, &sB[r*64]);
      }
    }
    // stage A tile (64 rows)
    if (KAN_H == 0) {
      const u16* Ap = (const u16*)Asrc + (size_t)m0 * K + k0;
      #pragma unroll
      for (int it=0; it<4; ++it) {
        int r = it*16 + wave*8;
        gld16(Ap + (size_t)(r + lr8) * K + swz8*8, &sA[r*64]);
      }
    } else {
      const u16* hsrc = (const u16*)Asrc;
      if (k0 < KAN_H) {
        // silu region: 64 rows x 64 cols = 512 chunks of 8
        #pragma unroll
        for (int it=0; it<4; ++it) {
          int chunk = t + it*128;
          int r = chunk >> 3, ck = chunk & 7;
          const u16* src = hsrc + (size_t)(m0+r)*KAN_H + k0 + ck*8;
          ushort4 a = *(const ushort4*)src;
          ushort4 b2 = *(const ushort4*)(src+4);
          alignas(16) u16 o[8];
          o[0]=f2bf(silu_f(bf2f(a.x))); o[1]=f2bf(silu_f(bf2f(a.y)));
          o[2]=f2bf(silu_f(bf2f(a.z))); o[3]=f2bf(silu_f(bf2f(a.w)));
          o[4]=f2bf(silu_f(bf2f(b2.x))); o[5]=f2bf(silu_f(bf2f(b2.y)));
          o[6]=f2bf(silu_f(bf2f(b2.z))); o[7]=f2bf(silu_f(bf2f(b2.w)));
          *(float4*)(&sA[r*64 + (ck ^ (r&7))*8]) = *(const float4*)o;
        }
      } else {
        // spline region: (row, feature) -> 8 bases, only 4 nonzero
        int i0 = (k0 - KAN_H) >> 3;
        const float4 zf4 = make_float4(0.f,0.f,0.f,0.f);
        #pragma unroll
        for (int it=0; it<4; ++it) {
          int pair = t + it*128;
          int r = pair >> 3, ii = pair & 7;
          int base = r*64 + (ii ^ (r&7))*8;
          *(float4*)(&sA[base]) = zf4;             // zero-fill the 8 bases
          float x = bf2f(hsrc[(size_t)(m0+r)*KAN_H + i0 + ii]);
          float u = x*2.5f + 5.5f;
          bool valid = (u >= 0.f) & (u < 11.f);
          float uc = fminf(fmaxf(u, 0.f), 10.999f);
          int m = (int)uc;
          float tt = uc - (float)m;
          float omt = 1.f - tt, t2 = tt*tt, t3 = t2*tt;
          float w0 = omt*omt*omt*(1.f/6.f);
          float w3 = t3*(1.f/6.f);
          float w1 = 0.5f*t3 - t2 + (2.f/3.f);
          float w2 = 1.f - w0 - w1 - w3;
          float ws[4] = {w0, w1, w2, w3};
          int c0 = m - 3;
          #pragma unroll
          for (int j=0;j<4;j++){
            int c = c0 + j;
            bool ok = valid & ((unsigned)c < 8u);
            int off = ok ? (base + c) : 4096;     // dump slot (sA[4096] = smem[12288])
            sA[off] = f2bf(ws[j]);
          }
        }
      }
    }
    __syncthreads();
    #pragma unroll
    for (int kk=0; kk<64; kk+=32) {
      const int c0k = kk >> 3;
      bh8 af[4], bfr[4];
      #pragma unroll
      for (int i=0;i<4;i++) {
        int row = i*16 + lr;
        af[i] = *(const bh8*)(&sA[row*64 + ((c0k+lq) ^ (row&7))*8]);
      }
      #pragma unroll
      for (int j=0;j<4;j++) {
        int row = wave*64 + j*16 + lr;
        bfr[j] = *(const bh8*)(&sB[row*64 + ((c0k+lq) ^ (row&7))*8]);
      }
      #pragma unroll
      for (int i=0;i<4;i++)
        #pragma unroll
        for (int j=0;j<4;j++)
          acc[i][j] = __builtin_amdgcn_mfma_f32_16x16x32_bf16(af[i], bfr[j], acc[i][j], 0, 0, 0);
    }
    __syncthreads();
  }
  // epilogue: C/D layout col=lane&15, row=(lane>>4)*4+reg
  if (OUT_BF16) {
    // stage bf16 tile (64 x 128, stride 136) in LDS, then 256B-contiguous stores
    u16* Cb = (u16*)Cout;
    #pragma unroll
    for (int i=0;i<4;i++) {
      #pragma unroll
      for (int j=0;j<4;j++) {
        int col = wave*64 + j*16 + lr;
        float bv = bias ? bias[n0 + col] : 0.f;
        #pragma unroll
        for (int r4=0;r4<4;r4++) {
          int row = i*16 + lq*4 + r4;
          smem[row*136 + col] = f2bf(acc[i][j][r4] + bv);
        }
      }
    }
    __syncthreads();
    #pragma unroll
    for (int it=0; it<8; ++it) {
      int idx = t + it*128;
      int row = idx >> 4, seg = idx & 15;
      *(float4*)(Cb + (size_t)(m0+row)*N + n0 + seg*8) =
          *(const float4*)&smem[row*136 + seg*8];
    }
  } else {
    float* Cf = (float*)Cout;
    if (split) Cf += (size_t)blockIdx.z * M * N;
    #pragma unroll
    for (int i=0;i<4;i++) {
      int row = m0 + i*16 + lq*4;
      #pragma unroll
      for (int j=0;j<4;j++) {
        int col = n0 + wave*64 + j*16 + lr;
        float bv = bias ? bias[col] : 0.f;
        #pragma unroll
        for (int r4=0;r4<4;r4++) {
          size_t idx = (size_t)(row + r4) * N + col;
          float v = acc[i][j][r4] + bv;
          if (R1) v += R1[idx];
          Cf[idx] = v;
        }
      }
    }
  }
}

// ---------------- transpose + LN1: x5d (B,C,N) -> x_t (B,N,C) f32 and ln1_t bf16 ----------------
__global__ __launch_bounds__(256) void k_ln1_trans(const float* __restrict__ x5d,
    float* __restrict__ x_t, u16* __restrict__ ln1_t,
    const float* __restrict__ g, const float* __restrict__ bv)
{
  __shared__ float tile[128*65];
  __shared__ float red_s[256], red_q[256];
  __shared__ float st_mu[64], st_rs[64];
  int b = blockIdx.y, n0 = blockIdx.x * 64;
  int j = threadIdx.x & 63, part = threadIdx.x >> 6;
  for (int cc=0; cc<32; ++cc) {
    int c = part*32 + cc;
    tile[c*65 + j] = x5d[((size_t)b*128 + c)*9216 + n0 + j];
  }
  __syncthreads();
  float s=0.f, s2=0.f;
  for (int cc=0; cc<32; ++cc) {
    float v = tile[(part*32+cc)*65 + j];
    s += v; s2 += v*v;
  }
  red_s[threadIdx.x]=s; red_q[threadIdx.x]=s2;
  __syncthreads();
  if (threadIdx.x < 64) {
    int jj = threadIdx.x;
    float ts = red_s[jj]+red_s[jj+64]+red_s[jj+128]+red_s[jj+192];
    float tq = red_q[jj]+red_q[jj+64]+red_q[jj+128]+red_q[jj+192];
    float mu = ts*(1.f/128.f);
    st_mu[jj]=mu;
    st_rs[jj]=rsqrtf(tq*(1.f/128.f) - mu*mu + 1e-5f);
  }
  __syncthreads();
  for (int it=0; it<32; ++it) {
    int idx = threadIdx.x + it*256;
    int tok = idx >> 7, c = idx & 127;
    float v = tile[c*65 + tok];
    size_t a = ((size_t)b*9216 + n0 + tok)*128 + c;
    x_t[a] = v;
    ln1_t[a] = f2bf((v - st_mu[tok])*st_rs[tok]*g[c] + bv[c]);
  }
}

// ---------------- double LN + KAN expansion: writes A1 (T x 1152 bf16) ----------------
__global__ void k_ln_double_expand(const float* __restrict__ in, u16* __restrict__ A1,
    const float* __restrict__ g1, const float* __restrict__ b1,
    const float* __restrict__ g2, const float* __restrict__ b2)
{
  int tok = blockIdx.x*4 + (threadIdx.x>>6);
  int lane = threadIdx.x & 63;
  const float* row = in + (size_t)tok*128;
  float v0=row[lane], v1=row[lane+64];
  float s=v0+v1, s2=v0*v0+v1*v1;
  #pragma unroll
  for (int o=1;o<64;o<<=1){ s += __shfl_xor(s,o); s2 += __shfl_xor(s2,o); }
  float mu=s*(1.f/128.f);
  float rs=rsqrtf(s2*(1.f/128.f)-mu*mu+1e-5f);
  float y0=(v0-mu)*rs*g1[lane]+b1[lane];
  float y1=(v1-mu)*rs*g1[lane+64]+b1[lane+64];
  s=y0+y1; s2=y0*y0+y1*y1;
  #pragma unroll
  for (int o=1;o<64;o<<=1){ s += __shfl_xor(s,o); s2 += __shfl_xor(s2,o); }
  mu=s*(1.f/128.f);
  rs=rsqrtf(s2*(1.f/128.f)-mu*mu+1e-5f);
  y0=(y0-mu)*rs*g2[lane]+b2[lane];
  y1=(y1-mu)*rs*g2[lane+64]+b2[lane+64];
  u16* arow = A1 + (size_t)tok*1152;
  arow[lane]    = f2bf(silu_f(y0));
  arow[lane+64] = f2bf(silu_f(y1));
  float w[8]; alignas(16) u16 o8[8];
  bspline8(y0, w);
  #pragma unroll
  for (int j=0;j<8;j++) o8[j]=f2bf(w[j]);
  *(float4*)(&arow[128 + lane*8]) = *(const float4*)o8;
  bspline8(y1, w);
  #pragma unroll
  for (int j=0;j<8;j++) o8[j]=f2bf(w[j]);
  *(float4*)(&arow[128 + (lane+64)*8]) = *(const float4*)o8;
}

// ---------------- depthwise 3x3 conv, token-major, bf16 in -> bf16 out, + bias ----------------
__global__ __launch_bounds__(256) void k_dwconv(const u16* __restrict__ qkv_t,
    u16* __restrict__ qkvd, const float* __restrict__ dw_w, const float* __restrict__ dw_b)
{
  __shared__ float lt[100*68];
  int tile = blockIdx.x; int th=(tile/12)*8, tw=(tile%12)*8;
  int cg = blockIdx.y, b = blockIdx.z;
  int t = threadIdx.x;
  for (int pp=0; pp<7; ++pp) {
    int pos = pp*16 + (t>>4);
    if (pos < 100) {
      int ih = th + pos/10 - 1, iw = tw + pos%10 - 1;
      int c4 = (t & 15)*4;
      float4 v = make_float4(0.f,0.f,0.f,0.f);
      if (ih>=0 && ih<96 && iw>=0 && iw<96) {
        ushort4 raw = *(const ushort4*)&qkv_t[(((size_t)b*9216) + ih*96 + iw)*384 + cg*64 + c4];
        v = make_float4(bf2f(raw.x), bf2f(raw.y), bf2f(raw.z), bf2f(raw.w));
      }
      *(float4*)&lt[pos*68 + c4] = v;
    }
  }
  __syncthreads();
  int ch = t & 63, gch = cg*64 + ch;
  float w[9];
  #pragma unroll
  for (int k=0;k<9;k++) w[k]=dw_w[gch*9+k];
  float bias = dw_b[gch];
  for (int pp=0; pp<16; ++pp) {
    int pos = (t>>6) + pp*4;
    int oh = pos>>3, ow = pos&7;
    float acc = bias;
    #pragma unroll
    for (int di=0; di<3; ++di)
      #pragma unroll
      for (int dj=0; dj<3; ++dj)
        acc += lt[((oh+di)*10 + ow+dj)*68 + ch] * w[di*3+dj];
    qkvd[(((size_t)b*9216) + (th+oh)*96 + tw+ow)*384 + gch] = f2bf(acc);
  }
}

// ---------------- sum of squares over n for q,k channels (c = 0..255) ----------------
__global__ void k_normsum(const u16* __restrict__ qkvd, float* __restrict__ ss)
{
  int b = blockIdx.y, n0 = blockIdx.x*128;
  int c = threadIdx.x;
  float acc=0.f;
  for (int i=0;i<128;++i){
    float v = bf2f(qkvd[((size_t)b*9216 + n0+i)*384 + c]);
    acc += v*v;
  }
  atomicAdd(&ss[b*256 + c], acc);
}

// ---------------- partial q@k^T with normalization, atomic into S ----------------
__global__ __launch_bounds__(256) void k_qk(const u16* __restrict__ qkvd,
    const float* __restrict__ ss, float* __restrict__ S)
{
  __shared__ float ql[128][32];
  __shared__ float kl[128][32];
  int nc=blockIdx.x, h=blockIdx.y, b=blockIdx.z;
  int t = threadIdx.x;
  int r = t>>1, half = t&1;
  size_t rowa = ((size_t)b*9216 + nc*128 + r)*384 + (half?128:0) + h*32;
  #pragma unroll
  for (int cc=0; cc<32; ++cc) {
    float v = bf2f(qkvd[rowa + cc]);
    if (half) kl[r][cc]=v; else ql[r][cc]=v;
  }
  __syncthreads();
  int i0 = (t>>4)*2, j0 = (t&15)*2;
  float a00=0.f,a01=0.f,a10=0.f,a11=0.f;
  for (int n=0;n<128;++n){
    float2 qv = *(const float2*)&ql[n][i0];
    float2 kv = *(const float2*)&kl[n][j0];
    a00 += qv.x*kv.x; a01 += qv.x*kv.y;
    a10 += qv.y*kv.x; a11 += qv.y*kv.y;
  }
  const float* ssb = ss + b*256;
  float rq0 = 1.f/fmaxf(sqrtf(ssb[h*32+i0]),1e-12f);
  float rq1 = 1.f/fmaxf(sqrtf(ssb[h*32+i0+1]),1e-12f);
  float rk0 = 1.f/fmaxf(sqrtf(ssb[128+h*32+j0]),1e-12f);
  float rk1 = 1.f/fmaxf(sqrtf(ssb[128+h*32+j0+1]),1e-12f);
  float* Sp = S + ((size_t)(b*4+h))*1024;
  atomicAdd(&Sp[i0*32+j0],     a00*rq0*rk0);
  atomicAdd(&Sp[i0*32+j0+1],   a01*rq0*rk1);
  atomicAdd(&Sp[(i0+1)*32+j0], a10*rq1*rk0);
  atomicAdd(&Sp[(i0+1)*32+j0+1], a11*rq1*rk1);
}

// ---------------- softmax over 32 cols per row, with per-head temp ----------------
__global__ void k_softmax(const float* __restrict__ S, float* __restrict__ attnP,
                          const float* __restrict__ temp)
{
  int bh = blockIdx.x; int h = bh & 3;
  int i = threadIdx.x;
  const float* row = S + (size_t)bh*1024 + i*32;
  float tp = temp[h];
  float vals[32]; float mx = -1e30f;
  #pragma unroll
  for (int j=0;j<32;++j){ float v=row[j]*tp; vals[j]=v; mx=fmaxf(mx,v); }
  float sum=0.f;
  #pragma unroll
  for (int j=0;j<32;++j){ vals[j]=__expf(vals[j]-mx); sum+=vals[j]; }
  float inv=1.f/sum;
  float* out = attnP + (size_t)bh*1024 + i*32;
  #pragma unroll
  for (int j=0;j<32;++j) out[j]=vals[j]*inv;
}

// ---------------- out = attn @ v, token-major bf16 out ----------------
__global__ __launch_bounds__(256) void k_av(const u16* __restrict__ qkvd,
    const float* __restrict__ attnP, u16* __restrict__ attnout)
{
  __shared__ float at[1024];
  int b=blockIdx.z, h=blockIdx.y;
  int n = blockIdx.x*256 + threadIdx.x;
  #pragma unroll
  for (int it=0;it<4;++it)
    at[threadIdx.x + it*256] = attnP[((size_t)(b*4+h))*1024 + threadIdx.x + it*256];
  __syncthreads();
  const u16* vrow = &qkvd[((size_t)b*9216 + n)*384 + 256 + h*32];
  float acc[32];
  #pragma unroll
  for (int i=0;i<32;++i) acc[i]=0.f;
  #pragma unroll 4
  for (int j=0;j<32;++j){
    float vj = bf2f(vrow[j]);
    #pragma unroll
    for (int i=0;i<32;++i) acc[i] += at[i*32+j]*vj;
  }
  u16* orow = &attnout[((size_t)b*9216 + n)*128 + h*32];
  #pragma unroll
  for (int i=0;i<32;++i) orow[i] = f2bf(acc[i]);
}

// ---------------- out = R1 + R2 + sum of 4 split-K partials ----------------
__global__ void k_reduce4(const float4* __restrict__ P, const float4* __restrict__ R1,
                          const float4* __restrict__ R2, float4* __restrict__ o, int n4)
{
  int i = blockIdx.x*256 + threadIdx.x;
  if (i<n4){
    float4 a=P[i], b=P[i+n4], c=P[i+2*n4], d=P[i+3*n4], r=R1[i], s=R2[i];
    o[i]=make_float4(a.x+b.x+c.x+d.x+r.x+s.x, a.y+b.y+c.y+d.y+r.y+s.y,
                     a.z+b.z+c.z+d.z+r.z+s.z, a.w+b.w+c.w+d.w+r.w+s.w);
  }
}

// ---------------- fused: xtr = R1+R2+4 partials ; xm = LN(xtr) bf16 ----------------
__global__ void k_reduce4_ln(const float4* __restrict__ P, const float4* __restrict__ R1,
    const float4* __restrict__ R2, float4* __restrict__ xtr, u16* __restrict__ xm,
    const float* __restrict__ g, const float* __restrict__ bv, int n4)
{
  int i = blockIdx.x*256 + threadIdx.x;
  int q = i & 31;
  float4 a=P[i], b=P[i+n4], c=P[i+2*n4], d=P[i+3*n4], r=R1[i], s=R2[i];
  float4 v=make_float4(a.x+b.x+c.x+d.x+r.x+s.x, a.y+b.y+c.y+d.y+r.y+s.y,
                       a.z+b.z+c.z+d.z+r.z+s.z, a.w+b.w+c.w+d.w+r.w+s.w);
  xtr[i]=v;
  float s1 = v.x+v.y+v.z+v.w;
  float s2 = v.x*v.x+v.y*v.y+v.z*v.z+v.w*v.w;
  #pragma unroll
  for (int o=1;o<32;o<<=1){ s1 += __shfl_xor(s1,o); s2 += __shfl_xor(s2,o); }
  float mu = s1*(1.f/128.f);
  float rs = rsqrtf(s2*(1.f/128.f)-mu*mu+1e-5f);
  float4 g4 = *(const float4*)(g + q*4);
  float4 b4 = *(const float4*)(bv + q*4);
  ushort4 o4;
  o4.x = f2bf((v.x-mu)*rs*g4.x + b4.x);
  o4.y = f2bf((v.y-mu)*rs*g4.y + b4.y);
  o4.z = f2bf((v.z-mu)*rs*g4.z + b4.z);
  o4.w = f2bf((v.w-mu)*rs*g4.w + b4.w);
  ((ushort4*)xm)[i] = o4;
}

// ---------------- fused misc prep: weight bf16 casts + Aneg + zeroing ----------------
__global__ void k_prep(const float* __restrict__ qkv_w, const float* __restrict__ po_w,
    const float* __restrict__ in_w, const float* __restrict__ out_w,
    const float* __restrict__ A_log, u16* __restrict__ qkvw_bf, u16* __restrict__ pow_bf,
    u16* __restrict__ inw_bf, u16* __restrict__ outw_bf, float* __restrict__ Aneg,
    float* __restrict__ zbuf, int nz)
{
  int i = blockIdx.x*256 + threadIdx.x;
  if (i < 49152) { qkvw_bf[i] = f2bf(qkv_w[i]); return; }
  i -= 49152;
  if (i < 16384) { pow_bf[i] = f2bf(po_w[i]); return; }
  i -= 16384;
  if (i < 16384) { inw_bf[i] = f2bf(in_w[i]); return; }
  i -= 16384;
  if (i < 16384) { outw_bf[i] = f2bf(out_w[i]); return; }
  i -= 16384;
  if (i < 512) { Aneg[i] = -__expf(A_log[i]); return; }
  i -= 512;
  if (i < nz) zbuf[i] = 0.f;
}

// ---------------- mamba pre: conv1d+silu for x/z, x_proj, delta ----------------
__global__ __launch_bounds__(256) void k_mamba_pre(const float* __restrict__ xz,
    float* __restrict__ xl, float* __restrict__ delta,
    float* __restrict__ Bm, float* __restrict__ Cm, u16* __restrict__ A_out,
    const float* __restrict__ cxw, const float* __restrict__ czw,
    const float* __restrict__ xpw, const float* __restrict__ dtw, const float* __restrict__ dtb)
{
  __shared__ float xls[4][64];
  __shared__ float xds[4][24];
  int w = threadIdx.x>>6;
  int tok = blockIdx.x*4 + w;
  int lane = threadIdx.x & 63;
  int l = tok % 9216;
  size_t base = (size_t)tok*128;
  float xm1 = (l>0)?     xz[base-128+lane]    : 0.f;
  float x0  =            xz[base+lane];
  float xp1 = (l<9215)?  xz[base+128+lane]    : 0.f;
  float zm1 = (l>0)?     xz[base-128+64+lane] : 0.f;
  float z0  =            xz[base+64+lane];
  float zp1 = (l<9215)?  xz[base+128+64+lane] : 0.f;
  float xc = silu_f(cxw[lane*3]*xm1 + cxw[lane*3+1]*x0 + cxw[lane*3+2]*xp1);
  float zc = silu_f(czw[lane*3]*zm1 + czw[lane*3+1]*z0 + czw[lane*3+2]*zp1);
  xl[(size_t)tok*64+lane] = xc;
  A_out[(size_t)tok*128 + 64 + lane] = f2bf(zc);
  xls[w][lane] = xc;
  __syncthreads();
  if (lane < 24) {
    float s=0.f;
    #pragma unroll 8
    for (int c=0;c<64;++c) s += xls[w][c]*xpw[lane*64+c];
    xds[w][lane]=s;
  }
  __syncthreads();
  float dacc = dtb[lane];
  #pragma unroll
  for (int r=0;r<8;++r) dacc += xds[w][r]*dtw[lane*8+r];
  delta[(size_t)tok*64+lane] = (dacc>20.f)? dacc : log1pf(__expf(dacc));
  if (lane<8)       Bm[(size_t)tok*8+lane]   = xds[w][8+lane];
  else if (lane<16) Cm[(size_t)tok*8+lane-8] = xds[w][16+lane-8];
}

// ---------------- chunked scan ----------------
__global__ __launch_bounds__(512) void k_scan1(const float* __restrict__ delta,
    const float* __restrict__ Bm, const float* __restrict__ xl,
    const float* __restrict__ Aneg, float* __restrict__ cP, float* __restrict__ cS)
{
  int b=blockIdx.y, ch=blockIdx.x;
  int t=threadIdx.x; int d=t>>3, n=t&7;
  float An = Aneg[d*8+n];
  float P=1.f, S=0.f;
  int l0 = ch*96;
  #pragma unroll 8
  for (int i=0;i<96;++i){
    size_t s = (size_t)b*9216 + l0+i;
    float del = delta[s*64+d];
    float a = __expf(del*An);
    float dbu = del * Bm[s*8+n] * xl[s*64+d];
    P *= a; S = fmaf(a,S,dbu);
  }
  size_t o = ((size_t)(b*96+ch))*512 + t;
  cP[o]=P; cS[o]=S;
}

__global__ __launch_bounds__(512) void k_scan2(const float* __restrict__ cP,
    const float* __restrict__ cS, float* __restrict__ cI)
{
  int b=blockIdx.x; int t=threadIdx.x;
  float carry=0.f;
  #pragma unroll 4
  for (int c=0;c<96;++c){
    size_t o = ((size_t)(b*96+c))*512 + t;
    cI[o]=carry;
    carry = fmaf(cP[o], carry, cS[o]);
  }
}

__global__ __launch_bounds__(512) void k_scan3(const float* __restrict__ delta,
    const float* __restrict__ Bm, const float* __restrict__ Cm,
    const float* __restrict__ xl, const float* __restrict__ Aneg,
    const float* __restrict__ Dp, const float* __restrict__ cI, u16* __restrict__ A_out)
{
  int b=blockIdx.y, ch=blockIdx.x;
  int t=threadIdx.x; int d=t>>3, n=t&7;
  float An = Aneg[d*8+n];
  float h = cI[((size_t)(b*96+ch))*512 + t];
  float Dd = Dp[d];
  int l0 = ch*96;
  #pragma unroll 4
  for (int i=0;i<96;++i){
    size_t s = (size_t)b*9216 + l0+i;
    float del = delta[s*64+d];
    float a = __expf(del*An);
    float xv = xl[s*64+d];
    h = fmaf(a, h, del * Bm[s*8+n] * xv);
    float contrib = h * Cm[s*8+n];
    contrib += __shfl_xor(contrib,1);
    contrib += __shfl_xor(contrib,2);
    contrib += __shfl_xor(contrib,4);
    if (n==0) A_out[s*128 + d] = f2bf(contrib + xv*Dd);
  }
}

// ---------------- final transpose (B,N,C) -> (B,C,N) ----------------
__global__ __launch_bounds__(256) void k_transpose_out(const float* __restrict__ sfin,
                                                       float* __restrict__ out)
{
  __shared__ float tile[128*65];
  int b=blockIdx.y, n0=blockIdx.x*64;
  for (int it=0;it<32;++it){
    int idx = threadIdx.x + it*256;
    int tok = idx>>7, c = idx&127;
    tile[c*65+tok] = sfin[((size_t)b*9216 + n0+tok)*128 + c];
  }
  __syncthreads();
  int j = threadIdx.x & 63, part = threadIdx.x>>6;
  for (int cc=0;cc<32;++cc){
    int c = part*32+cc;
    out[((size_t)b*128 + c)*9216 + n0 + j] = tile[c*65 + j];
  }
}

// ---------------- weight packers ----------------
__global__ void k_pack_w1t(const float* __restrict__ bw0, const float* __restrict__ sw0,
                           const float* __restrict__ sc0, u16* __restrict__ W1t)
{
  int idx = blockIdx.x*256 + threadIdx.x;
  if (idx >= 512*1152) return;
  int o = idx/1152, k = idx%1152;
  float v;
  if (k < 128) v = bw0[o*128+k];
  else { int i=(k-128)>>3, c=(k-128)&7; v = sw0[(o*128+i)*8+c]*sc0[o*128+i]; }
  W1t[idx]=f2bf(v);
}
__global__ void k_pack_w2t(const float* __restrict__ bw1, const float* __restrict__ sw1,
                           const float* __restrict__ sc1, u16* __restrict__ W2t)
{
  int idx = blockIdx.x*256 + threadIdx.x;
  if (idx >= 128*4608) return;
  int o = idx/4608, k = idx%4608;
  float v;
  if (k < 512) v = bw1[o*512+k];
  else { int i=(k-512)>>3, c=(k-512)&7; v = sw1[(o*512+i)*8+c]*sc1[o*512+i]; }
  W2t[idx]=f2bf(v);
}

extern "C" void kernel_launch(void* const* d_in, const int* in_sizes, int n_in,
                              void* d_out, int out_size, void* d_ws, size_t ws_size,
                              hipStream_t stream)
{
  (void)in_sizes; (void)n_in; (void)out_size; (void)ws_size;
  const float* x5d   =(const float*)d_in[0];
  const float* ln1_g =(const float*)d_in[1];
  const float* ln1_b =(const float*)d_in[2];
  const float* ln2_g =(const float*)d_in[3];
  const float* ln2_b =(const float*)d_in[4];
  const float* ln3_g =(const float*)d_in[5];
  const float* ln3_b =(const float*)d_in[6];
  const float* ln4_g =(const float*)d_in[7];
  const float* ln4_b =(const float*)d_in[8];
  const float* temp  =(const float*)d_in[9];
  const float* qkv_w =(const float*)d_in[10];
  const float* qkv_b =(const float*)d_in[11];
  const float* dw_w  =(const float*)d_in[12];
  const float* dw_b  =(const float*)d_in[13];
  const float* po_w  =(const float*)d_in[14];
  const float* po_b  =(const float*)d_in[15];
  const float* f1_ng =(const float*)d_in[16];
  const float* f1_nb =(const float*)d_in[17];
  const float* f1_bw0=(const float*)d_in[18];
  const float* f1_sw0=(const float*)d_in[19];
  const float* f1_sc0=(const float*)d_in[20];
  const float* f1_bw1=(const float*)d_in[21];
  const float* f1_sw1=(const float*)d_in[22];
  const float* f1_sc1=(const float*)d_in[23];
  const float* f2_ng =(const float*)d_in[24];
  const float* f2_nb =(const float*)d_in[25];
  const float* f2_bw0=(const float*)d_in[26];
  const float* f2_sw0=(const float*)d_in[27];
  const float* f2_sc0=(const float*)d_in[28];
  const float* f2_bw1=(const float*)d_in[29];
  const float* f2_sw1=(const float*)d_in[30];
  const float* f2_sc1=(const float*)d_in[31];
  const float* in_w  =(const float*)d_in[32];
  const float* xp_w  =(const float*)d_in[33];
  const float* dt_w  =(const float*)d_in[34];
  const float* dt_b  =(const float*)d_in[35];
  const float* A_log =(const float*)d_in[36];
  const float* Dp    =(const float*)d_in[37];
  const float* out_w =(const float*)d_in[38];
  const float* cx_w  =(const float*)d_in[39];
  const float* cz_w  =(const float*)d_in[40];
  float* out = (float*)d_out;

  const size_t T = 18432;   // B*N tokens
  char* wsb = (char*)d_ws;
  size_t off = 0;
  auto alloc = [&](size_t bytes)->void* {
    void* p = wsb + off; off += (bytes + 255) & ~(size_t)255; return p;
  };
  float* x_t    = (float*)alloc(T*128*4);
  char*  scrA   = (char*) alloc(38*1024*1024);   // shared scratch region
  float* ssS    = (float*)alloc((512+8192+8192)*4);
  float* t_t    = (float*)alloc(T*128*4);        // reused as m_t
  u16*   A1     = (u16*)  alloc(T*1152*2);
  u16*   hbuf   = (u16*)  alloc(T*512*2);
  float* xtr    = (float*)alloc(T*128*4);
  u16*   xm     = (u16*)  alloc(T*128*2);
  float* xl     = (float*)alloc(T*64*4);
  float* delta  = (float*)alloc(T*64*4);
  float* Bm     = (float*)alloc(T*8*4);
  float* Cm     = (float*)alloc(T*8*4);
  u16*   A_out  = (u16*)  alloc(T*128*2);
  float* cP     = (float*)alloc(2*96*512*4);
  float* cS     = (float*)alloc(2*96*512*4);
  float* cI     = (float*)alloc(2*96*512*4);
  float* sfin   = (float*)alloc(T*128*4);
  u16* qkvw_bf  = (u16*)alloc(384*128*2);
  u16* pow_bf   = (u16*)alloc(128*128*2);
  u16* inw_bf   = (u16*)alloc(128*128*2);
  u16* outw_bf  = (u16*)alloc(128*128*2);
  u16* W1t_a    = (u16*)alloc(512*1152*2);
  u16* W2t_a    = (u16*)alloc(128*4608*2);
  u16* W1t_b    = (u16*)alloc(512*1152*2);
  u16* W2t_b    = (u16*)alloc(128*4608*2);
  float* Aneg   = (float*)alloc(512*4);
  float* ss = ssS;
  float* S  = ssS + 512;
  float* attnP = ssS + 512 + 8192;
  // scratch-region sub-allocations (lifetimes disjoint):
  u16*   ln1_t  = (u16*)(scrA);                              // 4.7 MB
  u16*   qkv_tb = (u16*)(scrA + 4718592);                    // 14.2 MB
  u16*   qkvd   = (u16*)(scrA + 4718592 + 14155776);         // 14.2 MB
  u16*   attnout= (u16*)(scrA + 4718592 + 2*14155776);       // 4.7 MB
  float* part   = (float*)scrA;    // 4 x T*128 f32 = 37.7 MB (FKAN split-K partials)
  float* xz     = (float*)scrA;    // T*128 f32 (mamba, disjoint from partial use)
  float* m_t    = t_t;

  // ---- weight prep ----
  k_pack_w1t<<<2304,256,0,stream>>>(f1_bw0, f1_sw0, f1_sc0, W1t_a);
  k_pack_w1t<<<2304,256,0,stream>>>(f2_bw0, f2_sw0, f2_sc0, W1t_b);
  k_pack_w2t<<<2304,256,0,stream>>>(f1_bw1, f1_sw1, f1_sc1, W2t_a);
  k_pack_w2t<<<2304,256,0,stream>>>(f2_bw1, f2_sw1, f2_sc1, W2t_b);
  k_prep<<<420,256,0,stream>>>(qkv_w, po_w, in_w, out_w, A_log,
      qkvw_bf, pow_bf, inw_bf, outw_bf, Aneg, ssS, 512+8192);

  // ---- attention ----
  k_ln1_trans<<<dim3(144,2),256,0,stream>>>(x5d, x_t, ln1_t, ln1_g, ln1_b);
  gemm2w<0,true><<<dim3(3,288,1),128,0,stream>>>(ln1_t, qkvw_bf, qkv_tb,
      18432, 384, 128, 2, 0, qkv_b, nullptr);
  k_dwconv<<<dim3(144,6,2),256,0,stream>>>(qkv_tb, qkvd, dw_w, dw_b);
  k_normsum<<<dim3(72,2),256,0,stream>>>(qkvd, ss);
  k_qk<<<dim3(72,4,2),256,0,stream>>>(qkvd, ss, S);
  k_softmax<<<8,32,0,stream>>>(S, attnP, temp);
  k_av<<<dim3(36,4,2),256,0,stream>>>(qkvd, attnP, attnout);
  gemm2w<0,false><<<dim3(1,288,1),128,0,stream>>>(attnout, pow_bf, t_t,
      18432, 128, 128, 2, 0, po_b, x_t);                 // t = x + attn(ln1(x))

  // ---- FKAN 1 ----
  k_ln_double_expand<<<4608,256,0,stream>>>(t_t, A1, ln2_g, ln2_b, f1_ng, f1_nb);
  gemm2w<0,true><<<dim3(4,288,1),128,0,stream>>>(A1, W1t_a, hbuf,
      18432, 512, 1152, 18, 0, nullptr, nullptr);
  gemm2w<512,false><<<dim3(1,288,4),128,0,stream>>>(hbuf, W2t_a, part,
      18432, 128, 4608, 18, 1, nullptr, nullptr);
  k_reduce4_ln<<<2304,256,0,stream>>>((const float4*)part, (const float4*)t_t,
      (const float4*)x_t, (float4*)xtr, xm, ln3_g, ln3_b, (int)(T*128/4));
      // x_tr = t + x + kan2 ; xm = LN3(x_tr) bf16

  // ---- Mamba ----
  gemm2w<0,false><<<dim3(1,288,1),128,0,stream>>>(xm, inw_bf, xz,
      18432, 128, 128, 2, 0, nullptr, nullptr);
  k_mamba_pre<<<4608,256,0,stream>>>(xz, xl, delta, Bm, Cm, A_out,
      cx_w, cz_w, xp_w, dt_w, dt_b);
  k_scan1<<<dim3(96,2),512,0,stream>>>(delta, Bm, xl, Aneg, cP, cS);
  k_scan2<<<2,512,0,stream>>>(cP, cS, cI);
  k_scan3<<<dim3(96,2),512,0,stream>>>(delta, Bm, Cm, xl, Aneg, Dp, cI, A_out);
  gemm2w<0,false><<<dim3(1,288,1),128,0,stream>>>(A_out, outw_bf, m_t,
      18432, 128, 128, 2, 0, nullptr, xtr);              // m = mamba + x_tr

  // ---- FKAN 2 ----
  k_ln_double_expand<<<4608,256,0,stream>>>(m_t, A1, ln4_g, ln4_b, f2_ng, f2_nb);
  gemm2w<0,true><<<dim3(4,288,1),128,0,stream>>>(A1, W1t_b, hbuf,
      18432, 512, 1152, 18, 0, nullptr, nullptr);
  gemm2w<512,false><<<dim3(1,288,4),128,0,stream>>>(hbuf, W2t_b, part,
      18432, 128, 4608, 18, 1, nullptr, nullptr);
  k_reduce4<<<2304,256,0,stream>>>((const float4*)part, (const float4*)m_t,
      (const float4*)xtr, (float4*)sfin, (int)(T*128/4)); // out = m + x_tr + kan2

  k_transpose_out<<<dim3(144,2),256,0,stream>>>(sfin, out);
}

// Round 6
// 542.295 us; speedup vs baseline: 1.0394x; 1.0394x over previous
//
#include <hip/hip_runtime.h>

typedef unsigned short u16;
typedef __attribute__((ext_vector_type(8))) short bh8;   // 8 x bf16 (4 VGPRs)
typedef __attribute__((ext_vector_type(4))) float f4;    // MFMA accumulator

#define DI __device__ __forceinline__

DI u16 f2bf(float f){ unsigned u=__float_as_uint(f); u += 0x7fffu + ((u>>16)&1u); return (u16)(u>>16); }
DI float bf2f(u16 u){ return __uint_as_float(((unsigned)u)<<16); }
DI float silu_f(float x){ return x/(1.f+__expf(-x)); }

DI void gld16(const u16* g, u16* l){
  __builtin_amdgcn_global_load_lds((const __attribute__((address_space(1))) void*)g,
                                   (__attribute__((address_space(3))) void*)l, 16, 0, 0);
}

// uniform cubic B-spline bases on grid [-2.2 : 0.4 : 2.2], 8 output bases.
// Branchless gather form: basis j = B3(u-(j+2)), B3(a)=(2-a)+^3/6 - (1-a)+^3*2/3.
// Out-of-range u -> all zero (matches indicator recursion). 0 LDS bank conflicts
// when written as a single b128 [measured r3].
DI void bspline8(float x, float* v){
  float u = x*2.5f + 5.5f;           // (x + 2.2)/0.4
  #pragma unroll
  for (int j=0;j<8;j++){
    float a  = fabsf(u - (float)(j+2));
    float t1 = fmaxf(2.f-a, 0.f);
    float t2 = fmaxf(1.f-a, 0.f);
    v[j] = t1*t1*t1*(1.f/6.f) - t2*t2*t2*(2.f/3.f);
  }
}

// ---------------- GEMM (64x128 tile, 4 waves): C = A(MxK) * Bt(NxK)^T ----------------
// Round-4 shape (best measured): wave w owns rows 0..63 x cols w*32..w*32+31, 4x2 acc.
// BK=64. LDS: sB(128x64) | sA(64x64), 16B chunks XOR-swizzled (chunk c of row r at
// c^(r&7)); global_load_lds lanes fetch permuted chunks so swizzle is free.
// KAN_H>0: A generated from h (M x KAN_H bf16): cols [0,KAN_H)=silu(h), rest=spline
// via branchless 8-basis + single b128 write (0 bank conflicts).
// OUT_BF16: bf16 output staged via LDS -> 256B-contiguous stores (no RMW
// amplification). Else f32 direct (+bias/R1); split!=0 -> C += z*M*N.
template<int KAN_H, bool OUT_BF16>
__global__ __launch_bounds__(256, 4)
void gemm64(const void* __restrict__ Asrc, const u16* __restrict__ Bt,
            void* __restrict__ Cout, int M, int N, int K, int ktiles_per_z,
            int split, const float* __restrict__ bias, const float* __restrict__ R1)
{
  __shared__ __align__(128) u16 smem[12288];  // sB[0..8192) sA[8192..12288)
  u16* const sB = smem;
  u16* const sA = smem + 8192;
  const int m0 = blockIdx.y * 64;
  const int n0 = blockIdx.x * 128;
  const int ktiles = K >> 6;
  int kt0 = blockIdx.z * ktiles_per_z;
  int kt1 = kt0 + ktiles_per_z; if (kt1 > ktiles) kt1 = ktiles;
  const int t = threadIdx.x;
  const int wave = t >> 6, lane = t & 63;
  const int lr = lane & 15, lq = lane >> 4;
  const int lr8 = lane >> 3, lc8 = lane & 7;
  const int swz8 = lc8 ^ lr8;      // swizzled global chunk for this lane (row&7 == lr8)
  f4 acc[4][2];
  f4 z4 = {0.f,0.f,0.f,0.f};
  #pragma unroll
  for (int i=0;i<4;i++){ acc[i][0]=z4; acc[i][1]=z4; }

  for (int kt = kt0; kt < kt1; ++kt) {
    int k0 = kt << 6;
    // stage Bt tile (128 rows) via async global->LDS, swizzled
    {
      const u16* Bp = Bt + (size_t)n0 * K + k0;
      #pragma unroll
      for (int it=0; it<4; ++it) {
        int r = it*32 + wave*8;
        gld16(Bp + (size_t)(r + lr8) * K + swz8*8, &sB[r*64]);
      }
    }
    // stage A tile (64 rows)
    if (KAN_H == 0) {
      const u16* Ap = (const u16*)Asrc + (size_t)m0 * K + k0;
      #pragma unroll
      for (int it=0; it<2; ++it) {
        int r = it*32 + wave*8;
        gld16(Ap + (size_t)(r + lr8) * K + swz8*8, &sA[r*64]);
      }
    } else {
      const u16* hsrc = (const u16*)Asrc;
      if (k0 < KAN_H) {
        // silu region: 64 rows x 64 cols = 512 chunks of 8
        #pragma unroll
        for (int it=0; it<2; ++it) {
          int chunk = t + it*256;
          int r = chunk >> 3, ck = chunk & 7;
          const u16* src = hsrc + (size_t)(m0+r)*KAN_H + k0 + ck*8;
          ushort4 a = *(const ushort4*)src;
          ushort4 b2 = *(const ushort4*)(src+4);
          alignas(16) u16 o[8];
          o[0]=f2bf(silu_f(bf2f(a.x))); o[1]=f2bf(silu_f(bf2f(a.y)));
          o[2]=f2bf(silu_f(bf2f(a.z))); o[3]=f2bf(silu_f(bf2f(a.w)));
          o[4]=f2bf(silu_f(bf2f(b2.x))); o[5]=f2bf(silu_f(bf2f(b2.y)));
          o[6]=f2bf(silu_f(bf2f(b2.z))); o[7]=f2bf(silu_f(bf2f(b2.w)));
          *(float4*)(&sA[r*64 + (ck ^ (r&7))*8]) = *(const float4*)o;
        }
      } else {
        // spline region: (row, feature) -> 8 bases, single b128 write
        int i0 = (k0 - KAN_H) >> 3;
        #pragma unroll
        for (int it=0; it<2; ++it) {
          int pair = t + it*256;
          int r = pair >> 3, ii = pair & 7;
          float x = bf2f(hsrc[(size_t)(m0+r)*KAN_H + i0 + ii]);
          float w[8];
          bspline8(x, w);
          alignas(16) u16 o[8];
          #pragma unroll
          for (int j=0;j<8;j++) o[j]=f2bf(w[j]);
          *(float4*)(&sA[r*64 + (ii ^ (r&7))*8]) = *(const float4*)o;
        }
      }
    }
    __syncthreads();
    #pragma unroll
    for (int kk=0; kk<64; kk+=32) {
      const int c0k = kk >> 3;
      bh8 af[4], bfr[2];
      #pragma unroll
      for (int i=0;i<4;i++) {
        int row = i*16 + lr;
        af[i] = *(const bh8*)(&sA[row*64 + ((c0k+lq) ^ (row&7))*8]);
      }
      #pragma unroll
      for (int j=0;j<2;j++) {
        int row = wave*32 + j*16 + lr;
        bfr[j] = *(const bh8*)(&sB[row*64 + ((c0k+lq) ^ (row&7))*8]);
      }
      #pragma unroll
      for (int i=0;i<4;i++)
        #pragma unroll
        for (int j=0;j<2;j++)
          acc[i][j] = __builtin_amdgcn_mfma_f32_16x16x32_bf16(af[i], bfr[j], acc[i][j], 0, 0, 0);
    }
    __syncthreads();
  }
  // epilogue: C/D layout col=lane&15, row=(lane>>4)*4+reg
  if (OUT_BF16) {
    // stage bf16 tile (64 x 128, stride 136) in LDS -> 256B-contiguous stores
    u16* Cb = (u16*)Cout;
    #pragma unroll
    for (int i=0;i<4;i++) {
      #pragma unroll
      for (int j=0;j<2;j++) {
        int col = wave*32 + j*16 + lr;
        float bv = bias ? bias[n0 + col] : 0.f;
        #pragma unroll
        for (int r4=0;r4<4;r4++) {
          int row = i*16 + lq*4 + r4;
          smem[row*136 + col] = f2bf(acc[i][j][r4] + bv);
        }
      }
    }
    __syncthreads();
    #pragma unroll
    for (int it=0; it<4; ++it) {
      int idx = t + it*256;
      int row = idx >> 4, seg = idx & 15;
      *(float4*)(Cb + (size_t)(m0+row)*N + n0 + seg*8) =
          *(const float4*)&smem[row*136 + seg*8];
    }
  } else {
    float* Cf = (float*)Cout;
    if (split) Cf += (size_t)blockIdx.z * M * N;
    #pragma unroll
    for (int i=0;i<4;i++) {
      int row = m0 + i*16 + lq*4;
      #pragma unroll
      for (int j=0;j<2;j++) {
        int col = n0 + wave*32 + j*16 + lr;
        float bv = bias ? bias[col] : 0.f;
        #pragma unroll
        for (int r4=0;r4<4;r4++) {
          size_t idx = (size_t)(row + r4) * N + col;
          float v = acc[i][j][r4] + bv;
          if (R1) v += R1[idx];
          Cf[idx] = v;
        }
      }
    }
  }
}

// ---------------- transpose + LN1: x5d (B,C,N) -> x_t (B,N,C) f32 and ln1_t bf16 ----------------
__global__ __launch_bounds__(256) void k_ln1_trans(const float* __restrict__ x5d,
    float* __restrict__ x_t, u16* __restrict__ ln1_t,
    const float* __restrict__ g, const float* __restrict__ bv)
{
  __shared__ float tile[128*65];
  __shared__ float red_s[256], red_q[256];
  __shared__ float st_mu[64], st_rs[64];
  int b = blockIdx.y, n0 = blockIdx.x * 64;
  int j = threadIdx.x & 63, part = threadIdx.x >> 6;
  for (int cc=0; cc<32; ++cc) {
    int c = part*32 + cc;
    tile[c*65 + j] = x5d[((size_t)b*128 + c)*9216 + n0 + j];
  }
  __syncthreads();
  float s=0.f, s2=0.f;
  for (int cc=0; cc<32; ++cc) {
    float v = tile[(part*32+cc)*65 + j];
    s += v; s2 += v*v;
  }
  red_s[threadIdx.x]=s; red_q[threadIdx.x]=s2;
  __syncthreads();
  if (threadIdx.x < 64) {
    int jj = threadIdx.x;
    float ts = red_s[jj]+red_s[jj+64]+red_s[jj+128]+red_s[jj+192];
    float tq = red_q[jj]+red_q[jj+64]+red_q[jj+128]+red_q[jj+192];
    float mu = ts*(1.f/128.f);
    st_mu[jj]=mu;
    st_rs[jj]=rsqrtf(tq*(1.f/128.f) - mu*mu + 1e-5f);
  }
  __syncthreads();
  for (int it=0; it<32; ++it) {
    int idx = threadIdx.x + it*256;
    int tok = idx >> 7, c = idx & 127;
    float v = tile[c*65 + tok];
    size_t a = ((size_t)b*9216 + n0 + tok)*128 + c;
    x_t[a] = v;
    ln1_t[a] = f2bf((v - st_mu[tok])*st_rs[tok]*g[c] + bv[c]);
  }
}

// ---------------- double LN + KAN expansion: writes A1 (T x 1152 bf16) ----------------
__global__ void k_ln_double_expand(const float* __restrict__ in, u16* __restrict__ A1,
    const float* __restrict__ g1, const float* __restrict__ b1,
    const float* __restrict__ g2, const float* __restrict__ b2)
{
  int tok = blockIdx.x*4 + (threadIdx.x>>6);
  int lane = threadIdx.x & 63;
  const float* row = in + (size_t)tok*128;
  float v0=row[lane], v1=row[lane+64];
  float s=v0+v1, s2=v0*v0+v1*v1;
  #pragma unroll
  for (int o=1;o<64;o<<=1){ s += __shfl_xor(s,o); s2 += __shfl_xor(s2,o); }
  float mu=s*(1.f/128.f);
  float rs=rsqrtf(s2*(1.f/128.f)-mu*mu+1e-5f);
  float y0=(v0-mu)*rs*g1[lane]+b1[lane];
  float y1=(v1-mu)*rs*g1[lane+64]+b1[lane+64];
  s=y0+y1; s2=y0*y0+y1*y1;
  #pragma unroll
  for (int o=1;o<64;o<<=1){ s += __shfl_xor(s,o); s2 += __shfl_xor(s2,o); }
  mu=s*(1.f/128.f);
  rs=rsqrtf(s2*(1.f/128.f)-mu*mu+1e-5f);
  y0=(y0-mu)*rs*g2[lane]+b2[lane];
  y1=(y1-mu)*rs*g2[lane+64]+b2[lane+64];
  u16* arow = A1 + (size_t)tok*1152;
  arow[lane]    = f2bf(silu_f(y0));
  arow[lane+64] = f2bf(silu_f(y1));
  float w[8]; alignas(16) u16 o8[8];
  bspline8(y0, w);
  #pragma unroll
  for (int j=0;j<8;j++) o8[j]=f2bf(w[j]);
  *(float4*)(&arow[128 + lane*8]) = *(const float4*)o8;
  bspline8(y1, w);
  #pragma unroll
  for (int j=0;j<8;j++) o8[j]=f2bf(w[j]);
  *(float4*)(&arow[128 + (lane+64)*8]) = *(const float4*)o8;
}

// ---------------- depthwise 3x3 conv, token-major, bf16 in -> bf16 out, + bias ----------------
__global__ __launch_bounds__(256) void k_dwconv(const u16* __restrict__ qkv_t,
    u16* __restrict__ qkvd, const float* __restrict__ dw_w, const float* __restrict__ dw_b)
{
  __shared__ float lt[100*68];
  int tile = blockIdx.x; int th=(tile/12)*8, tw=(tile%12)*8;
  int cg = blockIdx.y, b = blockIdx.z;
  int t = threadIdx.x;
  for (int pp=0; pp<7; ++pp) {
    int pos = pp*16 + (t>>4);
    if (pos < 100) {
      int ih = th + pos/10 - 1, iw = tw + pos%10 - 1;
      int c4 = (t & 15)*4;
      float4 v = make_float4(0.f,0.f,0.f,0.f);
      if (ih>=0 && ih<96 && iw>=0 && iw<96) {
        ushort4 raw = *(const ushort4*)&qkv_t[(((size_t)b*9216) + ih*96 + iw)*384 + cg*64 + c4];
        v = make_float4(bf2f(raw.x), bf2f(raw.y), bf2f(raw.z), bf2f(raw.w));
      }
      *(float4*)&lt[pos*68 + c4] = v;
    }
  }
  __syncthreads();
  int ch = t & 63, gch = cg*64 + ch;
  float w[9];
  #pragma unroll
  for (int k=0;k<9;k++) w[k]=dw_w[gch*9+k];
  float bias = dw_b[gch];
  for (int pp=0; pp<16; ++pp) {
    int pos = (t>>6) + pp*4;
    int oh = pos>>3, ow = pos&7;
    float acc = bias;
    #pragma unroll
    for (int di=0; di<3; ++di)
      #pragma unroll
      for (int dj=0; dj<3; ++dj)
        acc += lt[((oh+di)*10 + ow+dj)*68 + ch] * w[di*3+dj];
    qkvd[(((size_t)b*9216) + (th+oh)*96 + tw+ow)*384 + gch] = f2bf(acc);
  }
}

// ---------------- sum of squares over n for q,k channels (c = 0..255) ----------------
__global__ void k_normsum(const u16* __restrict__ qkvd, float* __restrict__ ss)
{
  int b = blockIdx.y, n0 = blockIdx.x*128;
  int c = threadIdx.x;
  float acc=0.f;
  for (int i=0;i<128;++i){
    float v = bf2f(qkvd[((size_t)b*9216 + n0+i)*384 + c]);
    acc += v*v;
  }
  atomicAdd(&ss[b*256 + c], acc);
}

// ---------------- partial q@k^T with normalization, atomic into S ----------------
__global__ __launch_bounds__(256) void k_qk(const u16* __restrict__ qkvd,
    const float* __restrict__ ss, float* __restrict__ S)
{
  __shared__ float ql[128][32];
  __shared__ float kl[128][32];
  int nc=blockIdx.x, h=blockIdx.y, b=blockIdx.z;
  int t = threadIdx.x;
  int r = t>>1, half = t&1;
  size_t rowa = ((size_t)b*9216 + nc*128 + r)*384 + (half?128:0) + h*32;
  #pragma unroll
  for (int cc=0; cc<32; ++cc) {
    float v = bf2f(qkvd[rowa + cc]);
    if (half) kl[r][cc]=v; else ql[r][cc]=v;
  }
  __syncthreads();
  int i0 = (t>>4)*2, j0 = (t&15)*2;
  float a00=0.f,a01=0.f,a10=0.f,a11=0.f;
  for (int n=0;n<128;++n){
    float2 qv = *(const float2*)&ql[n][i0];
    float2 kv = *(const float2*)&kl[n][j0];
    a00 += qv.x*kv.x; a01 += qv.x*kv.y;
    a10 += qv.y*kv.x; a11 += qv.y*kv.y;
  }
  const float* ssb = ss + b*256;
  float rq0 = 1.f/fmaxf(sqrtf(ssb[h*32+i0]),1e-12f);
  float rq1 = 1.f/fmaxf(sqrtf(ssb[h*32+i0+1]),1e-12f);
  float rk0 = 1.f/fmaxf(sqrtf(ssb[128+h*32+j0]),1e-12f);
  float rk1 = 1.f/fmaxf(sqrtf(ssb[128+h*32+j0+1]),1e-12f);
  float* Sp = S + ((size_t)(b*4+h))*1024;
  atomicAdd(&Sp[i0*32+j0],     a00*rq0*rk0);
  atomicAdd(&Sp[i0*32+j0+1],   a01*rq0*rk1);
  atomicAdd(&Sp[(i0+1)*32+j0], a10*rq1*rk0);
  atomicAdd(&Sp[(i0+1)*32+j0+1], a11*rq1*rk1);
}

// ---------------- softmax over 32 cols per row, with per-head temp ----------------
__global__ void k_softmax(const float* __restrict__ S, float* __restrict__ attnP,
                          const float* __restrict__ temp)
{
  int bh = blockIdx.x; int h = bh & 3;
  int i = threadIdx.x;
  const float* row = S + (size_t)bh*1024 + i*32;
  float tp = temp[h];
  float vals[32]; float mx = -1e30f;
  #pragma unroll
  for (int j=0;j<32;++j){ float v=row[j]*tp; vals[j]=v; mx=fmaxf(mx,v); }
  float sum=0.f;
  #pragma unroll
  for (int j=0;j<32;++j){ vals[j]=__expf(vals[j]-mx); sum+=vals[j]; }
  float inv=1.f/sum;
  float* out = attnP + (size_t)bh*1024 + i*32;
  #pragma unroll
  for (int j=0;j<32;++j) out[j]=vals[j]*inv;
}

// ---------------- out = attn @ v, token-major bf16 out ----------------
__global__ __launch_bounds__(256) void k_av(const u16* __restrict__ qkvd,
    const float* __restrict__ attnP, u16* __restrict__ attnout)
{
  __shared__ float at[1024];
  int b=blockIdx.z, h=blockIdx.y;
  int n = blockIdx.x*256 + threadIdx.x;
  #pragma unroll
  for (int it=0;it<4;++it)
    at[threadIdx.x + it*256] = attnP[((size_t)(b*4+h))*1024 + threadIdx.x + it*256];
  __syncthreads();
  const u16* vrow = &qkvd[((size_t)b*9216 + n)*384 + 256 + h*32];
  float acc[32];
  #pragma unroll
  for (int i=0;i<32;++i) acc[i]=0.f;
  #pragma unroll 4
  for (int j=0;j<32;++j){
    float vj = bf2f(vrow[j]);
    #pragma unroll
    for (int i=0;i<32;++i) acc[i] += at[i*32+j]*vj;
  }
  u16* orow = &attnout[((size_t)b*9216 + n)*128 + h*32];
  #pragma unroll
  for (int i=0;i<32;++i) orow[i] = f2bf(acc[i]);
}

// ---------------- out = R1 + R2 + sum of 4 split-K partials ----------------
__global__ void k_reduce4(const float4* __restrict__ P, const float4* __restrict__ R1,
                          const float4* __restrict__ R2, float4* __restrict__ o, int n4)
{
  int i = blockIdx.x*256 + threadIdx.x;
  if (i<n4){
    float4 a=P[i], b=P[i+n4], c=P[i+2*n4], d=P[i+3*n4], r=R1[i], s=R2[i];
    o[i]=make_float4(a.x+b.x+c.x+d.x+r.x+s.x, a.y+b.y+c.y+d.y+r.y+s.y,
                     a.z+b.z+c.z+d.z+r.z+s.z, a.w+b.w+c.w+d.w+r.w+s.w);
  }
}

// ---------------- fused: xtr = R1+R2+4 partials ; xm = LN(xtr) bf16 ----------------
__global__ void k_reduce4_ln(const float4* __restrict__ P, const float4* __restrict__ R1,
    const float4* __restrict__ R2, float4* __restrict__ xtr, u16* __restrict__ xm,
    const float* __restrict__ g, const float* __restrict__ bv, int n4)
{
  int i = blockIdx.x*256 + threadIdx.x;
  int q = i & 31;
  float4 a=P[i], b=P[i+n4], c=P[i+2*n4], d=P[i+3*n4], r=R1[i], s=R2[i];
  float4 v=make_float4(a.x+b.x+c.x+d.x+r.x+s.x, a.y+b.y+c.y+d.y+r.y+s.y,
                       a.z+b.z+c.z+d.z+r.z+s.z, a.w+b.w+c.w+d.w+r.w+s.w);
  xtr[i]=v;
  float s1 = v.x+v.y+v.z+v.w;
  float s2 = v.x*v.x+v.y*v.y+v.z*v.z+v.w*v.w;
  #pragma unroll
  for (int o=1;o<32;o<<=1){ s1 += __shfl_xor(s1,o); s2 += __shfl_xor(s2,o); }
  float mu = s1*(1.f/128.f);
  float rs = rsqrtf(s2*(1.f/128.f)-mu*mu+1e-5f);
  float4 g4 = *(const float4*)(g + q*4);
  float4 b4 = *(const float4*)(bv + q*4);
  ushort4 o4;
  o4.x = f2bf((v.x-mu)*rs*g4.x + b4.x);
  o4.y = f2bf((v.y-mu)*rs*g4.y + b4.y);
  o4.z = f2bf((v.z-mu)*rs*g4.z + b4.z);
  o4.w = f2bf((v.w-mu)*rs*g4.w + b4.w);
  ((ushort4*)xm)[i] = o4;
}

// ---------------- fused misc prep: weight bf16 casts + Aneg + zeroing ----------------
__global__ void k_prep(const float* __restrict__ qkv_w, const float* __restrict__ po_w,
    const float* __restrict__ in_w, const float* __restrict__ out_w,
    const float* __restrict__ A_log, u16* __restrict__ qkvw_bf, u16* __restrict__ pow_bf,
    u16* __restrict__ inw_bf, u16* __restrict__ outw_bf, float* __restrict__ Aneg,
    float* __restrict__ zbuf, int nz)
{
  int i = blockIdx.x*256 + threadIdx.x;
  if (i < 49152) { qkvw_bf[i] = f2bf(qkv_w[i]); return; }
  i -= 49152;
  if (i < 16384) { pow_bf[i] = f2bf(po_w[i]); return; }
  i -= 16384;
  if (i < 16384) { inw_bf[i] = f2bf(in_w[i]); return; }
  i -= 16384;
  if (i < 16384) { outw_bf[i] = f2bf(out_w[i]); return; }
  i -= 16384;
  if (i < 512) { Aneg[i] = -__expf(A_log[i]); return; }
  i -= 512;
  if (i < nz) zbuf[i] = 0.f;
}

// ---------------- mamba pre: conv1d+silu for x/z, x_proj, delta ----------------
__global__ __launch_bounds__(256) void k_mamba_pre(const float* __restrict__ xz,
    float* __restrict__ xl, float* __restrict__ delta,
    float* __restrict__ Bm, float* __restrict__ Cm, u16* __restrict__ A_out,
    const float* __restrict__ cxw, const float* __restrict__ czw,
    const float* __restrict__ xpw, const float* __restrict__ dtw, const float* __restrict__ dtb)
{
  __shared__ float xls[4][64];
  __shared__ float xds[4][24];
  int w = threadIdx.x>>6;
  int tok = blockIdx.x*4 + w;
  int lane = threadIdx.x & 63;
  int l = tok % 9216;
  size_t base = (size_t)tok*128;
  float xm1 = (l>0)?     xz[base-128+lane]    : 0.f;
  float x0  =            xz[base+lane];
  float xp1 = (l<9215)?  xz[base+128+lane]    : 0.f;
  float zm1 = (l>0)?     xz[base-128+64+lane] : 0.f;
  float z0  =            xz[base+64+lane];
  float zp1 = (l<9215)?  xz[base+128+64+lane] : 0.f;
  float xc = silu_f(cxw[lane*3]*xm1 + cxw[lane*3+1]*x0 + cxw[lane*3+2]*xp1);
  float zc = silu_f(czw[lane*3]*zm1 + czw[lane*3+1]*z0 + czw[lane*3+2]*zp1);
  xl[(size_t)tok*64+lane] = xc;
  A_out[(size_t)tok*128 + 64 + lane] = f2bf(zc);
  xls[w][lane] = xc;
  __syncthreads();
  if (lane < 24) {
    float s=0.f;
    #pragma unroll 8
    for (int c=0;c<64;++c) s += xls[w][c]*xpw[lane*64+c];
    xds[w][lane]=s;
  }
  __syncthreads();
  float dacc = dtb[lane];
  #pragma unroll
  for (int r=0;r<8;++r) dacc += xds[w][r]*dtw[lane*8+r];
  delta[(size_t)tok*64+lane] = (dacc>20.f)? dacc : log1pf(__expf(dacc));
  if (lane<8)       Bm[(size_t)tok*8+lane]   = xds[w][8+lane];
  else if (lane<16) Cm[(size_t)tok*8+lane-8] = xds[w][16+lane-8];
}

// ---------------- chunked scan ----------------
__global__ __launch_bounds__(512) void k_scan1(const float* __restrict__ delta,
    const float* __restrict__ Bm, const float* __restrict__ xl,
    const float* __restrict__ Aneg, float* __restrict__ cP, float* __restrict__ cS)
{
  int b=blockIdx.y, ch=blockIdx.x;
  int t=threadIdx.x; int d=t>>3, n=t&7;
  float An = Aneg[d*8+n];
  float P=1.f, S=0.f;
  int l0 = ch*96;
  #pragma unroll 8
  for (int i=0;i<96;++i){
    size_t s = (size_t)b*9216 + l0+i;
    float del = delta[s*64+d];
    float a = __expf(del*An);
    float dbu = del * Bm[s*8+n] * xl[s*64+d];
    P *= a; S = fmaf(a,S,dbu);
  }
  size_t o = ((size_t)(b*96+ch))*512 + t;
  cP[o]=P; cS[o]=S;
}

__global__ __launch_bounds__(512) void k_scan2(const float* __restrict__ cP,
    const float* __restrict__ cS, float* __restrict__ cI)
{
  int b=blockIdx.x; int t=threadIdx.x;
  float carry=0.f;
  #pragma unroll 4
  for (int c=0;c<96;++c){
    size_t o = ((size_t)(b*96+c))*512 + t;
    cI[o]=carry;
    carry = fmaf(cP[o], carry, cS[o]);
  }
}

__global__ __launch_bounds__(512) void k_scan3(const float* __restrict__ delta,
    const float* __restrict__ Bm, const float* __restrict__ Cm,
    const float* __restrict__ xl, const float* __restrict__ Aneg,
    const float* __restrict__ Dp, const float* __restrict__ cI, u16* __restrict__ A_out)
{
  int b=blockIdx.y, ch=blockIdx.x;
  int t=threadIdx.x; int d=t>>3, n=t&7;
  float An = Aneg[d*8+n];
  float h = cI[((size_t)(b*96+ch))*512 + t];
  float Dd = Dp[d];
  int l0 = ch*96;
  #pragma unroll 4
  for (int i=0;i<96;++i){
    size_t s = (size_t)b*9216 + l0+i;
    float del = delta[s*64+d];
    float a = __expf(del*An);
    float xv = xl[s*64+d];
    h = fmaf(a, h, del * Bm[s*8+n] * xv);
    float contrib = h * Cm[s*8+n];
    contrib += __shfl_xor(contrib,1);
    contrib += __shfl_xor(contrib,2);
    contrib += __shfl_xor(contrib,4);
    if (n==0) A_out[s*128 + d] = f2bf(contrib + xv*Dd);
  }
}

// ---------------- final transpose (B,N,C) -> (B,C,N) ----------------
__global__ __launch_bounds__(256) void k_transpose_out(const float* __restrict__ sfin,
                                                       float* __restrict__ out)
{
  __shared__ float tile[128*65];
  int b=blockIdx.y, n0=blockIdx.x*64;
  for (int it=0;it<32;++it){
    int idx = threadIdx.x + it*256;
    int tok = idx>>7, c = idx&127;
    tile[c*65+tok] = sfin[((size_t)b*9216 + n0+tok)*128 + c];
  }
  __syncthreads();
  int j = threadIdx.x & 63, part = threadIdx.x>>6;
  for (int cc=0;cc<32;++cc){
    int c = part*32+cc;
    out[((size_t)b*128 + c)*9216 + n0 + j] = tile[c*65 + j];
  }
}

// ---------------- weight packers ----------------
__global__ void k_pack_w1t(const float* __restrict__ bw0, const float* __restrict__ sw0,
                           const float* __restrict__ sc0, u16* __restrict__ W1t)
{
  int idx = blockIdx.x*256 + threadIdx.x;
  if (idx >= 512*1152) return;
  int o = idx/1152, k = idx%1152;
  float v;
  if (k < 128) v = bw0[o*128+k];
  else { int i=(k-128)>>3, c=(k-128)&7; v = sw0[(o*128+i)*8+c]*sc0[o*128+i]; }
  W1t[idx]=f2bf(v);
}
__global__ void k_pack_w2t(const float* __restrict__ bw1, const float* __restrict__ sw1,
                           const float* __restrict__ sc1, u16* __restrict__ W2t)
{
  int idx = blockIdx.x*256 + threadIdx.x;
  if (idx >= 128*4608) return;
  int o = idx/4608, k = idx%4608;
  float v;
  if (k < 512) v = bw1[o*512+k];
  else { int i=(k-512)>>3, c=(k-512)&7; v = sw1[(o*512+i)*8+c]*sc1[o*512+i]; }
  W2t[idx]=f2bf(v);
}

extern "C" void kernel_launch(void* const* d_in, const int* in_sizes, int n_in,
                              void* d_out, int out_size, void* d_ws, size_t ws_size,
                              hipStream_t stream)
{
  (void)in_sizes; (void)n_in; (void)out_size; (void)ws_size;
  const float* x5d   =(const float*)d_in[0];
  const float* ln1_g =(const float*)d_in[1];
  const float* ln1_b =(const float*)d_in[2];
  const float* ln2_g =(const float*)d_in[3];
  const float* ln2_b =(const float*)d_in[4];
  const float* ln3_g =(const float*)d_in[5];
  const float* ln3_b =(const float*)d_in[6];
  const float* ln4_g =(const float*)d_in[7];
  const float* ln4_b =(const float*)d_in[8];
  const float* temp  =(const float*)d_in[9];
  const float* qkv_w =(const float*)d_in[10];
  const float* qkv_b =(const float*)d_in[11];
  const float* dw_w  =(const float*)d_in[12];
  const float* dw_b  =(const float*)d_in[13];
  const float* po_w  =(const float*)d_in[14];
  const float* po_b  =(const float*)d_in[15];
  const float* f1_ng =(const float*)d_in[16];
  const float* f1_nb =(const float*)d_in[17];
  const float* f1_bw0=(const float*)d_in[18];
  const float* f1_sw0=(const float*)d_in[19];
  const float* f1_sc0=(const float*)d_in[20];
  const float* f1_bw1=(const float*)d_in[21];
  const float* f1_sw1=(const float*)d_in[22];
  const float* f1_sc1=(const float*)d_in[23];
  const float* f2_ng =(const float*)d_in[24];
  const float* f2_nb =(const float*)d_in[25];
  const float* f2_bw0=(const float*)d_in[26];
  const float* f2_sw0=(const float*)d_in[27];
  const float* f2_sc0=(const float*)d_in[28];
  const float* f2_bw1=(const float*)d_in[29];
  const float* f2_sw1=(const float*)d_in[30];
  const float* f2_sc1=(const float*)d_in[31];
  const float* in_w  =(const float*)d_in[32];
  const float* xp_w  =(const float*)d_in[33];
  const float* dt_w  =(const float*)d_in[34];
  const float* dt_b  =(const float*)d_in[35];
  const float* A_log =(const float*)d_in[36];
  const float* Dp    =(const float*)d_in[37];
  const float* out_w =(const float*)d_in[38];
  const float* cx_w  =(const float*)d_in[39];
  const float* cz_w  =(const float*)d_in[40];
  float* out = (float*)d_out;

  const size_t T = 18432;   // B*N tokens
  char* wsb = (char*)d_ws;
  size_t off = 0;
  auto alloc = [&](size_t bytes)->void* {
    void* p = wsb + off; off += (bytes + 255) & ~(size_t)255; return p;
  };
  float* x_t    = (float*)alloc(T*128*4);
  char*  scrA   = (char*) alloc(38*1024*1024);   // shared scratch region
  float* ssS    = (float*)alloc((512+8192+8192)*4);
  float* t_t    = (float*)alloc(T*128*4);        // reused as m_t
  u16*   A1     = (u16*)  alloc(T*1152*2);
  u16*   hbuf   = (u16*)  alloc(T*512*2);
  float* xtr    = (float*)alloc(T*128*4);
  u16*   xm     = (u16*)  alloc(T*128*2);
  float* xl     = (float*)alloc(T*64*4);
  float* delta  = (float*)alloc(T*64*4);
  float* Bm     = (float*)alloc(T*8*4);
  float* Cm     = (float*)alloc(T*8*4);
  u16*   A_out  = (u16*)  alloc(T*128*2);
  float* cP     = (float*)alloc(2*96*512*4);
  float* cS     = (float*)alloc(2*96*512*4);
  float* cI     = (float*)alloc(2*96*512*4);
  float* sfin   = (float*)alloc(T*128*4);
  u16* qkvw_bf  = (u16*)alloc(384*128*2);
  u16* pow_bf   = (u16*)alloc(128*128*2);
  u16* inw_bf   = (u16*)alloc(128*128*2);
  u16* outw_bf  = (u16*)alloc(128*128*2);
  u16* W1t_a    = (u16*)alloc(512*1152*2);
  u16* W2t_a    = (u16*)alloc(128*4608*2);
  u16* W1t_b    = (u16*)alloc(512*1152*2);
  u16* W2t_b    = (u16*)alloc(128*4608*2);
  float* Aneg   = (float*)alloc(512*4);
  float* ss = ssS;
  float* S  = ssS + 512;
  float* attnP = ssS + 512 + 8192;
  // scratch-region sub-allocations (lifetimes disjoint):
  u16*   ln1_t  = (u16*)(scrA);                              // 4.7 MB
  u16*   qkv_tb = (u16*)(scrA + 4718592);                    // 14.2 MB
  u16*   qkvd   = (u16*)(scrA + 4718592 + 14155776);         // 14.2 MB
  u16*   attnout= (u16*)(scrA + 4718592 + 2*14155776);       // 4.7 MB
  float* part   = (float*)scrA;    // 4 x T*128 f32 = 37.7 MB (FKAN split-K partials)
  float* xz     = (float*)scrA;    // T*128 f32 (mamba, disjoint from partial use)
  float* m_t    = t_t;

  // ---- weight prep ----
  k_pack_w1t<<<2304,256,0,stream>>>(f1_bw0, f1_sw0, f1_sc0, W1t_a);
  k_pack_w1t<<<2304,256,0,stream>>>(f2_bw0, f2_sw0, f2_sc0, W1t_b);
  k_pack_w2t<<<2304,256,0,stream>>>(f1_bw1, f1_sw1, f1_sc1, W2t_a);
  k_pack_w2t<<<2304,256,0,stream>>>(f2_bw1, f2_sw1, f2_sc1, W2t_b);
  k_prep<<<420,256,0,stream>>>(qkv_w, po_w, in_w, out_w, A_log,
      qkvw_bf, pow_bf, inw_bf, outw_bf, Aneg, ssS, 512+8192);

  // ---- attention ----
  k_ln1_trans<<<dim3(144,2),256,0,stream>>>(x5d, x_t, ln1_t, ln1_g, ln1_b);
  gemm64<0,true><<<dim3(3,288,1),256,0,stream>>>(ln1_t, qkvw_bf, qkv_tb,
      18432, 384, 128, 2, 0, qkv_b, nullptr);
  k_dwconv<<<dim3(144,6,2),256,0,stream>>>(qkv_tb, qkvd, dw_w, dw_b);
  k_normsum<<<dim3(72,2),256,0,stream>>>(qkvd, ss);
  k_qk<<<dim3(72,4,2),256,0,stream>>>(qkvd, ss, S);
  k_softmax<<<8,32,0,stream>>>(S, attnP, temp);
  k_av<<<dim3(36,4,2),256,0,stream>>>(qkvd, attnP, attnout);
  gemm64<0,false><<<dim3(1,288,1),256,0,stream>>>(attnout, pow_bf, t_t,
      18432, 128, 128, 2, 0, po_b, x_t);                 // t = x + attn(ln1(x))

  // ---- FKAN 1 ----
  k_ln_double_expand<<<4608,256,0,stream>>>(t_t, A1, ln2_g, ln2_b, f1_ng, f1_nb);
  gemm64<0,true><<<dim3(4,288,1),256,0,stream>>>(A1, W1t_a, hbuf,
      18432, 512, 1152, 18, 0, nullptr, nullptr);
  gemm64<512,false><<<dim3(1,288,4),256,0,stream>>>(hbuf, W2t_a, part,
      18432, 128, 4608, 18, 1, nullptr, nullptr);
  k_reduce4_ln<<<2304,256,0,stream>>>((const float4*)part, (const float4*)t_t,
      (const float4*)x_t, (float4*)xtr, xm, ln3_g, ln3_b, (int)(T*128/4));
      // x_tr = t + x + kan2 ; xm = LN3(x_tr) bf16

  // ---- Mamba ----
  gemm64<0,false><<<dim3(1,288,1),256,0,stream>>>(xm, inw_bf, xz,
      18432, 128, 128, 2, 0, nullptr, nullptr);
  k_mamba_pre<<<4608,256,0,stream>>>(xz, xl, delta, Bm, Cm, A_out,
      cx_w, cz_w, xp_w, dt_w, dt_b);
  k_scan1<<<dim3(96,2),512,0,stream>>>(delta, Bm, xl, Aneg, cP, cS);
  k_scan2<<<2,512,0,stream>>>(cP, cS, cI);
  k_scan3<<<dim3(96,2),512,0,stream>>>(delta, Bm, Cm, xl, Aneg, Dp, cI, A_out);
  gemm64<0,false><<<dim3(1,288,1),256,0,stream>>>(A_out, outw_bf, m_t,
      18432, 128, 128, 2, 0, nullptr, xtr);              // m = mamba + x_tr

  // ---- FKAN 2 ----
  k_ln_double_expand<<<4608,256,0,stream>>>(m_t, A1, ln4_g, ln4_b, f2_ng, f2_nb);
  gemm64<0,true><<<dim3(4,288,1),256,0,stream>>>(A1, W1t_b, hbuf,
      18432, 512, 1152, 18, 0, nullptr, nullptr);
  gemm64<512,false><<<dim3(1,288,4),256,0,stream>>>(hbuf, W2t_b, part,
      18432, 128, 4608, 18, 1, nullptr, nullptr);
  k_reduce4<<<2304,256,0,stream>>>((const float4*)part, (const float4*)m_t,
      (const float4*)xtr, (float4*)sfin, (int)(T*128/4)); // out = m + x_tr + kan2

  k_transpose_out<<<dim3(144,2),256,0,stream>>>(sfin, out);
}

// Round 7
// 535.149 us; speedup vs baseline: 1.0532x; 1.0134x over previous
//
#include <hip/hip_runtime.h>

typedef unsigned short u16;
typedef __attribute__((ext_vector_type(8))) short bh8;   // 8 x bf16 (4 VGPRs)
typedef __attribute__((ext_vector_type(4))) float f4;    // MFMA accumulator

#define DI __device__ __forceinline__

DI u16 f2bf(float f){ unsigned u=__float_as_uint(f); u += 0x7fffu + ((u>>16)&1u); return (u16)(u>>16); }
DI float bf2f(u16 u){ return __uint_as_float(((unsigned)u)<<16); }
DI float silu_f(float x){ return x/(1.f+__expf(-x)); }

DI void gld16(const u16* g, u16* l){
  __builtin_amdgcn_global_load_lds((const __attribute__((address_space(1))) void*)g,
                                   (__attribute__((address_space(3))) void*)l, 16, 0, 0);
}

// uniform cubic B-spline bases on grid [-2.2 : 0.4 : 2.2], 8 output bases (branchless,
// used only in the A1 materialization kernel where VALU cost is minor).
DI void bspline8(float x, float* v){
  float u = x*2.5f + 5.5f;           // (x + 2.2)/0.4
  #pragma unroll
  for (int j=0;j<8;j++){
    float a  = fabsf(u - (float)(j+2));
    float t1 = fmaxf(2.f-a, 0.f);
    float t2 = fmaxf(1.f-a, 0.f);
    v[j] = t1*t1*t1*(1.f/6.f) - t2*t2*t2*(2.f/3.f);
  }
}

// ---------------- GEMM (64x128 tile, 4 waves): C = A(MxK) * Bt(NxK)^T ----------------
// Wave w owns rows 0..63 x cols w*32..w*32+31, 4x2 acc. BK=64.
// LDS: sB(128x64) | sA(64x64) | dump slot. 16B chunks XOR-swizzled (chunk c of row r
// at c^(r&7)); global_load_lds lanes fetch permuted chunks so swizzle is free.
// KAN_H>0: A generated from h (M x KAN_H bf16): cols [0,KAN_H)=silu(h), rest=spline
// via zero-fill + 4-nonzero-weight scatter (measured fastest vs branchless-8: the
// scatter's ~3.3M conflict-cycles (~5us) < branchless's extra ~25% VALU (~10us) [r4/r6 A/B]).
// OUT_BF16: bf16 output staged via LDS -> 256B-contiguous stores (no RMW
// amplification [r5/r6 verified]). Else f32 direct (+bias/R1); split!=0 -> C += z*M*N.
template<int KAN_H, bool OUT_BF16>
__global__ __launch_bounds__(256, 6)
void gemm64(const void* __restrict__ Asrc, const u16* __restrict__ Bt,
            void* __restrict__ Cout, int M, int N, int K, int ktiles_per_z,
            int split, const float* __restrict__ bias, const float* __restrict__ R1)
{
  __shared__ __align__(128) u16 smem[12296];  // sB[0..8192) sA[8192..12288) dump[12288..)
  u16* const sB = smem;
  u16* const sA = smem + 8192;
  const int m0 = blockIdx.y * 64;
  const int n0 = blockIdx.x * 128;
  const int ktiles = K >> 6;
  int kt0 = blockIdx.z * ktiles_per_z;
  int kt1 = kt0 + ktiles_per_z; if (kt1 > ktiles) kt1 = ktiles;
  const int t = threadIdx.x;
  const int wave = t >> 6, lane = t & 63;
  const int lr = lane & 15, lq = lane >> 4;
  const int lr8 = lane >> 3, lc8 = lane & 7;
  const int swz8 = lc8 ^ lr8;      // swizzled global chunk for this lane (row&7 == lr8)
  f4 acc[4][2];
  f4 z4 = {0.f,0.f,0.f,0.f};
  #pragma unroll
  for (int i=0;i<4;i++){ acc[i][0]=z4; acc[i][1]=z4; }

  for (int kt = kt0; kt < kt1; ++kt) {
    int k0 = kt << 6;
    // stage Bt tile (128 rows) via async global->LDS, swizzled
    {
      const u16* Bp = Bt + (size_t)n0 * K + k0;
      #pragma unroll
      for (int it=0; it<4; ++it) {
        int r = it*32 + wave*8;
        gld16(Bp + (size_t)(r + lr8) * K + swz8*8, &sB[r*64]);
      }
    }
    // stage A tile (64 rows)
    if (KAN_H == 0) {
      const u16* Ap = (const u16*)Asrc + (size_t)m0 * K + k0;
      #pragma unroll
      for (int it=0; it<2; ++it) {
        int r = it*32 + wave*8;
        gld16(Ap + (size_t)(r + lr8) * K + swz8*8, &sA[r*64]);
      }
    } else {
      const u16* hsrc = (const u16*)Asrc;
      if (k0 < KAN_H) {
        // silu region: 64 rows x 64 cols = 512 chunks of 8
        #pragma unroll
        for (int it=0; it<2; ++it) {
          int chunk = t + it*256;
          int r = chunk >> 3, ck = chunk & 7;
          const u16* src = hsrc + (size_t)(m0+r)*KAN_H + k0 + ck*8;
          ushort4 a = *(const ushort4*)src;
          ushort4 b2 = *(const ushort4*)(src+4);
          alignas(16) u16 o[8];
          o[0]=f2bf(silu_f(bf2f(a.x))); o[1]=f2bf(silu_f(bf2f(a.y)));
          o[2]=f2bf(silu_f(bf2f(a.z))); o[3]=f2bf(silu_f(bf2f(a.w)));
          o[4]=f2bf(silu_f(bf2f(b2.x))); o[5]=f2bf(silu_f(bf2f(b2.y)));
          o[6]=f2bf(silu_f(bf2f(b2.z))); o[7]=f2bf(silu_f(bf2f(b2.w)));
          *(float4*)(&sA[r*64 + (ck ^ (r&7))*8]) = *(const float4*)o;
        }
      } else {
        // spline region: (row, feature) -> 8 bases, only 4 nonzero
        int i0 = (k0 - KAN_H) >> 3;
        const float4 zf4 = make_float4(0.f,0.f,0.f,0.f);
        #pragma unroll
        for (int it=0; it<2; ++it) {
          int pair = t + it*256;
          int r = pair >> 3, ii = pair & 7;
          int base = r*64 + (ii ^ (r&7))*8;
          *(float4*)(&sA[base]) = zf4;             // zero-fill the 8 bases
          float x = bf2f(hsrc[(size_t)(m0+r)*KAN_H + i0 + ii]);
          float u = x*2.5f + 5.5f;
          bool valid = (u >= 0.f) & (u < 11.f);
          float uc = fminf(fmaxf(u, 0.f), 10.999f);
          int m = (int)uc;
          float tt = uc - (float)m;
          float omt = 1.f - tt, t2 = tt*tt, t3 = t2*tt;
          float w0 = omt*omt*omt*(1.f/6.f);
          float w3 = t3*(1.f/6.f);
          float w1 = 0.5f*t3 - t2 + (2.f/3.f);
          float w2 = 1.f - w0 - w1 - w3;
          float ws[4] = {w0, w1, w2, w3};
          int c0 = m - 3;
          #pragma unroll
          for (int j=0;j<4;j++){
            int c = c0 + j;
            bool ok = valid & ((unsigned)c < 8u);
            int off = ok ? (base + c) : 4096;     // dump slot (sA[4096] = smem[12288])
            sA[off] = f2bf(ws[j]);
          }
        }
      }
    }
    __syncthreads();
    #pragma unroll
    for (int kk=0; kk<64; kk+=32) {
      const int c0k = kk >> 3;
      bh8 af[4], bfr[2];
      #pragma unroll
      for (int i=0;i<4;i++) {
        int row = i*16 + lr;
        af[i] = *(const bh8*)(&sA[row*64 + ((c0k+lq) ^ (row&7))*8]);
      }
      #pragma unroll
      for (int j=0;j<2;j++) {
        int row = wave*32 + j*16 + lr;
        bfr[j] = *(const bh8*)(&sB[row*64 + ((c0k+lq) ^ (row&7))*8]);
      }
      #pragma unroll
      for (int i=0;i<4;i++)
        #pragma unroll
        for (int j=0;j<2;j++)
          acc[i][j] = __builtin_amdgcn_mfma_f32_16x16x32_bf16(af[i], bfr[j], acc[i][j], 0, 0, 0);
    }
    __syncthreads();
  }
  // epilogue: C/D layout col=lane&15, row=(lane>>4)*4+reg
  if (OUT_BF16) {
    // stage bf16 tile (64 x 128, stride 136) in LDS -> 256B-contiguous stores
    u16* Cb = (u16*)Cout;
    #pragma unroll
    for (int i=0;i<4;i++) {
      #pragma unroll
      for (int j=0;j<2;j++) {
        int col = wave*32 + j*16 + lr;
        float bv = bias ? bias[n0 + col] : 0.f;
        #pragma unroll
        for (int r4=0;r4<4;r4++) {
          int row = i*16 + lq*4 + r4;
          smem[row*136 + col] = f2bf(acc[i][j][r4] + bv);
        }
      }
    }
    __syncthreads();
    #pragma unroll
    for (int it=0; it<4; ++it) {
      int idx = t + it*256;
      int row = idx >> 4, seg = idx & 15;
      *(float4*)(Cb + (size_t)(m0+row)*N + n0 + seg*8) =
          *(const float4*)&smem[row*136 + seg*8];
    }
  } else {
    float* Cf = (float*)Cout;
    if (split) Cf += (size_t)blockIdx.z * M * N;
    #pragma unroll
    for (int i=0;i<4;i++) {
      int row = m0 + i*16 + lq*4;
      #pragma unroll
      for (int j=0;j<2;j++) {
        int col = n0 + wave*32 + j*16 + lr;
        float bv = bias ? bias[col] : 0.f;
        #pragma unroll
        for (int r4=0;r4<4;r4++) {
          size_t idx = (size_t)(row + r4) * N + col;
          float v = acc[i][j][r4] + bv;
          if (R1) v += R1[idx];
          Cf[idx] = v;
        }
      }
    }
  }
}

// ---------------- transpose + LN1: x5d (B,C,N) -> x_t (B,N,C) f32 and ln1_t bf16 ----------------
__global__ __launch_bounds__(256) void k_ln1_trans(const float* __restrict__ x5d,
    float* __restrict__ x_t, u16* __restrict__ ln1_t,
    const float* __restrict__ g, const float* __restrict__ bv)
{
  __shared__ float tile[128*65];
  __shared__ float red_s[256], red_q[256];
  __shared__ float st_mu[64], st_rs[64];
  int b = blockIdx.y, n0 = blockIdx.x * 64;
  int j = threadIdx.x & 63, part = threadIdx.x >> 6;
  for (int cc=0; cc<32; ++cc) {
    int c = part*32 + cc;
    tile[c*65 + j] = x5d[((size_t)b*128 + c)*9216 + n0 + j];
  }
  __syncthreads();
  float s=0.f, s2=0.f;
  for (int cc=0; cc<32; ++cc) {
    float v = tile[(part*32+cc)*65 + j];
    s += v; s2 += v*v;
  }
  red_s[threadIdx.x]=s; red_q[threadIdx.x]=s2;
  __syncthreads();
  if (threadIdx.x < 64) {
    int jj = threadIdx.x;
    float ts = red_s[jj]+red_s[jj+64]+red_s[jj+128]+red_s[jj+192];
    float tq = red_q[jj]+red_q[jj+64]+red_q[jj+128]+red_q[jj+192];
    float mu = ts*(1.f/128.f);
    st_mu[jj]=mu;
    st_rs[jj]=rsqrtf(tq*(1.f/128.f) - mu*mu + 1e-5f);
  }
  __syncthreads();
  for (int it=0; it<32; ++it) {
    int idx = threadIdx.x + it*256;
    int tok = idx >> 7, c = idx & 127;
    float v = tile[c*65 + tok];
    size_t a = ((size_t)b*9216 + n0 + tok)*128 + c;
    x_t[a] = v;
    ln1_t[a] = f2bf((v - st_mu[tok])*st_rs[tok]*g[c] + bv[c]);
  }
}

// ---------------- double LN + KAN expansion: writes A1 (T x 1152 bf16) ----------------
__global__ void k_ln_double_expand(const float* __restrict__ in, u16* __restrict__ A1,
    const float* __restrict__ g1, const float* __restrict__ b1,
    const float* __restrict__ g2, const float* __restrict__ b2)
{
  int tok = blockIdx.x*4 + (threadIdx.x>>6);
  int lane = threadIdx.x & 63;
  const float* row = in + (size_t)tok*128;
  float v0=row[lane], v1=row[lane+64];
  float s=v0+v1, s2=v0*v0+v1*v1;
  #pragma unroll
  for (int o=1;o<64;o<<=1){ s += __shfl_xor(s,o); s2 += __shfl_xor(s2,o); }
  float mu=s*(1.f/128.f);
  float rs=rsqrtf(s2*(1.f/128.f)-mu*mu+1e-5f);
  float y0=(v0-mu)*rs*g1[lane]+b1[lane];
  float y1=(v1-mu)*rs*g1[lane+64]+b1[lane+64];
  s=y0+y1; s2=y0*y0+y1*y1;
  #pragma unroll
  for (int o=1;o<64;o<<=1){ s += __shfl_xor(s,o); s2 += __shfl_xor(s2,o); }
  mu=s*(1.f/128.f);
  rs=rsqrtf(s2*(1.f/128.f)-mu*mu+1e-5f);
  y0=(y0-mu)*rs*g2[lane]+b2[lane];
  y1=(y1-mu)*rs*g2[lane+64]+b2[lane+64];
  u16* arow = A1 + (size_t)tok*1152;
  arow[lane]    = f2bf(silu_f(y0));
  arow[lane+64] = f2bf(silu_f(y1));
  float w[8]; alignas(16) u16 o8[8];
  bspline8(y0, w);
  #pragma unroll
  for (int j=0;j<8;j++) o8[j]=f2bf(w[j]);
  *(float4*)(&arow[128 + lane*8]) = *(const float4*)o8;
  bspline8(y1, w);
  #pragma unroll
  for (int j=0;j<8;j++) o8[j]=f2bf(w[j]);
  *(float4*)(&arow[128 + (lane+64)*8]) = *(const float4*)o8;
}

// ---------------- depthwise 3x3 conv, token-major, bf16 in -> bf16 out, + bias ----------------
__global__ __launch_bounds__(256) void k_dwconv(const u16* __restrict__ qkv_t,
    u16* __restrict__ qkvd, const float* __restrict__ dw_w, const float* __restrict__ dw_b)
{
  __shared__ float lt[100*68];
  int tile = blockIdx.x; int th=(tile/12)*8, tw=(tile%12)*8;
  int cg = blockIdx.y, b = blockIdx.z;
  int t = threadIdx.x;
  for (int pp=0; pp<7; ++pp) {
    int pos = pp*16 + (t>>4);
    if (pos < 100) {
      int ih = th + pos/10 - 1, iw = tw + pos%10 - 1;
      int c4 = (t & 15)*4;
      float4 v = make_float4(0.f,0.f,0.f,0.f);
      if (ih>=0 && ih<96 && iw>=0 && iw<96) {
        ushort4 raw = *(const ushort4*)&qkv_t[(((size_t)b*9216) + ih*96 + iw)*384 + cg*64 + c4];
        v = make_float4(bf2f(raw.x), bf2f(raw.y), bf2f(raw.z), bf2f(raw.w));
      }
      *(float4*)&lt[pos*68 + c4] = v;
    }
  }
  __syncthreads();
  int ch = t & 63, gch = cg*64 + ch;
  float w[9];
  #pragma unroll
  for (int k=0;k<9;k++) w[k]=dw_w[gch*9+k];
  float bias = dw_b[gch];
  for (int pp=0; pp<16; ++pp) {
    int pos = (t>>6) + pp*4;
    int oh = pos>>3, ow = pos&7;
    float acc = bias;
    #pragma unroll
    for (int di=0; di<3; ++di)
      #pragma unroll
      for (int dj=0; dj<3; ++dj)
        acc += lt[((oh+di)*10 + ow+dj)*68 + ch] * w[di*3+dj];
    qkvd[(((size_t)b*9216) + (th+oh)*96 + tw+ow)*384 + gch] = f2bf(acc);
  }
}

// ---------------- sum of squares over n for q,k channels (c = 0..255) ----------------
__global__ void k_normsum(const u16* __restrict__ qkvd, float* __restrict__ ss)
{
  int b = blockIdx.y, n0 = blockIdx.x*128;
  int c = threadIdx.x;
  float acc=0.f;
  for (int i=0;i<128;++i){
    float v = bf2f(qkvd[((size_t)b*9216 + n0+i)*384 + c]);
    acc += v*v;
  }
  atomicAdd(&ss[b*256 + c], acc);
}

// ---------------- partial q@k^T with normalization, atomic into S ----------------
__global__ __launch_bounds__(256) void k_qk(const u16* __restrict__ qkvd,
    const float* __restrict__ ss, float* __restrict__ S)
{
  __shared__ float ql[128][32];
  __shared__ float kl[128][32];
  int nc=blockIdx.x, h=blockIdx.y, b=blockIdx.z;
  int t = threadIdx.x;
  int r = t>>1, half = t&1;
  size_t rowa = ((size_t)b*9216 + nc*128 + r)*384 + (half?128:0) + h*32;
  #pragma unroll
  for (int cc=0; cc<32; ++cc) {
    float v = bf2f(qkvd[rowa + cc]);
    if (half) kl[r][cc]=v; else ql[r][cc]=v;
  }
  __syncthreads();
  int i0 = (t>>4)*2, j0 = (t&15)*2;
  float a00=0.f,a01=0.f,a10=0.f,a11=0.f;
  for (int n=0;n<128;++n){
    float2 qv = *(const float2*)&ql[n][i0];
    float2 kv = *(const float2*)&kl[n][j0];
    a00 += qv.x*kv.x; a01 += qv.x*kv.y;
    a10 += qv.y*kv.x; a11 += qv.y*kv.y;
  }
  const float* ssb = ss + b*256;
  float rq0 = 1.f/fmaxf(sqrtf(ssb[h*32+i0]),1e-12f);
  float rq1 = 1.f/fmaxf(sqrtf(ssb[h*32+i0+1]),1e-12f);
  float rk0 = 1.f/fmaxf(sqrtf(ssb[128+h*32+j0]),1e-12f);
  float rk1 = 1.f/fmaxf(sqrtf(ssb[128+h*32+j0+1]),1e-12f);
  float* Sp = S + ((size_t)(b*4+h))*1024;
  atomicAdd(&Sp[i0*32+j0],     a00*rq0*rk0);
  atomicAdd(&Sp[i0*32+j0+1],   a01*rq0*rk1);
  atomicAdd(&Sp[(i0+1)*32+j0], a10*rq1*rk0);
  atomicAdd(&Sp[(i0+1)*32+j0+1], a11*rq1*rk1);
}

// ---------------- softmax over 32 cols per row, with per-head temp ----------------
__global__ void k_softmax(const float* __restrict__ S, float* __restrict__ attnP,
                          const float* __restrict__ temp)
{
  int bh = blockIdx.x; int h = bh & 3;
  int i = threadIdx.x;
  const float* row = S + (size_t)bh*1024 + i*32;
  float tp = temp[h];
  float vals[32]; float mx = -1e30f;
  #pragma unroll
  for (int j=0;j<32;++j){ float v=row[j]*tp; vals[j]=v; mx=fmaxf(mx,v); }
  float sum=0.f;
  #pragma unroll
  for (int j=0;j<32;++j){ vals[j]=__expf(vals[j]-mx); sum+=vals[j]; }
  float inv=1.f/sum;
  float* out = attnP + (size_t)bh*1024 + i*32;
  #pragma unroll
  for (int j=0;j<32;++j) out[j]=vals[j]*inv;
}

// ---------------- out = attn @ v, token-major bf16 out ----------------
__global__ __launch_bounds__(256) void k_av(const u16* __restrict__ qkvd,
    const float* __restrict__ attnP, u16* __restrict__ attnout)
{
  __shared__ float at[1024];
  int b=blockIdx.z, h=blockIdx.y;
  int n = blockIdx.x*256 + threadIdx.x;
  #pragma unroll
  for (int it=0;it<4;++it)
    at[threadIdx.x + it*256] = attnP[((size_t)(b*4+h))*1024 + threadIdx.x + it*256];
  __syncthreads();
  const u16* vrow = &qkvd[((size_t)b*9216 + n)*384 + 256 + h*32];
  float acc[32];
  #pragma unroll
  for (int i=0;i<32;++i) acc[i]=0.f;
  #pragma unroll 4
  for (int j=0;j<32;++j){
    float vj = bf2f(vrow[j]);
    #pragma unroll
    for (int i=0;i<32;++i) acc[i] += at[i*32+j]*vj;
  }
  u16* orow = &attnout[((size_t)b*9216 + n)*128 + h*32];
  #pragma unroll
  for (int i=0;i<32;++i) orow[i] = f2bf(acc[i]);
}

// ---------------- out = R1 + R2 + sum of 4 split-K partials ----------------
__global__ void k_reduce4(const float4* __restrict__ P, const float4* __restrict__ R1,
                          const float4* __restrict__ R2, float4* __restrict__ o, int n4)
{
  int i = blockIdx.x*256 + threadIdx.x;
  if (i<n4){
    float4 a=P[i], b=P[i+n4], c=P[i+2*n4], d=P[i+3*n4], r=R1[i], s=R2[i];
    o[i]=make_float4(a.x+b.x+c.x+d.x+r.x+s.x, a.y+b.y+c.y+d.y+r.y+s.y,
                     a.z+b.z+c.z+d.z+r.z+s.z, a.w+b.w+c.w+d.w+r.w+s.w);
  }
}

// ---------------- fused: xtr = R1+R2+4 partials ; xm = LN(xtr) bf16 ----------------
__global__ void k_reduce4_ln(const float4* __restrict__ P, const float4* __restrict__ R1,
    const float4* __restrict__ R2, float4* __restrict__ xtr, u16* __restrict__ xm,
    const float* __restrict__ g, const float* __restrict__ bv, int n4)
{
  int i = blockIdx.x*256 + threadIdx.x;
  int q = i & 31;
  float4 a=P[i], b=P[i+n4], c=P[i+2*n4], d=P[i+3*n4], r=R1[i], s=R2[i];
  float4 v=make_float4(a.x+b.x+c.x+d.x+r.x+s.x, a.y+b.y+c.y+d.y+r.y+s.y,
                       a.z+b.z+c.z+d.z+r.z+s.z, a.w+b.w+c.w+d.w+r.w+s.w);
  xtr[i]=v;
  float s1 = v.x+v.y+v.z+v.w;
  float s2 = v.x*v.x+v.y*v.y+v.z*v.z+v.w*v.w;
  #pragma unroll
  for (int o=1;o<32;o<<=1){ s1 += __shfl_xor(s1,o); s2 += __shfl_xor(s2,o); }
  float mu = s1*(1.f/128.f);
  float rs = rsqrtf(s2*(1.f/128.f)-mu*mu+1e-5f);
  float4 g4 = *(const float4*)(g + q*4);
  float4 b4 = *(const float4*)(bv + q*4);
  ushort4 o4;
  o4.x = f2bf((v.x-mu)*rs*g4.x + b4.x);
  o4.y = f2bf((v.y-mu)*rs*g4.y + b4.y);
  o4.z = f2bf((v.z-mu)*rs*g4.z + b4.z);
  o4.w = f2bf((v.w-mu)*rs*g4.w + b4.w);
  ((ushort4*)xm)[i] = o4;
}

// ---------------- fused misc prep: weight bf16 casts + Aneg + zeroing ----------------
__global__ void k_prep(const float* __restrict__ qkv_w, const float* __restrict__ po_w,
    const float* __restrict__ in_w, const float* __restrict__ out_w,
    const float* __restrict__ A_log, u16* __restrict__ qkvw_bf, u16* __restrict__ pow_bf,
    u16* __restrict__ inw_bf, u16* __restrict__ outw_bf, float* __restrict__ Aneg,
    float* __restrict__ zbuf, int nz)
{
  int i = blockIdx.x*256 + threadIdx.x;
  if (i < 49152) { qkvw_bf[i] = f2bf(qkv_w[i]); return; }
  i -= 49152;
  if (i < 16384) { pow_bf[i] = f2bf(po_w[i]); return; }
  i -= 16384;
  if (i < 16384) { inw_bf[i] = f2bf(in_w[i]); return; }
  i -= 16384;
  if (i < 16384) { outw_bf[i] = f2bf(out_w[i]); return; }
  i -= 16384;
  if (i < 512) { Aneg[i] = -__expf(A_log[i]); return; }
  i -= 512;
  if (i < nz) zbuf[i] = 0.f;
}

// ---------------- mamba pre: conv1d+silu for x/z, x_proj, delta ----------------
__global__ __launch_bounds__(256) void k_mamba_pre(const float* __restrict__ xz,
    float* __restrict__ xl, float* __restrict__ delta,
    float* __restrict__ Bm, float* __restrict__ Cm, u16* __restrict__ A_out,
    const float* __restrict__ cxw, const float* __restrict__ czw,
    const float* __restrict__ xpw, const float* __restrict__ dtw, const float* __restrict__ dtb)
{
  __shared__ float xls[4][64];
  __shared__ float xds[4][24];
  int w = threadIdx.x>>6;
  int tok = blockIdx.x*4 + w;
  int lane = threadIdx.x & 63;
  int l = tok % 9216;
  size_t base = (size_t)tok*128;
  float xm1 = (l>0)?     xz[base-128+lane]    : 0.f;
  float x0  =            xz[base+lane];
  float xp1 = (l<9215)?  xz[base+128+lane]    : 0.f;
  float zm1 = (l>0)?     xz[base-128+64+lane] : 0.f;
  float z0  =            xz[base+64+lane];
  float zp1 = (l<9215)?  xz[base+128+64+lane] : 0.f;
  float xc = silu_f(cxw[lane*3]*xm1 + cxw[lane*3+1]*x0 + cxw[lane*3+2]*xp1);
  float zc = silu_f(czw[lane*3]*zm1 + czw[lane*3+1]*z0 + czw[lane*3+2]*zp1);
  xl[(size_t)tok*64+lane] = xc;
  A_out[(size_t)tok*128 + 64 + lane] = f2bf(zc);
  xls[w][lane] = xc;
  __syncthreads();
  if (lane < 24) {
    float s=0.f;
    #pragma unroll 8
    for (int c=0;c<64;++c) s += xls[w][c]*xpw[lane*64+c];
    xds[w][lane]=s;
  }
  __syncthreads();
  float dacc = dtb[lane];
  #pragma unroll
  for (int r=0;r<8;++r) dacc += xds[w][r]*dtw[lane*8+r];
  delta[(size_t)tok*64+lane] = (dacc>20.f)? dacc : log1pf(__expf(dacc));
  if (lane<8)       Bm[(size_t)tok*8+lane]   = xds[w][8+lane];
  else if (lane<16) Cm[(size_t)tok*8+lane-8] = xds[w][16+lane-8];
}

// ---------------- chunked scan ----------------
__global__ __launch_bounds__(512) void k_scan1(const float* __restrict__ delta,
    const float* __restrict__ Bm, const float* __restrict__ xl,
    const float* __restrict__ Aneg, float* __restrict__ cP, float* __restrict__ cS)
{
  int b=blockIdx.y, ch=blockIdx.x;
  int t=threadIdx.x; int d=t>>3, n=t&7;
  float An = Aneg[d*8+n];
  float P=1.f, S=0.f;
  int l0 = ch*96;
  #pragma unroll 8
  for (int i=0;i<96;++i){
    size_t s = (size_t)b*9216 + l0+i;
    float del = delta[s*64+d];
    float a = __expf(del*An);
    float dbu = del * Bm[s*8+n] * xl[s*64+d];
    P *= a; S = fmaf(a,S,dbu);
  }
  size_t o = ((size_t)(b*96+ch))*512 + t;
  cP[o]=P; cS[o]=S;
}

__global__ __launch_bounds__(512) void k_scan2(const float* __restrict__ cP,
    const float* __restrict__ cS, float* __restrict__ cI)
{
  int b=blockIdx.x; int t=threadIdx.x;
  float carry=0.f;
  #pragma unroll 4
  for (int c=0;c<96;++c){
    size_t o = ((size_t)(b*96+c))*512 + t;
    cI[o]=carry;
    carry = fmaf(cP[o], carry, cS[o]);
  }
}

__global__ __launch_bounds__(512) void k_scan3(const float* __restrict__ delta,
    const float* __restrict__ Bm, const float* __restrict__ Cm,
    const float* __restrict__ xl, const float* __restrict__ Aneg,
    const float* __restrict__ Dp, const float* __restrict__ cI, u16* __restrict__ A_out)
{
  int b=blockIdx.y, ch=blockIdx.x;
  int t=threadIdx.x; int d=t>>3, n=t&7;
  float An = Aneg[d*8+n];
  float h = cI[((size_t)(b*96+ch))*512 + t];
  float Dd = Dp[d];
  int l0 = ch*96;
  #pragma unroll 4
  for (int i=0;i<96;++i){
    size_t s = (size_t)b*9216 + l0+i;
    float del = delta[s*64+d];
    float a = __expf(del*An);
    float xv = xl[s*64+d];
    h = fmaf(a, h, del * Bm[s*8+n] * xv);
    float contrib = h * Cm[s*8+n];
    contrib += __shfl_xor(contrib,1);
    contrib += __shfl_xor(contrib,2);
    contrib += __shfl_xor(contrib,4);
    if (n==0) A_out[s*128 + d] = f2bf(contrib + xv*Dd);
  }
}

// ---------------- final transpose (B,N,C) -> (B,C,N) ----------------
__global__ __launch_bounds__(256) void k_transpose_out(const float* __restrict__ sfin,
                                                       float* __restrict__ out)
{
  __shared__ float tile[128*65];
  int b=blockIdx.y, n0=blockIdx.x*64;
  for (int it=0;it<32;++it){
    int idx = threadIdx.x + it*256;
    int tok = idx>>7, c = idx&127;
    tile[c*65+tok] = sfin[((size_t)b*9216 + n0+tok)*128 + c];
  }
  __syncthreads();
  int j = threadIdx.x & 63, part = threadIdx.x>>6;
  for (int cc=0;cc<32;++cc){
    int c = part*32+cc;
    out[((size_t)b*128 + c)*9216 + n0 + j] = tile[c*65 + j];
  }
}

// ---------------- weight packers ----------------
__global__ void k_pack_w1t(const float* __restrict__ bw0, const float* __restrict__ sw0,
                           const float* __restrict__ sc0, u16* __restrict__ W1t)
{
  int idx = blockIdx.x*256 + threadIdx.x;
  if (idx >= 512*1152) return;
  int o = idx/1152, k = idx%1152;
  float v;
  if (k < 128) v = bw0[o*128+k];
  else { int i=(k-128)>>3, c=(k-128)&7; v = sw0[(o*128+i)*8+c]*sc0[o*128+i]; }
  W1t[idx]=f2bf(v);
}
__global__ void k_pack_w2t(const float* __restrict__ bw1, const float* __restrict__ sw1,
                           const float* __restrict__ sc1, u16* __restrict__ W2t)
{
  int idx = blockIdx.x*256 + threadIdx.x;
  if (idx >= 128*4608) return;
  int o = idx/4608, k = idx%4608;
  float v;
  if (k < 512) v = bw1[o*512+k];
  else { int i=(k-512)>>3, c=(k-512)&7; v = sw1[(o*512+i)*8+c]*sc1[o*512+i]; }
  W2t[idx]=f2bf(v);
}

extern "C" void kernel_launch(void* const* d_in, const int* in_sizes, int n_in,
                              void* d_out, int out_size, void* d_ws, size_t ws_size,
                              hipStream_t stream)
{
  (void)in_sizes; (void)n_in; (void)out_size; (void)ws_size;
  const float* x5d   =(const float*)d_in[0];
  const float* ln1_g =(const float*)d_in[1];
  const float* ln1_b =(const float*)d_in[2];
  const float* ln2_g =(const float*)d_in[3];
  const float* ln2_b =(const float*)d_in[4];
  const float* ln3_g =(const float*)d_in[5];
  const float* ln3_b =(const float*)d_in[6];
  const float* ln4_g =(const float*)d_in[7];
  const float* ln4_b =(const float*)d_in[8];
  const float* temp  =(const float*)d_in[9];
  const float* qkv_w =(const float*)d_in[10];
  const float* qkv_b =(const float*)d_in[11];
  const float* dw_w  =(const float*)d_in[12];
  const float* dw_b  =(const float*)d_in[13];
  const float* po_w  =(const float*)d_in[14];
  const float* po_b  =(const float*)d_in[15];
  const float* f1_ng =(const float*)d_in[16];
  const float* f1_nb =(const float*)d_in[17];
  const float* f1_bw0=(const float*)d_in[18];
  const float* f1_sw0=(const float*)d_in[19];
  const float* f1_sc0=(const float*)d_in[20];
  const float* f1_bw1=(const float*)d_in[21];
  const float* f1_sw1=(const float*)d_in[22];
  const float* f1_sc1=(const float*)d_in[23];
  const float* f2_ng =(const float*)d_in[24];
  const float* f2_nb =(const float*)d_in[25];
  const float* f2_bw0=(const float*)d_in[26];
  const float* f2_sw0=(const float*)d_in[27];
  const float* f2_sc0=(const float*)d_in[28];
  const float* f2_bw1=(const float*)d_in[29];
  const float* f2_sw1=(const float*)d_in[30];
  const float* f2_sc1=(const float*)d_in[31];
  const float* in_w  =(const float*)d_in[32];
  const float* xp_w  =(const float*)d_in[33];
  const float* dt_w  =(const float*)d_in[34];
  const float* dt_b  =(const float*)d_in[35];
  const float* A_log =(const float*)d_in[36];
  const float* Dp    =(const float*)d_in[37];
  const float* out_w =(const float*)d_in[38];
  const float* cx_w  =(const float*)d_in[39];
  const float* cz_w  =(const float*)d_in[40];
  float* out = (float*)d_out;

  const size_t T = 18432;   // B*N tokens
  char* wsb = (char*)d_ws;
  size_t off = 0;
  auto alloc = [&](size_t bytes)->void* {
    void* p = wsb + off; off += (bytes + 255) & ~(size_t)255; return p;
  };
  float* x_t    = (float*)alloc(T*128*4);
  char*  scrA   = (char*) alloc(38*1024*1024);   // shared scratch region
  float* ssS    = (float*)alloc((512+8192+8192)*4);
  float* t_t    = (float*)alloc(T*128*4);        // reused as m_t
  u16*   A1     = (u16*)  alloc(T*1152*2);
  u16*   hbuf   = (u16*)  alloc(T*512*2);
  float* xtr    = (float*)alloc(T*128*4);
  u16*   xm     = (u16*)  alloc(T*128*2);
  float* xl     = (float*)alloc(T*64*4);
  float* delta  = (float*)alloc(T*64*4);
  float* Bm     = (float*)alloc(T*8*4);
  float* Cm     = (float*)alloc(T*8*4);
  u16*   A_out  = (u16*)  alloc(T*128*2);
  float* cP     = (float*)alloc(2*96*512*4);
  float* cS     = (float*)alloc(2*96*512*4);
  float* cI     = (float*)alloc(2*96*512*4);
  float* sfin   = (float*)alloc(T*128*4);
  u16* qkvw_bf  = (u16*)alloc(384*128*2);
  u16* pow_bf   = (u16*)alloc(128*128*2);
  u16* inw_bf   = (u16*)alloc(128*128*2);
  u16* outw_bf  = (u16*)alloc(128*128*2);
  u16* W1t_a    = (u16*)alloc(512*1152*2);
  u16* W2t_a    = (u16*)alloc(128*4608*2);
  u16* W1t_b    = (u16*)alloc(512*1152*2);
  u16* W2t_b    = (u16*)alloc(128*4608*2);
  float* Aneg   = (float*)alloc(512*4);
  float* ss = ssS;
  float* S  = ssS + 512;
  float* attnP = ssS + 512 + 8192;
  // scratch-region sub-allocations (lifetimes disjoint):
  u16*   ln1_t  = (u16*)(scrA);                              // 4.7 MB
  u16*   qkv_tb = (u16*)(scrA + 4718592);                    // 14.2 MB
  u16*   qkvd   = (u16*)(scrA + 4718592 + 14155776);         // 14.2 MB
  u16*   attnout= (u16*)(scrA + 4718592 + 2*14155776);       // 4.7 MB
  float* part   = (float*)scrA;    // 4 x T*128 f32 = 37.7 MB (FKAN split-K partials)
  float* xz     = (float*)scrA;    // T*128 f32 (mamba, disjoint from partial use)
  float* m_t    = t_t;

  // ---- weight prep ----
  k_pack_w1t<<<2304,256,0,stream>>>(f1_bw0, f1_sw0, f1_sc0, W1t_a);
  k_pack_w1t<<<2304,256,0,stream>>>(f2_bw0, f2_sw0, f2_sc0, W1t_b);
  k_pack_w2t<<<2304,256,0,stream>>>(f1_bw1, f1_sw1, f1_sc1, W2t_a);
  k_pack_w2t<<<2304,256,0,stream>>>(f2_bw1, f2_sw1, f2_sc1, W2t_b);
  k_prep<<<420,256,0,stream>>>(qkv_w, po_w, in_w, out_w, A_log,
      qkvw_bf, pow_bf, inw_bf, outw_bf, Aneg, ssS, 512+8192);

  // ---- attention ----
  k_ln1_trans<<<dim3(144,2),256,0,stream>>>(x5d, x_t, ln1_t, ln1_g, ln1_b);
  gemm64<0,true><<<dim3(3,288,1),256,0,stream>>>(ln1_t, qkvw_bf, qkv_tb,
      18432, 384, 128, 2, 0, qkv_b, nullptr);
  k_dwconv<<<dim3(144,6,2),256,0,stream>>>(qkv_tb, qkvd, dw_w, dw_b);
  k_normsum<<<dim3(72,2),256,0,stream>>>(qkvd, ss);
  k_qk<<<dim3(72,4,2),256,0,stream>>>(qkvd, ss, S);
  k_softmax<<<8,32,0,stream>>>(S, attnP, temp);
  k_av<<<dim3(36,4,2),256,0,stream>>>(qkvd, attnP, attnout);
  gemm64<0,false><<<dim3(1,288,1),256,0,stream>>>(attnout, pow_bf, t_t,
      18432, 128, 128, 2, 0, po_b, x_t);                 // t = x + attn(ln1(x))

  // ---- FKAN 1 ----
  k_ln_double_expand<<<4608,256,0,stream>>>(t_t, A1, ln2_g, ln2_b, f1_ng, f1_nb);
  gemm64<0,true><<<dim3(4,288,1),256,0,stream>>>(A1, W1t_a, hbuf,
      18432, 512, 1152, 18, 0, nullptr, nullptr);
  gemm64<512,false><<<dim3(1,288,4),256,0,stream>>>(hbuf, W2t_a, part,
      18432, 128, 4608, 18, 1, nullptr, nullptr);
  k_reduce4_ln<<<2304,256,0,stream>>>((const float4*)part, (const float4*)t_t,
      (const float4*)x_t, (float4*)xtr, xm, ln3_g, ln3_b, (int)(T*128/4));
      // x_tr = t + x + kan2 ; xm = LN3(x_tr) bf16

  // ---- Mamba ----
  gemm64<0,false><<<dim3(1,288,1),256,0,stream>>>(xm, inw_bf, xz,
      18432, 128, 128, 2, 0, nullptr, nullptr);
  k_mamba_pre<<<4608,256,0,stream>>>(xz, xl, delta, Bm, Cm, A_out,
      cx_w, cz_w, xp_w, dt_w, dt_b);
  k_scan1<<<dim3(96,2),512,0,stream>>>(delta, Bm, xl, Aneg, cP, cS);
  k_scan2<<<2,512,0,stream>>>(cP, cS, cI);
  k_scan3<<<dim3(96,2),512,0,stream>>>(delta, Bm, Cm, xl, Aneg, Dp, cI, A_out);
  gemm64<0,false><<<dim3(1,288,1),256,0,stream>>>(A_out, outw_bf, m_t,
      18432, 128, 128, 2, 0, nullptr, xtr);              // m = mamba + x_tr

  // ---- FKAN 2 ----
  k_ln_double_expand<<<4608,256,0,stream>>>(m_t, A1, ln4_g, ln4_b, f2_ng, f2_nb);
  gemm64<0,true><<<dim3(4,288,1),256,0,stream>>>(A1, W1t_b, hbuf,
      18432, 512, 1152, 18, 0, nullptr, nullptr);
  gemm64<512,false><<<dim3(1,288,4),256,0,stream>>>(hbuf, W2t_b, part,
      18432, 128, 4608, 18, 1, nullptr, nullptr);
  k_reduce4<<<2304,256,0,stream>>>((const float4*)part, (const float4*)m_t,
      (const float4*)xtr, (float4*)sfin, (int)(T*128/4)); // out = m + x_tr + kan2

  k_transpose_out<<<dim3(144,2),256,0,stream>>>(sfin, out);
}

// Round 8
// 513.778 us; speedup vs baseline: 1.0971x; 1.0416x over previous
//
#include <hip/hip_runtime.h>

typedef unsigned short u16;
typedef __attribute__((ext_vector_type(8))) short bh8;   // 8 x bf16 (4 VGPRs)
typedef __attribute__((ext_vector_type(4))) float f4;    // MFMA accumulator

#define DI __device__ __forceinline__

DI u16 f2bf(float f){ unsigned u=__float_as_uint(f); u += 0x7fffu + ((u>>16)&1u); return (u16)(u>>16); }
DI float bf2f(u16 u){ return __uint_as_float(((unsigned)u)<<16); }
DI float silu_f(float x){ return x/(1.f+__expf(-x)); }

DI void gld16(const u16* g, u16* l){
  __builtin_amdgcn_global_load_lds((const __attribute__((address_space(1))) void*)g,
                                   (__attribute__((address_space(3))) void*)l, 16, 0, 0);
}

// uniform cubic B-spline bases on grid [-2.2 : 0.4 : 2.2], 8 output bases (branchless,
// used only in the A1 materialization kernel where VALU cost is minor).
DI void bspline8(float x, float* v){
  float u = x*2.5f + 5.5f;           // (x + 2.2)/0.4
  #pragma unroll
  for (int j=0;j<8;j++){
    float a  = fabsf(u - (float)(j+2));
    float t1 = fmaxf(2.f-a, 0.f);
    float t2 = fmaxf(1.f-a, 0.f);
    v[j] = t1*t1*t1*(1.f/6.f) - t2*t2*t2*(2.f/3.f);
  }
}

// ---------------- GEMM (64x128 tile, 4 waves): C = A(MxK) * Bt(NxK)^T ----------------
// Wave w owns rows 0..63 x cols w*32..w*32+31, 4x2 acc. BK=64. lb(256,4) = measured best
// [r4 48.6us vs r7 lb6 54.4us: lb6 raised L2 pressure, FETCH 19->25MB].
// LDS: sB(128x64) | sA(64x64) | dump. 16B chunks XOR-swizzled (chunk c of row r at
// c^(r&7)); global_load_lds lanes fetch permuted chunks so swizzle is free.
// KAN_H>0: A generated from h (M x KAN_H bf16): cols [0,KAN_H)=silu(h), rest=spline
// via zero-fill + 4-nonzero-weight scatter (scatter ~5us conflicts < branchless ~10us
// VALU [r4/r6 A/B]).
// OUT_BF16: bf16 output staged via LDS -> 256B full-cacheline stores (no RMW
// amplification [r5-r7 verified: f32 half-line stores showed WRITE 42.6 vs 36.9MB]).
// split!=0 offsets output by blockIdx.z*M*N (works in both OUT paths).
template<int KAN_H, bool OUT_BF16>
__global__ __launch_bounds__(256, 4)
void gemm64(const void* __restrict__ Asrc, const u16* __restrict__ Bt,
            void* __restrict__ Cout, int M, int N, int K, int ktiles_per_z,
            int split, const float* __restrict__ bias, const float* __restrict__ R1)
{
  __shared__ __align__(128) u16 smem[12296];  // sB[0..8192) sA[8192..12288) dump[12288..)
  u16* const sB = smem;
  u16* const sA = smem + 8192;
  const int m0 = blockIdx.y * 64;
  const int n0 = blockIdx.x * 128;
  const int ktiles = K >> 6;
  int kt0 = blockIdx.z * ktiles_per_z;
  int kt1 = kt0 + ktiles_per_z; if (kt1 > ktiles) kt1 = ktiles;
  const int t = threadIdx.x;
  const int wave = t >> 6, lane = t & 63;
  const int lr = lane & 15, lq = lane >> 4;
  const int lr8 = lane >> 3, lc8 = lane & 7;
  const int swz8 = lc8 ^ lr8;      // swizzled global chunk for this lane (row&7 == lr8)
  f4 acc[4][2];
  f4 z4 = {0.f,0.f,0.f,0.f};
  #pragma unroll
  for (int i=0;i<4;i++){ acc[i][0]=z4; acc[i][1]=z4; }

  for (int kt = kt0; kt < kt1; ++kt) {
    int k0 = kt << 6;
    // stage Bt tile (128 rows) via async global->LDS, swizzled
    {
      const u16* Bp = Bt + (size_t)n0 * K + k0;
      #pragma unroll
      for (int it=0; it<4; ++it) {
        int r = it*32 + wave*8;
        gld16(Bp + (size_t)(r + lr8) * K + swz8*8, &sB[r*64]);
      }
    }
    // stage A tile (64 rows)
    if (KAN_H == 0) {
      const u16* Ap = (const u16*)Asrc + (size_t)m0 * K + k0;
      #pragma unroll
      for (int it=0; it<2; ++it) {
        int r = it*32 + wave*8;
        gld16(Ap + (size_t)(r + lr8) * K + swz8*8, &sA[r*64]);
      }
    } else {
      const u16* hsrc = (const u16*)Asrc;
      if (k0 < KAN_H) {
        // silu region: 64 rows x 64 cols = 512 chunks of 8
        #pragma unroll
        for (int it=0; it<2; ++it) {
          int chunk = t + it*256;
          int r = chunk >> 3, ck = chunk & 7;
          const u16* src = hsrc + (size_t)(m0+r)*KAN_H + k0 + ck*8;
          ushort4 a = *(const ushort4*)src;
          ushort4 b2 = *(const ushort4*)(src+4);
          alignas(16) u16 o[8];
          o[0]=f2bf(silu_f(bf2f(a.x))); o[1]=f2bf(silu_f(bf2f(a.y)));
          o[2]=f2bf(silu_f(bf2f(a.z))); o[3]=f2bf(silu_f(bf2f(a.w)));
          o[4]=f2bf(silu_f(bf2f(b2.x))); o[5]=f2bf(silu_f(bf2f(b2.y)));
          o[6]=f2bf(silu_f(bf2f(b2.z))); o[7]=f2bf(silu_f(bf2f(b2.w)));
          *(float4*)(&sA[r*64 + (ck ^ (r&7))*8]) = *(const float4*)o;
        }
      } else {
        // spline region: (row, feature) -> 8 bases, only 4 nonzero
        int i0 = (k0 - KAN_H) >> 3;
        const float4 zf4 = make_float4(0.f,0.f,0.f,0.f);
        #pragma unroll
        for (int it=0; it<2; ++it) {
          int pair = t + it*256;
          int r = pair >> 3, ii = pair & 7;
          int base = r*64 + (ii ^ (r&7))*8;
          *(float4*)(&sA[base]) = zf4;             // zero-fill the 8 bases
          float x = bf2f(hsrc[(size_t)(m0+r)*KAN_H + i0 + ii]);
          float u = x*2.5f + 5.5f;
          bool valid = (u >= 0.f) & (u < 11.f);
          float uc = fminf(fmaxf(u, 0.f), 10.999f);
          int m = (int)uc;
          float tt = uc - (float)m;
          float omt = 1.f - tt, t2 = tt*tt, t3 = t2*tt;
          float w0 = omt*omt*omt*(1.f/6.f);
          float w3 = t3*(1.f/6.f);
          float w1 = 0.5f*t3 - t2 + (2.f/3.f);
          float w2 = 1.f - w0 - w1 - w3;
          float ws[4] = {w0, w1, w2, w3};
          int c0 = m - 3;
          #pragma unroll
          for (int j=0;j<4;j++){
            int c = c0 + j;
            bool ok = valid & ((unsigned)c < 8u);
            int off = ok ? (base + c) : 4096;     // dump slot (sA[4096] = smem[12288])
            sA[off] = f2bf(ws[j]);
          }
        }
      }
    }
    __syncthreads();
    #pragma unroll
    for (int kk=0; kk<64; kk+=32) {
      const int c0k = kk >> 3;
      bh8 af[4], bfr[2];
      #pragma unroll
      for (int i=0;i<4;i++) {
        int row = i*16 + lr;
        af[i] = *(const bh8*)(&sA[row*64 + ((c0k+lq) ^ (row&7))*8]);
      }
      #pragma unroll
      for (int j=0;j<2;j++) {
        int row = wave*32 + j*16 + lr;
        bfr[j] = *(const bh8*)(&sB[row*64 + ((c0k+lq) ^ (row&7))*8]);
      }
      #pragma unroll
      for (int i=0;i<4;i++)
        #pragma unroll
        for (int j=0;j<2;j++)
          acc[i][j] = __builtin_amdgcn_mfma_f32_16x16x32_bf16(af[i], bfr[j], acc[i][j], 0, 0, 0);
    }
    __syncthreads();
  }
  // epilogue: C/D layout col=lane&15, row=(lane>>4)*4+reg
  if (OUT_BF16) {
    // stage bf16 tile (64 x 128, stride 136) in LDS -> 256B-contiguous stores
    u16* Cb = (u16*)Cout;
    if (split) Cb += (size_t)blockIdx.z * M * N;
    #pragma unroll
    for (int i=0;i<4;i++) {
      #pragma unroll
      for (int j=0;j<2;j++) {
        int col = wave*32 + j*16 + lr;
        float bv = bias ? bias[n0 + col] : 0.f;
        #pragma unroll
        for (int r4=0;r4<4;r4++) {
          int row = i*16 + lq*4 + r4;
          smem[row*136 + col] = f2bf(acc[i][j][r4] + bv);
        }
      }
    }
    __syncthreads();
    #pragma unroll
    for (int it=0; it<4; ++it) {
      int idx = t + it*256;
      int row = idx >> 4, seg = idx & 15;
      *(float4*)(Cb + (size_t)(m0+row)*N + n0 + seg*8) =
          *(const float4*)&smem[row*136 + seg*8];
    }
  } else {
    float* Cf = (float*)Cout;
    if (split) Cf += (size_t)blockIdx.z * M * N;
    #pragma unroll
    for (int i=0;i<4;i++) {
      int row = m0 + i*16 + lq*4;
      #pragma unroll
      for (int j=0;j<2;j++) {
        int col = n0 + wave*32 + j*16 + lr;
        float bv = bias ? bias[col] : 0.f;
        #pragma unroll
        for (int r4=0;r4<4;r4++) {
          size_t idx = (size_t)(row + r4) * N + col;
          float v = acc[i][j][r4] + bv;
          if (R1) v += R1[idx];
          Cf[idx] = v;
        }
      }
    }
  }
}

// ---------------- transpose + LN1: x5d (B,C,N) -> x_t (B,N,C) f32 and ln1_t bf16 ----------------
__global__ __launch_bounds__(256) void k_ln1_trans(const float* __restrict__ x5d,
    float* __restrict__ x_t, u16* __restrict__ ln1_t,
    const float* __restrict__ g, const float* __restrict__ bv)
{
  __shared__ float tile[128*65];
  __shared__ float red_s[256], red_q[256];
  __shared__ float st_mu[64], st_rs[64];
  int b = blockIdx.y, n0 = blockIdx.x * 64;
  int j = threadIdx.x & 63, part = threadIdx.x >> 6;
  for (int cc=0; cc<32; ++cc) {
    int c = part*32 + cc;
    tile[c*65 + j] = x5d[((size_t)b*128 + c)*9216 + n0 + j];
  }
  __syncthreads();
  float s=0.f, s2=0.f;
  for (int cc=0; cc<32; ++cc) {
    float v = tile[(part*32+cc)*65 + j];
    s += v; s2 += v*v;
  }
  red_s[threadIdx.x]=s; red_q[threadIdx.x]=s2;
  __syncthreads();
  if (threadIdx.x < 64) {
    int jj = threadIdx.x;
    float ts = red_s[jj]+red_s[jj+64]+red_s[jj+128]+red_s[jj+192];
    float tq = red_q[jj]+red_q[jj+64]+red_q[jj+128]+red_q[jj+192];
    float mu = ts*(1.f/128.f);
    st_mu[jj]=mu;
    st_rs[jj]=rsqrtf(tq*(1.f/128.f) - mu*mu + 1e-5f);
  }
  __syncthreads();
  for (int it=0; it<32; ++it) {
    int idx = threadIdx.x + it*256;
    int tok = idx >> 7, c = idx & 127;
    float v = tile[c*65 + tok];
    size_t a = ((size_t)b*9216 + n0 + tok)*128 + c;
    x_t[a] = v;
    ln1_t[a] = f2bf((v - st_mu[tok])*st_rs[tok]*g[c] + bv[c]);
  }
}

// ---------------- double LN + KAN expansion: writes A1 (T x 1152 bf16) ----------------
__global__ void k_ln_double_expand(const float* __restrict__ in, u16* __restrict__ A1,
    const float* __restrict__ g1, const float* __restrict__ b1,
    const float* __restrict__ g2, const float* __restrict__ b2)
{
  int tok = blockIdx.x*4 + (threadIdx.x>>6);
  int lane = threadIdx.x & 63;
  const float* row = in + (size_t)tok*128;
  float v0=row[lane], v1=row[lane+64];
  float s=v0+v1, s2=v0*v0+v1*v1;
  #pragma unroll
  for (int o=1;o<64;o<<=1){ s += __shfl_xor(s,o); s2 += __shfl_xor(s2,o); }
  float mu=s*(1.f/128.f);
  float rs=rsqrtf(s2*(1.f/128.f)-mu*mu+1e-5f);
  float y0=(v0-mu)*rs*g1[lane]+b1[lane];
  float y1=(v1-mu)*rs*g1[lane+64]+b1[lane+64];
  s=y0+y1; s2=y0*y0+y1*y1;
  #pragma unroll
  for (int o=1;o<64;o<<=1){ s += __shfl_xor(s,o); s2 += __shfl_xor(s2,o); }
  mu=s*(1.f/128.f);
  rs=rsqrtf(s2*(1.f/128.f)-mu*mu+1e-5f);
  y0=(y0-mu)*rs*g2[lane]+b2[lane];
  y1=(y1-mu)*rs*g2[lane+64]+b2[lane+64];
  u16* arow = A1 + (size_t)tok*1152;
  arow[lane]    = f2bf(silu_f(y0));
  arow[lane+64] = f2bf(silu_f(y1));
  float w[8]; alignas(16) u16 o8[8];
  bspline8(y0, w);
  #pragma unroll
  for (int j=0;j<8;j++) o8[j]=f2bf(w[j]);
  *(float4*)(&arow[128 + lane*8]) = *(const float4*)o8;
  bspline8(y1, w);
  #pragma unroll
  for (int j=0;j<8;j++) o8[j]=f2bf(w[j]);
  *(float4*)(&arow[128 + (lane+64)*8]) = *(const float4*)o8;
}

// ---------------- depthwise 3x3 conv + fused q/k sumsq (normsum) ----------------
__global__ __launch_bounds__(256) void k_dwconv(const u16* __restrict__ qkv_t,
    u16* __restrict__ qkvd, const float* __restrict__ dw_w, const float* __restrict__ dw_b,
    float* __restrict__ ss)
{
  __shared__ float lt[100*68];
  int tile = blockIdx.x; int th=(tile/12)*8, tw=(tile%12)*8;
  int cg = blockIdx.y, b = blockIdx.z;
  int t = threadIdx.x;
  for (int pp=0; pp<7; ++pp) {
    int pos = pp*16 + (t>>4);
    if (pos < 100) {
      int ih = th + pos/10 - 1, iw = tw + pos%10 - 1;
      int c4 = (t & 15)*4;
      float4 v = make_float4(0.f,0.f,0.f,0.f);
      if (ih>=0 && ih<96 && iw>=0 && iw<96) {
        ushort4 raw = *(const ushort4*)&qkv_t[(((size_t)b*9216) + ih*96 + iw)*384 + cg*64 + c4];
        v = make_float4(bf2f(raw.x), bf2f(raw.y), bf2f(raw.z), bf2f(raw.w));
      }
      *(float4*)&lt[pos*68 + c4] = v;
    }
  }
  __syncthreads();
  int ch = t & 63, gch = cg*64 + ch;
  float w[9];
  #pragma unroll
  for (int k=0;k<9;k++) w[k]=dw_w[gch*9+k];
  float bias = dw_b[gch];
  float sq = 0.f;
  for (int pp=0; pp<16; ++pp) {
    int pos = (t>>6) + pp*4;
    int oh = pos>>3, ow = pos&7;
    float acc = bias;
    #pragma unroll
    for (int di=0; di<3; ++di)
      #pragma unroll
      for (int dj=0; dj<3; ++dj)
        acc += lt[((oh+di)*10 + ow+dj)*68 + ch] * w[di*3+dj];
    sq += acc*acc;
    qkvd[(((size_t)b*9216) + (th+oh)*96 + tw+ow)*384 + gch] = f2bf(acc);
  }
  if (cg < 4) {     // q (cg 0,1) and k (cg 2,3) channels need sum-of-squares over n
    __syncthreads();
    lt[(t>>6)*64 + ch] = sq;
    __syncthreads();
    if (t < 64) {
      float s = lt[t] + lt[64+t] + lt[128+t] + lt[192+t];
      atomicAdd(&ss[b*256 + cg*64 + t], s);
    }
  }
}

// ---------------- partial q@k^T with normalization, atomic into S ----------------
__global__ __launch_bounds__(256) void k_qk(const u16* __restrict__ qkvd,
    const float* __restrict__ ss, float* __restrict__ S)
{
  __shared__ float ql[128][32];
  __shared__ float kl[128][32];
  int nc=blockIdx.x, h=blockIdx.y, b=blockIdx.z;
  int t = threadIdx.x;
  int r = t>>1, half = t&1;
  size_t rowa = ((size_t)b*9216 + nc*128 + r)*384 + (half?128:0) + h*32;
  #pragma unroll
  for (int cc=0; cc<32; ++cc) {
    float v = bf2f(qkvd[rowa + cc]);
    if (half) kl[r][cc]=v; else ql[r][cc]=v;
  }
  __syncthreads();
  int i0 = (t>>4)*2, j0 = (t&15)*2;
  float a00=0.f,a01=0.f,a10=0.f,a11=0.f;
  for (int n=0;n<128;++n){
    float2 qv = *(const float2*)&ql[n][i0];
    float2 kv = *(const float2*)&kl[n][j0];
    a00 += qv.x*kv.x; a01 += qv.x*kv.y;
    a10 += qv.y*kv.x; a11 += qv.y*kv.y;
  }
  const float* ssb = ss + b*256;
  float rq0 = 1.f/fmaxf(sqrtf(ssb[h*32+i0]),1e-12f);
  float rq1 = 1.f/fmaxf(sqrtf(ssb[h*32+i0+1]),1e-12f);
  float rk0 = 1.f/fmaxf(sqrtf(ssb[128+h*32+j0]),1e-12f);
  float rk1 = 1.f/fmaxf(sqrtf(ssb[128+h*32+j0+1]),1e-12f);
  float* Sp = S + ((size_t)(b*4+h))*1024;
  atomicAdd(&Sp[i0*32+j0],     a00*rq0*rk0);
  atomicAdd(&Sp[i0*32+j0+1],   a01*rq0*rk1);
  atomicAdd(&Sp[(i0+1)*32+j0], a10*rq1*rk0);
  atomicAdd(&Sp[(i0+1)*32+j0+1], a11*rq1*rk1);
}

// ---------------- softmax over 32 cols per row, with per-head temp ----------------
__global__ void k_softmax(const float* __restrict__ S, float* __restrict__ attnP,
                          const float* __restrict__ temp)
{
  int bh = blockIdx.x; int h = bh & 3;
  int i = threadIdx.x;
  const float* row = S + (size_t)bh*1024 + i*32;
  float tp = temp[h];
  float vals[32]; float mx = -1e30f;
  #pragma unroll
  for (int j=0;j<32;++j){ float v=row[j]*tp; vals[j]=v; mx=fmaxf(mx,v); }
  float sum=0.f;
  #pragma unroll
  for (int j=0;j<32;++j){ vals[j]=__expf(vals[j]-mx); sum+=vals[j]; }
  float inv=1.f/sum;
  float* out = attnP + (size_t)bh*1024 + i*32;
  #pragma unroll
  for (int j=0;j<32;++j) out[j]=vals[j]*inv;
}

// ---------------- out = attn @ v, token-major bf16 out ----------------
__global__ __launch_bounds__(256) void k_av(const u16* __restrict__ qkvd,
    const float* __restrict__ attnP, u16* __restrict__ attnout)
{
  __shared__ float at[1024];
  int b=blockIdx.z, h=blockIdx.y;
  int n = blockIdx.x*256 + threadIdx.x;
  #pragma unroll
  for (int it=0;it<4;++it)
    at[threadIdx.x + it*256] = attnP[((size_t)(b*4+h))*1024 + threadIdx.x + it*256];
  __syncthreads();
  const u16* vrow = &qkvd[((size_t)b*9216 + n)*384 + 256 + h*32];
  float acc[32];
  #pragma unroll
  for (int i=0;i<32;++i) acc[i]=0.f;
  #pragma unroll 4
  for (int j=0;j<32;++j){
    float vj = bf2f(vrow[j]);
    #pragma unroll
    for (int i=0;i<32;++i) acc[i] += at[i*32+j]*vj;
  }
  u16* orow = &attnout[((size_t)b*9216 + n)*128 + h*32];
  #pragma unroll
  for (int i=0;i<32;++i) orow[i] = f2bf(acc[i]);
}

// ---------------- fused: xtr = R1+R2+4 bf16 partials ; xm = LN(xtr) bf16 ----------------
__global__ void k_reduce4_ln(const ushort4* __restrict__ P, const float4* __restrict__ R1,
    const float4* __restrict__ R2, float4* __restrict__ xtr, u16* __restrict__ xm,
    const float* __restrict__ g, const float* __restrict__ bv, int n4)
{
  int i = blockIdx.x*256 + threadIdx.x;
  int q = i & 31;
  ushort4 a=P[i], b=P[i+n4], c=P[i+2*n4], d=P[i+3*n4];
  float4 r=R1[i], s=R2[i];
  float4 v=make_float4(bf2f(a.x)+bf2f(b.x)+bf2f(c.x)+bf2f(d.x)+r.x+s.x,
                       bf2f(a.y)+bf2f(b.y)+bf2f(c.y)+bf2f(d.y)+r.y+s.y,
                       bf2f(a.z)+bf2f(b.z)+bf2f(c.z)+bf2f(d.z)+r.z+s.z,
                       bf2f(a.w)+bf2f(b.w)+bf2f(c.w)+bf2f(d.w)+r.w+s.w);
  xtr[i]=v;
  float s1 = v.x+v.y+v.z+v.w;
  float s2 = v.x*v.x+v.y*v.y+v.z*v.z+v.w*v.w;
  #pragma unroll
  for (int o=1;o<32;o<<=1){ s1 += __shfl_xor(s1,o); s2 += __shfl_xor(s2,o); }
  float mu = s1*(1.f/128.f);
  float rs = rsqrtf(s2*(1.f/128.f)-mu*mu+1e-5f);
  float4 g4 = *(const float4*)(g + q*4);
  float4 b4 = *(const float4*)(bv + q*4);
  ushort4 o4;
  o4.x = f2bf((v.x-mu)*rs*g4.x + b4.x);
  o4.y = f2bf((v.y-mu)*rs*g4.y + b4.y);
  o4.z = f2bf((v.z-mu)*rs*g4.z + b4.z);
  o4.w = f2bf((v.w-mu)*rs*g4.w + b4.w);
  ((ushort4*)xm)[i] = o4;
}

// ---------------- fused final: out(B,C,N) = transpose(R1 + R2 + 4 bf16 partials) ------
__global__ __launch_bounds__(256) void k_reduce4_trans(const ushort4* __restrict__ P,
    const float4* __restrict__ R1, const float4* __restrict__ R2,
    float* __restrict__ out, int n4)
{
  __shared__ float tile[128*65];
  int b=blockIdx.y, n0=blockIdx.x*64;
  for (int it=0; it<8; ++it) {            // 64 tokens x 32 float4 = 2048
    int idx = threadIdx.x + it*256;
    int tok = idx >> 5, c4 = idx & 31;
    int gi = (b*9216 + n0 + tok)*32 + c4;
    ushort4 a=P[gi], bb=P[gi+n4], c=P[gi+2*n4], d=P[gi+3*n4];
    float4 r=R1[gi], s=R2[gi];
    tile[(c4*4+0)*65+tok] = bf2f(a.x)+bf2f(bb.x)+bf2f(c.x)+bf2f(d.x)+r.x+s.x;
    tile[(c4*4+1)*65+tok] = bf2f(a.y)+bf2f(bb.y)+bf2f(c.y)+bf2f(d.y)+r.y+s.y;
    tile[(c4*4+2)*65+tok] = bf2f(a.z)+bf2f(bb.z)+bf2f(c.z)+bf2f(d.z)+r.z+s.z;
    tile[(c4*4+3)*65+tok] = bf2f(a.w)+bf2f(bb.w)+bf2f(c.w)+bf2f(d.w)+r.w+s.w;
  }
  __syncthreads();
  int j = threadIdx.x & 63, part = threadIdx.x>>6;
  for (int cc=0;cc<32;++cc){
    int c = part*32+cc;
    out[((size_t)b*128 + c)*9216 + n0 + j] = tile[c*65 + j];
  }
}

// ---------------- one fused prep kernel: all weight packs + Aneg + zeroing ----------------
__global__ void k_pack_all(
    const float* __restrict__ f1_bw0, const float* __restrict__ f1_sw0, const float* __restrict__ f1_sc0,
    const float* __restrict__ f2_bw0, const float* __restrict__ f2_sw0, const float* __restrict__ f2_sc0,
    const float* __restrict__ f1_bw1, const float* __restrict__ f1_sw1, const float* __restrict__ f1_sc1,
    const float* __restrict__ f2_bw1, const float* __restrict__ f2_sw1, const float* __restrict__ f2_sc1,
    const float* __restrict__ qkv_w, const float* __restrict__ po_w,
    const float* __restrict__ in_w, const float* __restrict__ out_w,
    const float* __restrict__ A_log,
    u16* __restrict__ W1t_a, u16* __restrict__ W1t_b,
    u16* __restrict__ W2t_a, u16* __restrict__ W2t_b,
    u16* __restrict__ qkvw_bf, u16* __restrict__ pow_bf,
    u16* __restrict__ inw_bf, u16* __restrict__ outw_bf,
    float* __restrict__ Aneg, float* __restrict__ zbuf, int nz)
{
  int i = blockIdx.x*256 + threadIdx.x;
  const int NW1 = 512*1152, NW2 = 128*4608;
  if (i < NW1) {
    int o = i/1152, k = i%1152; float v;
    if (k < 128) v = f1_bw0[o*128+k];
    else { int f=(k-128)>>3, c=(k-128)&7; v = f1_sw0[(o*128+f)*8+c]*f1_sc0[o*128+f]; }
    W1t_a[i]=f2bf(v); return;
  }
  i -= NW1;
  if (i < NW1) {
    int o = i/1152, k = i%1152; float v;
    if (k < 128) v = f2_bw0[o*128+k];
    else { int f=(k-128)>>3, c=(k-128)&7; v = f2_sw0[(o*128+f)*8+c]*f2_sc0[o*128+f]; }
    W1t_b[i]=f2bf(v); return;
  }
  i -= NW1;
  if (i < NW2) {
    int o = i/4608, k = i%4608; float v;
    if (k < 512) v = f1_bw1[o*512+k];
    else { int f=(k-512)>>3, c=(k-512)&7; v = f1_sw1[(o*512+f)*8+c]*f1_sc1[o*512+f]; }
    W2t_a[i]=f2bf(v); return;
  }
  i -= NW2;
  if (i < NW2) {
    int o = i/4608, k = i%4608; float v;
    if (k < 512) v = f2_bw1[o*512+k];
    else { int f=(k-512)>>3, c=(k-512)&7; v = f2_sw1[(o*512+f)*8+c]*f2_sc1[o*512+f]; }
    W2t_b[i]=f2bf(v); return;
  }
  i -= NW2;
  if (i < 49152) { qkvw_bf[i] = f2bf(qkv_w[i]); return; }
  i -= 49152;
  if (i < 16384) { pow_bf[i] = f2bf(po_w[i]); return; }
  i -= 16384;
  if (i < 16384) { inw_bf[i] = f2bf(in_w[i]); return; }
  i -= 16384;
  if (i < 16384) { outw_bf[i] = f2bf(out_w[i]); return; }
  i -= 16384;
  if (i < 512) { Aneg[i] = -__expf(A_log[i]); return; }
  i -= 512;
  if (i < nz) zbuf[i] = 0.f;
}

// ---------------- mamba pre: conv1d+silu for x/z, x_proj, delta ----------------
__global__ __launch_bounds__(256) void k_mamba_pre(const float* __restrict__ xz,
    float* __restrict__ xl, float* __restrict__ delta,
    float* __restrict__ Bm, float* __restrict__ Cm, u16* __restrict__ A_out,
    const float* __restrict__ cxw, const float* __restrict__ czw,
    const float* __restrict__ xpw, const float* __restrict__ dtw, const float* __restrict__ dtb)
{
  __shared__ float xls[4][64];
  __shared__ float xds[4][24];
  int w = threadIdx.x>>6;
  int tok = blockIdx.x*4 + w;
  int lane = threadIdx.x & 63;
  int l = tok % 9216;
  size_t base = (size_t)tok*128;
  float xm1 = (l>0)?     xz[base-128+lane]    : 0.f;
  float x0  =            xz[base+lane];
  float xp1 = (l<9215)?  xz[base+128+lane]    : 0.f;
  float zm1 = (l>0)?     xz[base-128+64+lane] : 0.f;
  float z0  =            xz[base+64+lane];
  float zp1 = (l<9215)?  xz[base+128+64+lane] : 0.f;
  float xc = silu_f(cxw[lane*3]*xm1 + cxw[lane*3+1]*x0 + cxw[lane*3+2]*xp1);
  float zc = silu_f(czw[lane*3]*zm1 + czw[lane*3+1]*z0 + czw[lane*3+2]*zp1);
  xl[(size_t)tok*64+lane] = xc;
  A_out[(size_t)tok*128 + 64 + lane] = f2bf(zc);
  xls[w][lane] = xc;
  __syncthreads();
  if (lane < 24) {
    float s=0.f;
    #pragma unroll 8
    for (int c=0;c<64;++c) s += xls[w][c]*xpw[lane*64+c];
    xds[w][lane]=s;
  }
  __syncthreads();
  float dacc = dtb[lane];
  #pragma unroll
  for (int r=0;r<8;++r) dacc += xds[w][r]*dtw[lane*8+r];
  delta[(size_t)tok*64+lane] = (dacc>20.f)? dacc : log1pf(__expf(dacc));
  if (lane<8)       Bm[(size_t)tok*8+lane]   = xds[w][8+lane];
  else if (lane<16) Cm[(size_t)tok*8+lane-8] = xds[w][16+lane-8];
}

// ---------------- chunked scan ----------------
__global__ __launch_bounds__(512) void k_scan1(const float* __restrict__ delta,
    const float* __restrict__ Bm, const float* __restrict__ xl,
    const float* __restrict__ Aneg, float* __restrict__ cP, float* __restrict__ cS)
{
  int b=blockIdx.y, ch=blockIdx.x;
  int t=threadIdx.x; int d=t>>3, n=t&7;
  float An = Aneg[d*8+n];
  float P=1.f, S=0.f;
  int l0 = ch*96;
  #pragma unroll 8
  for (int i=0;i<96;++i){
    size_t s = (size_t)b*9216 + l0+i;
    float del = delta[s*64+d];
    float a = __expf(del*An);
    float dbu = del * Bm[s*8+n] * xl[s*64+d];
    P *= a; S = fmaf(a,S,dbu);
  }
  size_t o = ((size_t)(b*96+ch))*512 + t;
  cP[o]=P; cS[o]=S;
}

__global__ __launch_bounds__(512) void k_scan2(const float* __restrict__ cP,
    const float* __restrict__ cS, float* __restrict__ cI)
{
  int b=blockIdx.x; int t=threadIdx.x;
  float carry=0.f;
  #pragma unroll 4
  for (int c=0;c<96;++c){
    size_t o = ((size_t)(b*96+c))*512 + t;
    cI[o]=carry;
    carry = fmaf(cP[o], carry, cS[o]);
  }
}

__global__ __launch_bounds__(512) void k_scan3(const float* __restrict__ delta,
    const float* __restrict__ Bm, const float* __restrict__ Cm,
    const float* __restrict__ xl, const float* __restrict__ Aneg,
    const float* __restrict__ Dp, const float* __restrict__ cI, u16* __restrict__ A_out)
{
  int b=blockIdx.y, ch=blockIdx.x;
  int t=threadIdx.x; int d=t>>3, n=t&7;
  float An = Aneg[d*8+n];
  float h = cI[((size_t)(b*96+ch))*512 + t];
  float Dd = Dp[d];
  int l0 = ch*96;
  #pragma unroll 4
  for (int i=0;i<96;++i){
    size_t s = (size_t)b*9216 + l0+i;
    float del = delta[s*64+d];
    float a = __expf(del*An);
    float xv = xl[s*64+d];
    h = fmaf(a, h, del * Bm[s*8+n] * xv);
    float contrib = h * Cm[s*8+n];
    contrib += __shfl_xor(contrib,1);
    contrib += __shfl_xor(contrib,2);
    contrib += __shfl_xor(contrib,4);
    if (n==0) A_out[s*128 + d] = f2bf(contrib + xv*Dd);
  }
}

extern "C" void kernel_launch(void* const* d_in, const int* in_sizes, int n_in,
                              void* d_out, int out_size, void* d_ws, size_t ws_size,
                              hipStream_t stream)
{
  (void)in_sizes; (void)n_in; (void)out_size; (void)ws_size;
  const float* x5d   =(const float*)d_in[0];
  const float* ln1_g =(const float*)d_in[1];
  const float* ln1_b =(const float*)d_in[2];
  const float* ln2_g =(const float*)d_in[3];
  const float* ln2_b =(const float*)d_in[4];
  const float* ln3_g =(const float*)d_in[5];
  const float* ln3_b =(const float*)d_in[6];
  const float* ln4_g =(const float*)d_in[7];
  const float* ln4_b =(const float*)d_in[8];
  const float* temp  =(const float*)d_in[9];
  const float* qkv_w =(const float*)d_in[10];
  const float* qkv_b =(const float*)d_in[11];
  const float* dw_w  =(const float*)d_in[12];
  const float* dw_b  =(const float*)d_in[13];
  const float* po_w  =(const float*)d_in[14];
  const float* po_b  =(const float*)d_in[15];
  const float* f1_ng =(const float*)d_in[16];
  const float* f1_nb =(const float*)d_in[17];
  const float* f1_bw0=(const float*)d_in[18];
  const float* f1_sw0=(const float*)d_in[19];
  const float* f1_sc0=(const float*)d_in[20];
  const float* f1_bw1=(const float*)d_in[21];
  const float* f1_sw1=(const float*)d_in[22];
  const float* f1_sc1=(const float*)d_in[23];
  const float* f2_ng =(const float*)d_in[24];
  const float* f2_nb =(const float*)d_in[25];
  const float* f2_bw0=(const float*)d_in[26];
  const float* f2_sw0=(const float*)d_in[27];
  const float* f2_sc0=(const float*)d_in[28];
  const float* f2_bw1=(const float*)d_in[29];
  const float* f2_sw1=(const float*)d_in[30];
  const float* f2_sc1=(const float*)d_in[31];
  const float* in_w  =(const float*)d_in[32];
  const float* xp_w  =(const float*)d_in[33];
  const float* dt_w  =(const float*)d_in[34];
  const float* dt_b  =(const float*)d_in[35];
  const float* A_log =(const float*)d_in[36];
  const float* Dp    =(const float*)d_in[37];
  const float* out_w =(const float*)d_in[38];
  const float* cx_w  =(const float*)d_in[39];
  const float* cz_w  =(const float*)d_in[40];
  float* out = (float*)d_out;

  const size_t T = 18432;   // B*N tokens
  char* wsb = (char*)d_ws;
  size_t off = 0;
  auto alloc = [&](size_t bytes)->void* {
    void* p = wsb + off; off += (bytes + 255) & ~(size_t)255; return p;
  };
  float* x_t    = (float*)alloc(T*128*4);
  char*  scrA   = (char*) alloc(38*1024*1024);   // shared scratch region
  float* ssS    = (float*)alloc((512+8192+8192)*4);
  float* t_t    = (float*)alloc(T*128*4);        // reused as m_t
  u16*   A1     = (u16*)  alloc(T*1152*2);
  u16*   hbuf   = (u16*)  alloc(T*512*2);
  float* xtr    = (float*)alloc(T*128*4);
  u16*   xm     = (u16*)  alloc(T*128*2);
  float* xl     = (float*)alloc(T*64*4);
  float* delta  = (float*)alloc(T*64*4);
  float* Bm     = (float*)alloc(T*8*4);
  float* Cm     = (float*)alloc(T*8*4);
  u16*   A_out  = (u16*)  alloc(T*128*2);
  float* cP     = (float*)alloc(2*96*512*4);
  float* cS     = (float*)alloc(2*96*512*4);
  float* cI     = (float*)alloc(2*96*512*4);
  u16* qkvw_bf  = (u16*)alloc(384*128*2);
  u16* pow_bf   = (u16*)alloc(128*128*2);
  u16* inw_bf   = (u16*)alloc(128*128*2);
  u16* outw_bf  = (u16*)alloc(128*128*2);
  u16* W1t_a    = (u16*)alloc(512*1152*2);
  u16* W2t_a    = (u16*)alloc(128*4608*2);
  u16* W1t_b    = (u16*)alloc(512*1152*2);
  u16* W2t_b    = (u16*)alloc(128*4608*2);
  float* Aneg   = (float*)alloc(512*4);
  float* ss = ssS;
  float* S  = ssS + 512;
  float* attnP = ssS + 512 + 8192;
  // scratch-region sub-allocations (lifetimes disjoint):
  u16*   ln1_t  = (u16*)(scrA);                              // 4.7 MB
  u16*   qkv_tb = (u16*)(scrA + 4718592);                    // 14.2 MB
  u16*   qkvd   = (u16*)(scrA + 4718592 + 14155776);         // 14.2 MB
  u16*   attnout= (u16*)(scrA + 4718592 + 2*14155776);       // 4.7 MB
  u16*   partb  = (u16*)scrA;      // 4 x T*128 bf16 = 18.9 MB (FKAN split-K partials)
  float* xz     = (float*)scrA;    // T*128 f32 (mamba, disjoint from partial use)
  float* m_t    = t_t;
  const int n4 = (int)(T*128/4);

  // ---- all weight prep + zeroing in one kernel ----
  k_pack_all<<<9636,256,0,stream>>>(
      f1_bw0,f1_sw0,f1_sc0, f2_bw0,f2_sw0,f2_sc0,
      f1_bw1,f1_sw1,f1_sc1, f2_bw1,f2_sw1,f2_sc1,
      qkv_w, po_w, in_w, out_w, A_log,
      W1t_a, W1t_b, W2t_a, W2t_b,
      qkvw_bf, pow_bf, inw_bf, outw_bf, Aneg, ssS, 512+8192);

  // ---- attention ----
  k_ln1_trans<<<dim3(144,2),256,0,stream>>>(x5d, x_t, ln1_t, ln1_g, ln1_b);
  gemm64<0,true><<<dim3(3,288,1),256,0,stream>>>(ln1_t, qkvw_bf, qkv_tb,
      18432, 384, 128, 2, 0, qkv_b, nullptr);
  k_dwconv<<<dim3(144,6,2),256,0,stream>>>(qkv_tb, qkvd, dw_w, dw_b, ss);
  k_qk<<<dim3(72,4,2),256,0,stream>>>(qkvd, ss, S);
  k_softmax<<<8,32,0,stream>>>(S, attnP, temp);
  k_av<<<dim3(36,4,2),256,0,stream>>>(qkvd, attnP, attnout);
  gemm64<0,false><<<dim3(1,288,1),256,0,stream>>>(attnout, pow_bf, t_t,
      18432, 128, 128, 2, 0, po_b, x_t);                 // t = x + attn(ln1(x))

  // ---- FKAN 1 ----
  k_ln_double_expand<<<4608,256,0,stream>>>(t_t, A1, ln2_g, ln2_b, f1_ng, f1_nb);
  gemm64<0,true><<<dim3(4,288,1),256,0,stream>>>(A1, W1t_a, hbuf,
      18432, 512, 1152, 18, 0, nullptr, nullptr);
  gemm64<512,true><<<dim3(1,288,4),256,0,stream>>>(hbuf, W2t_a, partb,
      18432, 128, 4608, 18, 1, nullptr, nullptr);        // bf16 split-K partials
  k_reduce4_ln<<<2304,256,0,stream>>>((const ushort4*)partb, (const float4*)t_t,
      (const float4*)x_t, (float4*)xtr, xm, ln3_g, ln3_b, n4);
      // x_tr = t + x + kan2 ; xm = LN3(x_tr) bf16

  // ---- Mamba ----
  gemm64<0,false><<<dim3(1,288,1),256,0,stream>>>(xm, inw_bf, xz,
      18432, 128, 128, 2, 0, nullptr, nullptr);
  k_mamba_pre<<<4608,256,0,stream>>>(xz, xl, delta, Bm, Cm, A_out,
      cx_w, cz_w, xp_w, dt_w, dt_b);
  k_scan1<<<dim3(96,2),512,0,stream>>>(delta, Bm, xl, Aneg, cP, cS);
  k_scan2<<<2,512,0,stream>>>(cP, cS, cI);
  k_scan3<<<dim3(96,2),512,0,stream>>>(delta, Bm, Cm, xl, Aneg, Dp, cI, A_out);
  gemm64<0,false><<<dim3(1,288,1),256,0,stream>>>(A_out, outw_bf, m_t,
      18432, 128, 128, 2, 0, nullptr, xtr);              // m = mamba + x_tr

  // ---- FKAN 2 ----
  k_ln_double_expand<<<4608,256,0,stream>>>(m_t, A1, ln4_g, ln4_b, f2_ng, f2_nb);
  gemm64<0,true><<<dim3(4,288,1),256,0,stream>>>(A1, W1t_b, hbuf,
      18432, 512, 1152, 18, 0, nullptr, nullptr);
  gemm64<512,true><<<dim3(1,288,4),256,0,stream>>>(hbuf, W2t_b, partb,
      18432, 128, 4608, 18, 1, nullptr, nullptr);        // bf16 split-K partials
  k_reduce4_trans<<<dim3(144,2),256,0,stream>>>((const ushort4*)partb,
      (const float4*)m_t, (const float4*)xtr, out, n4);  // out = T(m + x_tr + kan2)
}

// Round 9
// 505.352 us; speedup vs baseline: 1.1153x; 1.0167x over previous
//
#include <hip/hip_runtime.h>

typedef unsigned short u16;
typedef __attribute__((ext_vector_type(8))) short bh8;   // 8 x bf16 (4 VGPRs)
typedef __attribute__((ext_vector_type(4))) float f4;    // MFMA accumulator

#define DI __device__ __forceinline__

DI u16 f2bf(float f){ unsigned u=__float_as_uint(f); u += 0x7fffu + ((u>>16)&1u); return (u16)(u>>16); }
DI float bf2f(u16 u){ return __uint_as_float(((unsigned)u)<<16); }
DI float silu_f(float x){ return x/(1.f+__expf(-x)); }

DI void gld16(const u16* g, u16* l){
  __builtin_amdgcn_global_load_lds((const __attribute__((address_space(1))) void*)g,
                                   (__attribute__((address_space(3))) void*)l, 16, 0, 0);
}

// uniform cubic B-spline bases on grid [-2.2 : 0.4 : 2.2], 8 output bases (branchless,
// used only in the A1 materialization kernel where VALU cost is minor).
DI void bspline8(float x, float* v){
  float u = x*2.5f + 5.5f;           // (x + 2.2)/0.4
  #pragma unroll
  for (int j=0;j<8;j++){
    float a  = fabsf(u - (float)(j+2));
    float t1 = fmaxf(2.f-a, 0.f);
    float t2 = fmaxf(1.f-a, 0.f);
    v[j] = t1*t1*t1*(1.f/6.f) - t2*t2*t2*(2.f/3.f);
  }
}

// ---------------- GEMM (64x128 tile, 4 waves): C = A(MxK) * Bt(NxK)^T ----------------
// Wave w owns rows 0..63 x cols w*32..w*32+31, 4x2 acc. BK=64. lb(256,4) measured best
// [r4 48.6us vs r7 lb6 54.4us: lb6 raised L2 pressure, FETCH 19->25MB].
// swz!=0: XCD-aware (bx,by) remap — all N-tiles sharing one A-row-block land on the
// same XCD (assuming round-robin workgroup->XCD), so the shared A-tile hits that
// XCD's L2 instead of being refetched into gridDim.x different L2s. Heuristic only.
// LDS: sB(128x64) | sA(64x64) | dump. 16B chunks XOR-swizzled (chunk c of row r at
// c^(r&7)); global_load_lds lanes fetch permuted chunks so swizzle is free.
// KAN_H>0: A generated from h (M x KAN_H bf16): cols [0,KAN_H)=silu(h), rest=spline
// via zero-fill + 4-nonzero-weight scatter (scatter ~5us conflicts < branchless ~10us
// VALU [r4/r6 A/B]).
// OUT_BF16: bf16 output staged via LDS -> 256B full-cacheline stores (no RMW
// amplification [r5-r8 verified]). split!=0 offsets output by blockIdx.z*M*N.
template<int KAN_H, bool OUT_BF16>
__global__ __launch_bounds__(256, 4)
void gemm64(const void* __restrict__ Asrc, const u16* __restrict__ Bt,
            void* __restrict__ Cout, int M, int N, int K, int ktiles_per_z,
            int split, int swz, const float* __restrict__ bias, const float* __restrict__ R1)
{
  __shared__ __align__(128) u16 smem[12296];  // sB[0..8192) sA[8192..12288) dump[12288..)
  u16* const sB = smem;
  u16* const sA = smem + 8192;
  int bx = blockIdx.x, by = blockIdx.y;
  if (swz) {
    const int NX = gridDim.x, NY = gridDim.y;
    int lin = bx + NX*by;
    int k8 = lin & 7, g = lin >> 3;
    by = k8*(NY>>3) + g/NX;
    bx = g%NX;
  }
  const int m0 = by * 64;
  const int n0 = bx * 128;
  const int ktiles = K >> 6;
  int kt0 = blockIdx.z * ktiles_per_z;
  int kt1 = kt0 + ktiles_per_z; if (kt1 > ktiles) kt1 = ktiles;
  const int t = threadIdx.x;
  const int wave = t >> 6, lane = t & 63;
  const int lr = lane & 15, lq = lane >> 4;
  const int lr8 = lane >> 3, lc8 = lane & 7;
  const int swz8 = lc8 ^ lr8;      // swizzled global chunk for this lane (row&7 == lr8)
  f4 acc[4][2];
  f4 z4 = {0.f,0.f,0.f,0.f};
  #pragma unroll
  for (int i=0;i<4;i++){ acc[i][0]=z4; acc[i][1]=z4; }

  for (int kt = kt0; kt < kt1; ++kt) {
    int k0 = kt << 6;
    // stage Bt tile (128 rows) via async global->LDS, swizzled
    {
      const u16* Bp = Bt + (size_t)n0 * K + k0;
      #pragma unroll
      for (int it=0; it<4; ++it) {
        int r = it*32 + wave*8;
        gld16(Bp + (size_t)(r + lr8) * K + swz8*8, &sB[r*64]);
      }
    }
    // stage A tile (64 rows)
    if (KAN_H == 0) {
      const u16* Ap = (const u16*)Asrc + (size_t)m0 * K + k0;
      #pragma unroll
      for (int it=0; it<2; ++it) {
        int r = it*32 + wave*8;
        gld16(Ap + (size_t)(r + lr8) * K + swz8*8, &sA[r*64]);
      }
    } else {
      const u16* hsrc = (const u16*)Asrc;
      if (k0 < KAN_H) {
        // silu region: 64 rows x 64 cols = 512 chunks of 8
        #pragma unroll
        for (int it=0; it<2; ++it) {
          int chunk = t + it*256;
          int r = chunk >> 3, ck = chunk & 7;
          const u16* src = hsrc + (size_t)(m0+r)*KAN_H + k0 + ck*8;
          ushort4 a = *(const ushort4*)src;
          ushort4 b2 = *(const ushort4*)(src+4);
          alignas(16) u16 o[8];
          o[0]=f2bf(silu_f(bf2f(a.x))); o[1]=f2bf(silu_f(bf2f(a.y)));
          o[2]=f2bf(silu_f(bf2f(a.z))); o[3]=f2bf(silu_f(bf2f(a.w)));
          o[4]=f2bf(silu_f(bf2f(b2.x))); o[5]=f2bf(silu_f(bf2f(b2.y)));
          o[6]=f2bf(silu_f(bf2f(b2.z))); o[7]=f2bf(silu_f(bf2f(b2.w)));
          *(float4*)(&sA[r*64 + (ck ^ (r&7))*8]) = *(const float4*)o;
        }
      } else {
        // spline region: (row, feature) -> 8 bases, only 4 nonzero
        int i0 = (k0 - KAN_H) >> 3;
        const float4 zf4 = make_float4(0.f,0.f,0.f,0.f);
        #pragma unroll
        for (int it=0; it<2; ++it) {
          int pair = t + it*256;
          int r = pair >> 3, ii = pair & 7;
          int base = r*64 + (ii ^ (r&7))*8;
          *(float4*)(&sA[base]) = zf4;             // zero-fill the 8 bases
          float x = bf2f(hsrc[(size_t)(m0+r)*KAN_H + i0 + ii]);
          float u = x*2.5f + 5.5f;
          bool valid = (u >= 0.f) & (u < 11.f);
          int m = (int)u;                          // out-of-range gated by valid+c-range
          float tt = u - (float)m;
          float omt = 1.f - tt, t2 = tt*tt, t3 = t2*tt;
          float w0 = omt*omt*omt*(1.f/6.f);
          float w3 = t3*(1.f/6.f);
          float w1 = 0.5f*t3 - t2 + (2.f/3.f);
          float w2 = 1.f - w0 - w1 - w3;
          float ws[4] = {w0, w1, w2, w3};
          int c0 = m - 3;
          #pragma unroll
          for (int j=0;j<4;j++){
            int c = c0 + j;
            bool ok = valid & ((unsigned)c < 8u);
            int off = ok ? (base + c) : 4096;     // dump slot (sA[4096] = smem[12288])
            sA[off] = f2bf(ws[j]);
          }
        }
      }
    }
    __syncthreads();
    #pragma unroll
    for (int kk=0; kk<64; kk+=32) {
      const int c0k = kk >> 3;
      bh8 af[4], bfr[2];
      #pragma unroll
      for (int i=0;i<4;i++) {
        int row = i*16 + lr;
        af[i] = *(const bh8*)(&sA[row*64 + ((c0k+lq) ^ (row&7))*8]);
      }
      #pragma unroll
      for (int j=0;j<2;j++) {
        int row = wave*32 + j*16 + lr;
        bfr[j] = *(const bh8*)(&sB[row*64 + ((c0k+lq) ^ (row&7))*8]);
      }
      #pragma unroll
      for (int i=0;i<4;i++)
        #pragma unroll
        for (int j=0;j<2;j++)
          acc[i][j] = __builtin_amdgcn_mfma_f32_16x16x32_bf16(af[i], bfr[j], acc[i][j], 0, 0, 0);
    }
    __syncthreads();
  }
  // epilogue: C/D layout col=lane&15, row=(lane>>4)*4+reg
  if (OUT_BF16) {
    // stage bf16 tile (64 x 128, stride 136) in LDS -> 256B-contiguous stores
    u16* Cb = (u16*)Cout;
    if (split) Cb += (size_t)blockIdx.z * M * N;
    #pragma unroll
    for (int i=0;i<4;i++) {
      #pragma unroll
      for (int j=0;j<2;j++) {
        int col = wave*32 + j*16 + lr;
        float bv = bias ? bias[n0 + col] : 0.f;
        #pragma unroll
        for (int r4=0;r4<4;r4++) {
          int row = i*16 + lq*4 + r4;
          smem[row*136 + col] = f2bf(acc[i][j][r4] + bv);
        }
      }
    }
    __syncthreads();
    #pragma unroll
    for (int it=0; it<4; ++it) {
      int idx = t + it*256;
      int row = idx >> 4, seg = idx & 15;
      *(float4*)(Cb + (size_t)(m0+row)*N + n0 + seg*8) =
          *(const float4*)&smem[row*136 + seg*8];
    }
  } else {
    float* Cf = (float*)Cout;
    if (split) Cf += (size_t)blockIdx.z * M * N;
    #pragma unroll
    for (int i=0;i<4;i++) {
      int row = m0 + i*16 + lq*4;
      #pragma unroll
      for (int j=0;j<2;j++) {
        int col = n0 + wave*32 + j*16 + lr;
        float bv = bias ? bias[col] : 0.f;
        #pragma unroll
        for (int r4=0;r4<4;r4++) {
          size_t idx = (size_t)(row + r4) * N + col;
          float v = acc[i][j][r4] + bv;
          if (R1) v += R1[idx];
          Cf[idx] = v;
        }
      }
    }
  }
}

// ---------------- transpose + LN1: x5d (B,C,N) -> x_t (B,N,C) f32 and ln1_t bf16 ----------------
__global__ __launch_bounds__(256) void k_ln1_trans(const float* __restrict__ x5d,
    float* __restrict__ x_t, u16* __restrict__ ln1_t,
    const float* __restrict__ g, const float* __restrict__ bv)
{
  __shared__ float tile[128*65];
  __shared__ float red_s[256], red_q[256];
  __shared__ float st_mu[64], st_rs[64];
  int b = blockIdx.y, n0 = blockIdx.x * 64;
  int j = threadIdx.x & 63, part = threadIdx.x >> 6;
  for (int cc=0; cc<32; ++cc) {
    int c = part*32 + cc;
    tile[c*65 + j] = x5d[((size_t)b*128 + c)*9216 + n0 + j];
  }
  __syncthreads();
  float s=0.f, s2=0.f;
  for (int cc=0; cc<32; ++cc) {
    float v = tile[(part*32+cc)*65 + j];
    s += v; s2 += v*v;
  }
  red_s[threadIdx.x]=s; red_q[threadIdx.x]=s2;
  __syncthreads();
  if (threadIdx.x < 64) {
    int jj = threadIdx.x;
    float ts = red_s[jj]+red_s[jj+64]+red_s[jj+128]+red_s[jj+192];
    float tq = red_q[jj]+red_q[jj+64]+red_q[jj+128]+red_q[jj+192];
    float mu = ts*(1.f/128.f);
    st_mu[jj]=mu;
    st_rs[jj]=rsqrtf(tq*(1.f/128.f) - mu*mu + 1e-5f);
  }
  __syncthreads();
  for (int it=0; it<32; ++it) {
    int idx = threadIdx.x + it*256;
    int tok = idx >> 7, c = idx & 127;
    float v = tile[c*65 + tok];
    size_t a = ((size_t)b*9216 + n0 + tok)*128 + c;
    x_t[a] = v;
    ln1_t[a] = f2bf((v - st_mu[tok])*st_rs[tok]*g[c] + bv[c]);
  }
}

// ---------------- double LN + KAN expansion: writes A1 (T x 1152 bf16) ----------------
__global__ void k_ln_double_expand(const float* __restrict__ in, u16* __restrict__ A1,
    const float* __restrict__ g1, const float* __restrict__ b1,
    const float* __restrict__ g2, const float* __restrict__ b2)
{
  int tok = blockIdx.x*4 + (threadIdx.x>>6);
  int lane = threadIdx.x & 63;
  const float* row = in + (size_t)tok*128;
  float v0=row[lane], v1=row[lane+64];
  float s=v0+v1, s2=v0*v0+v1*v1;
  #pragma unroll
  for (int o=1;o<64;o<<=1){ s += __shfl_xor(s,o); s2 += __shfl_xor(s2,o); }
  float mu=s*(1.f/128.f);
  float rs=rsqrtf(s2*(1.f/128.f)-mu*mu+1e-5f);
  float y0=(v0-mu)*rs*g1[lane]+b1[lane];
  float y1=(v1-mu)*rs*g1[lane+64]+b1[lane+64];
  s=y0+y1; s2=y0*y0+y1*y1;
  #pragma unroll
  for (int o=1;o<64;o<<=1){ s += __shfl_xor(s,o); s2 += __shfl_xor(s2,o); }
  mu=s*(1.f/128.f);
  rs=rsqrtf(s2*(1.f/128.f)-mu*mu+1e-5f);
  y0=(y0-mu)*rs*g2[lane]+b2[lane];
  y1=(y1-mu)*rs*g2[lane+64]+b2[lane+64];
  u16* arow = A1 + (size_t)tok*1152;
  arow[lane]    = f2bf(silu_f(y0));
  arow[lane+64] = f2bf(silu_f(y1));
  float w[8]; alignas(16) u16 o8[8];
  bspline8(y0, w);
  #pragma unroll
  for (int j=0;j<8;j++) o8[j]=f2bf(w[j]);
  *(float4*)(&arow[128 + lane*8]) = *(const float4*)o8;
  bspline8(y1, w);
  #pragma unroll
  for (int j=0;j<8;j++) o8[j]=f2bf(w[j]);
  *(float4*)(&arow[128 + (lane+64)*8]) = *(const float4*)o8;
}

// ---------------- depthwise 3x3 conv + fused q/k sumsq (normsum) ----------------
__global__ __launch_bounds__(256) void k_dwconv(const u16* __restrict__ qkv_t,
    u16* __restrict__ qkvd, const float* __restrict__ dw_w, const float* __restrict__ dw_b,
    float* __restrict__ ss)
{
  __shared__ float lt[100*68];
  int tile = blockIdx.x; int th=(tile/12)*8, tw=(tile%12)*8;
  int cg = blockIdx.y, b = blockIdx.z;
  int t = threadIdx.x;
  for (int pp=0; pp<7; ++pp) {
    int pos = pp*16 + (t>>4);
    if (pos < 100) {
      int ih = th + pos/10 - 1, iw = tw + pos%10 - 1;
      int c4 = (t & 15)*4;
      float4 v = make_float4(0.f,0.f,0.f,0.f);
      if (ih>=0 && ih<96 && iw>=0 && iw<96) {
        ushort4 raw = *(const ushort4*)&qkv_t[(((size_t)b*9216) + ih*96 + iw)*384 + cg*64 + c4];
        v = make_float4(bf2f(raw.x), bf2f(raw.y), bf2f(raw.z), bf2f(raw.w));
      }
      *(float4*)&lt[pos*68 + c4] = v;
    }
  }
  __syncthreads();
  int ch = t & 63, gch = cg*64 + ch;
  float w[9];
  #pragma unroll
  for (int k=0;k<9;k++) w[k]=dw_w[gch*9+k];
  float bias = dw_b[gch];
  float sq = 0.f;
  for (int pp=0; pp<16; ++pp) {
    int pos = (t>>6) + pp*4;
    int oh = pos>>3, ow = pos&7;
    float acc = bias;
    #pragma unroll
    for (int di=0; di<3; ++di)
      #pragma unroll
      for (int dj=0; dj<3; ++dj)
        acc += lt[((oh+di)*10 + ow+dj)*68 + ch] * w[di*3+dj];
    sq += acc*acc;
    qkvd[(((size_t)b*9216) + (th+oh)*96 + tw+ow)*384 + gch] = f2bf(acc);
  }
  if (cg < 4) {     // q (cg 0,1) and k (cg 2,3) channels need sum-of-squares over n
    __syncthreads();
    lt[(t>>6)*64 + ch] = sq;
    __syncthreads();
    if (t < 64) {
      float s = lt[t] + lt[64+t] + lt[128+t] + lt[192+t];
      atomicAdd(&ss[b*256 + cg*64 + t], s);
    }
  }
}

// ---------------- partial q@k^T with normalization, atomic into S ----------------
__global__ __launch_bounds__(256) void k_qk(const u16* __restrict__ qkvd,
    const float* __restrict__ ss, float* __restrict__ S)
{
  __shared__ float ql[128][32];
  __shared__ float kl[128][32];
  int nc=blockIdx.x, h=blockIdx.y, b=blockIdx.z;
  int t = threadIdx.x;
  int r = t>>1, half = t&1;
  size_t rowa = ((size_t)b*9216 + nc*128 + r)*384 + (half?128:0) + h*32;
  #pragma unroll
  for (int cc=0; cc<32; ++cc) {
    float v = bf2f(qkvd[rowa + cc]);
    if (half) kl[r][cc]=v; else ql[r][cc]=v;
  }
  __syncthreads();
  int i0 = (t>>4)*2, j0 = (t&15)*2;
  float a00=0.f,a01=0.f,a10=0.f,a11=0.f;
  for (int n=0;n<128;++n){
    float2 qv = *(const float2*)&ql[n][i0];
    float2 kv = *(const float2*)&kl[n][j0];
    a00 += qv.x*kv.x; a01 += qv.x*kv.y;
    a10 += qv.y*kv.x; a11 += qv.y*kv.y;
  }
  const float* ssb = ss + b*256;
  float rq0 = 1.f/fmaxf(sqrtf(ssb[h*32+i0]),1e-12f);
  float rq1 = 1.f/fmaxf(sqrtf(ssb[h*32+i0+1]),1e-12f);
  float rk0 = 1.f/fmaxf(sqrtf(ssb[128+h*32+j0]),1e-12f);
  float rk1 = 1.f/fmaxf(sqrtf(ssb[128+h*32+j0+1]),1e-12f);
  float* Sp = S + ((size_t)(b*4+h))*1024;
  atomicAdd(&Sp[i0*32+j0],     a00*rq0*rk0);
  atomicAdd(&Sp[i0*32+j0+1],   a01*rq0*rk1);
  atomicAdd(&Sp[(i0+1)*32+j0], a10*rq1*rk0);
  atomicAdd(&Sp[(i0+1)*32+j0+1], a11*rq1*rk1);
}

// ---------------- softmax over 32 cols per row, with per-head temp ----------------
__global__ void k_softmax(const float* __restrict__ S, float* __restrict__ attnP,
                          const float* __restrict__ temp)
{
  int bh = blockIdx.x; int h = bh & 3;
  int i = threadIdx.x;
  const float* row = S + (size_t)bh*1024 + i*32;
  float tp = temp[h];
  float vals[32]; float mx = -1e30f;
  #pragma unroll
  for (int j=0;j<32;++j){ float v=row[j]*tp; vals[j]=v; mx=fmaxf(mx,v); }
  float sum=0.f;
  #pragma unroll
  for (int j=0;j<32;++j){ vals[j]=__expf(vals[j]-mx); sum+=vals[j]; }
  float inv=1.f/sum;
  float* out = attnP + (size_t)bh*1024 + i*32;
  #pragma unroll
  for (int j=0;j<32;++j) out[j]=vals[j]*inv;
}

// ---------------- out = attn @ v, token-major bf16 out ----------------
__global__ __launch_bounds__(256) void k_av(const u16* __restrict__ qkvd,
    const float* __restrict__ attnP, u16* __restrict__ attnout)
{
  __shared__ float at[1024];
  int b=blockIdx.z, h=blockIdx.y;
  int n = blockIdx.x*256 + threadIdx.x;
  #pragma unroll
  for (int it=0;it<4;++it)
    at[threadIdx.x + it*256] = attnP[((size_t)(b*4+h))*1024 + threadIdx.x + it*256];
  __syncthreads();
  const u16* vrow = &qkvd[((size_t)b*9216 + n)*384 + 256 + h*32];
  float acc[32];
  #pragma unroll
  for (int i=0;i<32;++i) acc[i]=0.f;
  #pragma unroll 4
  for (int j=0;j<32;++j){
    float vj = bf2f(vrow[j]);
    #pragma unroll
    for (int i=0;i<32;++i) acc[i] += at[i*32+j]*vj;
  }
  u16* orow = &attnout[((size_t)b*9216 + n)*128 + h*32];
  #pragma unroll
  for (int i=0;i<32;++i) orow[i] = f2bf(acc[i]);
}

// ---------------- fused: xtr = R1+R2+4 bf16 partials ; xm = LN(xtr) bf16 ----------------
__global__ void k_reduce4_ln(const ushort4* __restrict__ P, const float4* __restrict__ R1,
    const float4* __restrict__ R2, float4* __restrict__ xtr, u16* __restrict__ xm,
    const float* __restrict__ g, const float* __restrict__ bv, int n4)
{
  int i = blockIdx.x*256 + threadIdx.x;
  int q = i & 31;
  ushort4 a=P[i], b=P[i+n4], c=P[i+2*n4], d=P[i+3*n4];
  float4 r=R1[i], s=R2[i];
  float4 v=make_float4(bf2f(a.x)+bf2f(b.x)+bf2f(c.x)+bf2f(d.x)+r.x+s.x,
                       bf2f(a.y)+bf2f(b.y)+bf2f(c.y)+bf2f(d.y)+r.y+s.y,
                       bf2f(a.z)+bf2f(b.z)+bf2f(c.z)+bf2f(d.z)+r.z+s.z,
                       bf2f(a.w)+bf2f(b.w)+bf2f(c.w)+bf2f(d.w)+r.w+s.w);
  xtr[i]=v;
  float s1 = v.x+v.y+v.z+v.w;
  float s2 = v.x*v.x+v.y*v.y+v.z*v.z+v.w*v.w;
  #pragma unroll
  for (int o=1;o<32;o<<=1){ s1 += __shfl_xor(s1,o); s2 += __shfl_xor(s2,o); }
  float mu = s1*(1.f/128.f);
  float rs = rsqrtf(s2*(1.f/128.f)-mu*mu+1e-5f);
  float4 g4 = *(const float4*)(g + q*4);
  float4 b4 = *(const float4*)(bv + q*4);
  ushort4 o4;
  o4.x = f2bf((v.x-mu)*rs*g4.x + b4.x);
  o4.y = f2bf((v.y-mu)*rs*g4.y + b4.y);
  o4.z = f2bf((v.z-mu)*rs*g4.z + b4.z);
  o4.w = f2bf((v.w-mu)*rs*g4.w + b4.w);
  ((ushort4*)xm)[i] = o4;
}

// ---------------- fused final: out(B,C,N) = transpose(R1 + R2 + 4 bf16 partials) ------
__global__ __launch_bounds__(256) void k_reduce4_trans(const ushort4* __restrict__ P,
    const float4* __restrict__ R1, const float4* __restrict__ R2,
    float* __restrict__ out, int n4)
{
  __shared__ float tile[128*65];
  int b=blockIdx.y, n0=blockIdx.x*64;
  for (int it=0; it<8; ++it) {            // 64 tokens x 32 float4 = 2048
    int idx = threadIdx.x + it*256;
    int tok = idx >> 5, c4 = idx & 31;
    int gi = (b*9216 + n0 + tok)*32 + c4;
    ushort4 a=P[gi], bb=P[gi+n4], c=P[gi+2*n4], d=P[gi+3*n4];
    float4 r=R1[gi], s=R2[gi];
    tile[(c4*4+0)*65+tok] = bf2f(a.x)+bf2f(bb.x)+bf2f(c.x)+bf2f(d.x)+r.x+s.x;
    tile[(c4*4+1)*65+tok] = bf2f(a.y)+bf2f(bb.y)+bf2f(c.y)+bf2f(d.y)+r.y+s.y;
    tile[(c4*4+2)*65+tok] = bf2f(a.z)+bf2f(bb.z)+bf2f(c.z)+bf2f(d.z)+r.z+s.z;
    tile[(c4*4+3)*65+tok] = bf2f(a.w)+bf2f(bb.w)+bf2f(c.w)+bf2f(d.w)+r.w+s.w;
  }
  __syncthreads();
  int j = threadIdx.x & 63, part = threadIdx.x>>6;
  for (int cc=0;cc<32;++cc){
    int c = part*32+cc;
    out[((size_t)b*128 + c)*9216 + n0 + j] = tile[c*65 + j];
  }
}

// ---------------- one fused prep kernel: all weight packs + Aneg + zeroing ----------------
__global__ void k_pack_all(
    const float* __restrict__ f1_bw0, const float* __restrict__ f1_sw0, const float* __restrict__ f1_sc0,
    const float* __restrict__ f2_bw0, const float* __restrict__ f2_sw0, const float* __restrict__ f2_sc0,
    const float* __restrict__ f1_bw1, const float* __restrict__ f1_sw1, const float* __restrict__ f1_sc1,
    const float* __restrict__ f2_bw1, const float* __restrict__ f2_sw1, const float* __restrict__ f2_sc1,
    const float* __restrict__ qkv_w, const float* __restrict__ po_w,
    const float* __restrict__ in_w, const float* __restrict__ out_w,
    const float* __restrict__ A_log,
    u16* __restrict__ W1t_a, u16* __restrict__ W1t_b,
    u16* __restrict__ W2t_a, u16* __restrict__ W2t_b,
    u16* __restrict__ qkvw_bf, u16* __restrict__ pow_bf,
    u16* __restrict__ inw_bf, u16* __restrict__ outw_bf,
    float* __restrict__ Aneg, float* __restrict__ zbuf, int nz)
{
  int i = blockIdx.x*256 + threadIdx.x;
  const int NW1 = 512*1152, NW2 = 128*4608;
  if (i < NW1) {
    int o = i/1152, k = i%1152; float v;
    if (k < 128) v = f1_bw0[o*128+k];
    else { int f=(k-128)>>3, c=(k-128)&7; v = f1_sw0[(o*128+f)*8+c]*f1_sc0[o*128+f]; }
    W1t_a[i]=f2bf(v); return;
  }
  i -= NW1;
  if (i < NW1) {
    int o = i/1152, k = i%1152; float v;
    if (k < 128) v = f2_bw0[o*128+k];
    else { int f=(k-128)>>3, c=(k-128)&7; v = f2_sw0[(o*128+f)*8+c]*f2_sc0[o*128+f]; }
    W1t_b[i]=f2bf(v); return;
  }
  i -= NW1;
  if (i < NW2) {
    int o = i/4608, k = i%4608; float v;
    if (k < 512) v = f1_bw1[o*512+k];
    else { int f=(k-512)>>3, c=(k-512)&7; v = f1_sw1[(o*512+f)*8+c]*f1_sc1[o*512+f]; }
    W2t_a[i]=f2bf(v); return;
  }
  i -= NW2;
  if (i < NW2) {
    int o = i/4608, k = i%4608; float v;
    if (k < 512) v = f2_bw1[o*512+k];
    else { int f=(k-512)>>3, c=(k-512)&7; v = f2_sw1[(o*512+f)*8+c]*f2_sc1[o*512+f]; }
    W2t_b[i]=f2bf(v); return;
  }
  i -= NW2;
  if (i < 49152) { qkvw_bf[i] = f2bf(qkv_w[i]); return; }
  i -= 49152;
  if (i < 16384) { pow_bf[i] = f2bf(po_w[i]); return; }
  i -= 16384;
  if (i < 16384) { inw_bf[i] = f2bf(in_w[i]); return; }
  i -= 16384;
  if (i < 16384) { outw_bf[i] = f2bf(out_w[i]); return; }
  i -= 16384;
  if (i < 512) { Aneg[i] = -__expf(A_log[i]); return; }
  i -= 512;
  if (i < nz) zbuf[i] = 0.f;
}

// ---------------- mamba pre: conv1d+silu for x/z, x_proj, delta ----------------
__global__ __launch_bounds__(256) void k_mamba_pre(const float* __restrict__ xz,
    float* __restrict__ xl, float* __restrict__ delta,
    float* __restrict__ Bm, float* __restrict__ Cm, u16* __restrict__ A_out,
    const float* __restrict__ cxw, const float* __restrict__ czw,
    const float* __restrict__ xpw, const float* __restrict__ dtw, const float* __restrict__ dtb)
{
  __shared__ float xls[4][64];
  __shared__ float xds[4][24];
  int w = threadIdx.x>>6;
  int tok = blockIdx.x*4 + w;
  int lane = threadIdx.x & 63;
  int l = tok % 9216;
  size_t base = (size_t)tok*128;
  float xm1 = (l>0)?     xz[base-128+lane]    : 0.f;
  float x0  =            xz[base+lane];
  float xp1 = (l<9215)?  xz[base+128+lane]    : 0.f;
  float zm1 = (l>0)?     xz[base-128+64+lane] : 0.f;
  float z0  =            xz[base+64+lane];
  float zp1 = (l<9215)?  xz[base+128+64+lane] : 0.f;
  float xc = silu_f(cxw[lane*3]*xm1 + cxw[lane*3+1]*x0 + cxw[lane*3+2]*xp1);
  float zc = silu_f(czw[lane*3]*zm1 + czw[lane*3+1]*z0 + czw[lane*3+2]*zp1);
  xl[(size_t)tok*64+lane] = xc;
  A_out[(size_t)tok*128 + 64 + lane] = f2bf(zc);
  xls[w][lane] = xc;
  __syncthreads();
  if (lane < 24) {
    float s=0.f;
    #pragma unroll 8
    for (int c=0;c<64;++c) s += xls[w][c]*xpw[lane*64+c];
    xds[w][lane]=s;
  }
  __syncthreads();
  float dacc = dtb[lane];
  #pragma unroll
  for (int r=0;r<8;++r) dacc += xds[w][r]*dtw[lane*8+r];
  delta[(size_t)tok*64+lane] = (dacc>20.f)? dacc : log1pf(__expf(dacc));
  if (lane<8)       Bm[(size_t)tok*8+lane]   = xds[w][8+lane];
  else if (lane<16) Cm[(size_t)tok*8+lane-8] = xds[w][16+lane-8];
}

// ---------------- chunked scan ----------------
__global__ __launch_bounds__(512) void k_scan1(const float* __restrict__ delta,
    const float* __restrict__ Bm, const float* __restrict__ xl,
    const float* __restrict__ Aneg, float* __restrict__ cP, float* __restrict__ cS)
{
  int b=blockIdx.y, ch=blockIdx.x;
  int t=threadIdx.x; int d=t>>3, n=t&7;
  float An = Aneg[d*8+n];
  float P=1.f, S=0.f;
  int l0 = ch*96;
  #pragma unroll 8
  for (int i=0;i<96;++i){
    size_t s = (size_t)b*9216 + l0+i;
    float del = delta[s*64+d];
    float a = __expf(del*An);
    float dbu = del * Bm[s*8+n] * xl[s*64+d];
    P *= a; S = fmaf(a,S,dbu);
  }
  size_t o = ((size_t)(b*96+ch))*512 + t;
  cP[o]=P; cS[o]=S;
}

__global__ __launch_bounds__(512) void k_scan2(const float* __restrict__ cP,
    const float* __restrict__ cS, float* __restrict__ cI)
{
  int b=blockIdx.x; int t=threadIdx.x;
  float carry=0.f;
  #pragma unroll 4
  for (int c=0;c<96;++c){
    size_t o = ((size_t)(b*96+c))*512 + t;
    cI[o]=carry;
    carry = fmaf(cP[o], carry, cS[o]);
  }
}

__global__ __launch_bounds__(512) void k_scan3(const float* __restrict__ delta,
    const float* __restrict__ Bm, const float* __restrict__ Cm,
    const float* __restrict__ xl, const float* __restrict__ Aneg,
    const float* __restrict__ Dp, const float* __restrict__ cI, u16* __restrict__ A_out)
{
  int b=blockIdx.y, ch=blockIdx.x;
  int t=threadIdx.x; int d=t>>3, n=t&7;
  float An = Aneg[d*8+n];
  float h = cI[((size_t)(b*96+ch))*512 + t];
  float Dd = Dp[d];
  int l0 = ch*96;
  #pragma unroll 4
  for (int i=0;i<96;++i){
    size_t s = (size_t)b*9216 + l0+i;
    float del = delta[s*64+d];
    float a = __expf(del*An);
    float xv = xl[s*64+d];
    h = fmaf(a, h, del * Bm[s*8+n] * xv);
    float contrib = h * Cm[s*8+n];
    contrib += __shfl_xor(contrib,1);
    contrib += __shfl_xor(contrib,2);
    contrib += __shfl_xor(contrib,4);
    if (n==0) A_out[s*128 + d] = f2bf(contrib + xv*Dd);
  }
}

extern "C" void kernel_launch(void* const* d_in, const int* in_sizes, int n_in,
                              void* d_out, int out_size, void* d_ws, size_t ws_size,
                              hipStream_t stream)
{
  (void)in_sizes; (void)n_in; (void)out_size; (void)ws_size;
  const float* x5d   =(const float*)d_in[0];
  const float* ln1_g =(const float*)d_in[1];
  const float* ln1_b =(const float*)d_in[2];
  const float* ln2_g =(const float*)d_in[3];
  const float* ln2_b =(const float*)d_in[4];
  const float* ln3_g =(const float*)d_in[5];
  const float* ln3_b =(const float*)d_in[6];
  const float* ln4_g =(const float*)d_in[7];
  const float* ln4_b =(const float*)d_in[8];
  const float* temp  =(const float*)d_in[9];
  const float* qkv_w =(const float*)d_in[10];
  const float* qkv_b =(const float*)d_in[11];
  const float* dw_w  =(const float*)d_in[12];
  const float* dw_b  =(const float*)d_in[13];
  const float* po_w  =(const float*)d_in[14];
  const float* po_b  =(const float*)d_in[15];
  const float* f1_ng =(const float*)d_in[16];
  const float* f1_nb =(const float*)d_in[17];
  const float* f1_bw0=(const float*)d_in[18];
  const float* f1_sw0=(const float*)d_in[19];
  const float* f1_sc0=(const float*)d_in[20];
  const float* f1_bw1=(const float*)d_in[21];
  const float* f1_sw1=(const float*)d_in[22];
  const float* f1_sc1=(const float*)d_in[23];
  const float* f2_ng =(const float*)d_in[24];
  const float* f2_nb =(const float*)d_in[25];
  const float* f2_bw0=(const float*)d_in[26];
  const float* f2_sw0=(const float*)d_in[27];
  const float* f2_sc0=(const float*)d_in[28];
  const float* f2_bw1=(const float*)d_in[29];
  const float* f2_sw1=(const float*)d_in[30];
  const float* f2_sc1=(const float*)d_in[31];
  const float* in_w  =(const float*)d_in[32];
  const float* xp_w  =(const float*)d_in[33];
  const float* dt_w  =(const float*)d_in[34];
  const float* dt_b  =(const float*)d_in[35];
  const float* A_log =(const float*)d_in[36];
  const float* Dp    =(const float*)d_in[37];
  const float* out_w =(const float*)d_in[38];
  const float* cx_w  =(const float*)d_in[39];
  const float* cz_w  =(const float*)d_in[40];
  float* out = (float*)d_out;

  const size_t T = 18432;   // B*N tokens
  char* wsb = (char*)d_ws;
  size_t off = 0;
  auto alloc = [&](size_t bytes)->void* {
    void* p = wsb + off; off += (bytes + 255) & ~(size_t)255; return p;
  };
  float* x_t    = (float*)alloc(T*128*4);
  char*  scrA   = (char*) alloc(38*1024*1024);   // shared scratch region
  float* ssS    = (float*)alloc((512+8192+8192)*4);
  float* t_t    = (float*)alloc(T*128*4);        // reused as m_t
  u16*   A1     = (u16*)  alloc(T*1152*2);
  u16*   hbuf   = (u16*)  alloc(T*512*2);
  float* xtr    = (float*)alloc(T*128*4);
  u16*   xm     = (u16*)  alloc(T*128*2);
  float* xl     = (float*)alloc(T*64*4);
  float* delta  = (float*)alloc(T*64*4);
  float* Bm     = (float*)alloc(T*8*4);
  float* Cm     = (float*)alloc(T*8*4);
  u16*   A_out  = (u16*)  alloc(T*128*2);
  float* cP     = (float*)alloc(2*96*512*4);
  float* cS     = (float*)alloc(2*96*512*4);
  float* cI     = (float*)alloc(2*96*512*4);
  u16* qkvw_bf  = (u16*)alloc(384*128*2);
  u16* pow_bf   = (u16*)alloc(128*128*2);
  u16* inw_bf   = (u16*)alloc(128*128*2);
  u16* outw_bf  = (u16*)alloc(128*128*2);
  u16* W1t_a    = (u16*)alloc(512*1152*2);
  u16* W2t_a    = (u16*)alloc(128*4608*2);
  u16* W1t_b    = (u16*)alloc(512*1152*2);
  u16* W2t_b    = (u16*)alloc(128*4608*2);
  float* Aneg   = (float*)alloc(512*4);
  float* ss = ssS;
  float* S  = ssS + 512;
  float* attnP = ssS + 512 + 8192;
  // scratch-region sub-allocations (lifetimes disjoint):
  u16*   ln1_t  = (u16*)(scrA);                              // 4.7 MB
  u16*   qkv_tb = (u16*)(scrA + 4718592);                    // 14.2 MB
  u16*   qkvd   = (u16*)(scrA + 4718592 + 14155776);         // 14.2 MB
  u16*   attnout= (u16*)(scrA + 4718592 + 2*14155776);       // 4.7 MB
  u16*   partb  = (u16*)scrA;      // 4 x T*128 bf16 = 18.9 MB (FKAN split-K partials)
  float* xz     = (float*)scrA;    // T*128 f32 (mamba, disjoint from partial use)
  float* m_t    = t_t;
  const int n4 = (int)(T*128/4);

  // ---- all weight prep + zeroing in one kernel ----
  k_pack_all<<<9636,256,0,stream>>>(
      f1_bw0,f1_sw0,f1_sc0, f2_bw0,f2_sw0,f2_sc0,
      f1_bw1,f1_sw1,f1_sc1, f2_bw1,f2_sw1,f2_sc1,
      qkv_w, po_w, in_w, out_w, A_log,
      W1t_a, W1t_b, W2t_a, W2t_b,
      qkvw_bf, pow_bf, inw_bf, outw_bf, Aneg, ssS, 512+8192);

  // ---- attention ----
  k_ln1_trans<<<dim3(144,2),256,0,stream>>>(x5d, x_t, ln1_t, ln1_g, ln1_b);
  gemm64<0,true><<<dim3(3,288,1),256,0,stream>>>(ln1_t, qkvw_bf, qkv_tb,
      18432, 384, 128, 2, 0, 1, qkv_b, nullptr);
  k_dwconv<<<dim3(144,6,2),256,0,stream>>>(qkv_tb, qkvd, dw_w, dw_b, ss);
  k_qk<<<dim3(72,4,2),256,0,stream>>>(qkvd, ss, S);
  k_softmax<<<8,32,0,stream>>>(S, attnP, temp);
  k_av<<<dim3(36,4,2),256,0,stream>>>(qkvd, attnP, attnout);
  gemm64<0,false><<<dim3(1,288,1),256,0,stream>>>(attnout, pow_bf, t_t,
      18432, 128, 128, 2, 0, 0, po_b, x_t);              // t = x + attn(ln1(x))

  // ---- FKAN 1 ----
  k_ln_double_expand<<<4608,256,0,stream>>>(t_t, A1, ln2_g, ln2_b, f1_ng, f1_nb);
  gemm64<0,true><<<dim3(4,288,1),256,0,stream>>>(A1, W1t_a, hbuf,
      18432, 512, 1152, 18, 0, 1, nullptr, nullptr);
  gemm64<512,true><<<dim3(1,288,4),256,0,stream>>>(hbuf, W2t_a, partb,
      18432, 128, 4608, 18, 1, 0, nullptr, nullptr);     // bf16 split-K partials
  k_reduce4_ln<<<2304,256,0,stream>>>((const ushort4*)partb, (const float4*)t_t,
      (const float4*)x_t, (float4*)xtr, xm, ln3_g, ln3_b, n4);
      // x_tr = t + x + kan2 ; xm = LN3(x_tr) bf16

  // ---- Mamba ----
  gemm64<0,false><<<dim3(1,288,1),256,0,stream>>>(xm, inw_bf, xz,
      18432, 128, 128, 2, 0, 0, nullptr, nullptr);
  k_mamba_pre<<<4608,256,0,stream>>>(xz, xl, delta, Bm, Cm, A_out,
      cx_w, cz_w, xp_w, dt_w, dt_b);
  k_scan1<<<dim3(96,2),512,0,stream>>>(delta, Bm, xl, Aneg, cP, cS);
  k_scan2<<<2,512,0,stream>>>(cP, cS, cI);
  k_scan3<<<dim3(96,2),512,0,stream>>>(delta, Bm, Cm, xl, Aneg, Dp, cI, A_out);
  gemm64<0,false><<<dim3(1,288,1),256,0,stream>>>(A_out, outw_bf, m_t,
      18432, 128, 128, 2, 0, 0, nullptr, xtr);           // m = mamba + x_tr

  // ---- FKAN 2 ----
  k_ln_double_expand<<<4608,256,0,stream>>>(m_t, A1, ln4_g, ln4_b, f2_ng, f2_nb);
  gemm64<0,true><<<dim3(4,288,1),256,0,stream>>>(A1, W1t_b, hbuf,
      18432, 512, 1152, 18, 0, 1, nullptr, nullptr);
  gemm64<512,true><<<dim3(1,288,4),256,0,stream>>>(hbuf, W2t_b, partb,
      18432, 128, 4608, 18, 1, 0, nullptr, nullptr);     // bf16 split-K partials
  k_reduce4_trans<<<dim3(144,2),256,0,stream>>>((const ushort4*)partb,
      (const float4*)m_t, (const float4*)xtr, out, n4);  // out = T(m + x_tr + kan2)
}

// Round 10
// 497.785 us; speedup vs baseline: 1.1323x; 1.0152x over previous
//
#include <hip/hip_runtime.h>

typedef unsigned short u16;
typedef unsigned long long u64;
typedef __attribute__((ext_vector_type(8))) short bh8;   // 8 x bf16 (4 VGPRs)
typedef __attribute__((ext_vector_type(4))) float f4;    // MFMA accumulator

#define DI __device__ __forceinline__

DI u16 f2bf(float f){ unsigned u=__float_as_uint(f); u += 0x7fffu + ((u>>16)&1u); return (u16)(u>>16); }
DI float bf2f(u16 u){ return __uint_as_float(((unsigned)u)<<16); }
DI float silu_f(float x){ return x/(1.f+__expf(-x)); }

DI void gld16(const u16* g, u16* l){
  __builtin_amdgcn_global_load_lds((const __attribute__((address_space(1))) void*)g,
                                   (__attribute__((address_space(3))) void*)l, 16, 0, 0);
}

// uniform cubic B-spline bases on grid [-2.2 : 0.4 : 2.2], 8 output bases (branchless,
// used only in the A1 materialization kernel where VALU cost is minor).
DI void bspline8(float x, float* v){
  float u = x*2.5f + 5.5f;           // (x + 2.2)/0.4
  #pragma unroll
  for (int j=0;j<8;j++){
    float a  = fabsf(u - (float)(j+2));
    float t1 = fmaxf(2.f-a, 0.f);
    float t2 = fmaxf(1.f-a, 0.f);
    v[j] = t1*t1*t1*(1.f/6.f) - t2*t2*t2*(2.f/3.f);
  }
}

// spline expansion -> packed 8 x bf16 (128-bit), built fully in registers:
// 4 nonzero weights packed into a u64 then funnel-shifted to slots c0..c0+3
// (c0 = m-3), ends clipped by the 128-bit container, invalid x -> all zero.
// Single b128 LDS write: no zero-fill, no scatter, no bank conflicts [r9->r10].
DI void bspline_pack(float x, u64& lo, u64& hi){
  float u = x*2.5f + 5.5f;
  bool valid = (u >= 0.f) & (u < 11.f);
  float uc = fminf(fmaxf(u, 0.f), 10.999f);
  int mi = (int)uc;                  // 0..10 (bounded -> all shifts bounded)
  float tt = uc - (float)mi;
  float omt = 1.f - tt, t2 = tt*tt, t3 = t2*tt;
  float w0 = omt*omt*omt*(1.f/6.f);
  float w3 = t3*(1.f/6.f);
  float w1 = 0.5f*t3 - t2 + (2.f/3.f);
  float w2 = 1.f - w0 - w1 - w3;
  u64 wblk = 0;
  if (valid) {
    unsigned a32 = (unsigned)f2bf(w0) | ((unsigned)f2bf(w1)<<16);
    unsigned b32 = (unsigned)f2bf(w2) | ((unsigned)f2bf(w3)<<16);
    wblk = (u64)a32 | ((u64)b32<<32);
  }
  int sh = (mi-3)*16;                // -48..112
  if (sh >= 0) {
    lo = (sh < 64) ? (wblk << sh) : 0ull;
    hi = (sh == 0) ? 0ull
       : (sh < 64) ? (wblk >> (64 - sh))
                   : (wblk << (sh - 64));
  } else {
    lo = wblk >> (-sh);
    hi = 0ull;
  }
}

// ---------------- GEMM (64x128 tile, 4 waves): C = A(MxK) * Bt(NxK)^T ----------------
// Wave w owns rows 0..63 x cols w*32..w*32+31, 4x2 acc. BK=64. lb(256,4) measured best
// [r4 48.6us vs r7 lb6 54.4us: lb6 raised L2 pressure, FETCH 19->25MB].
// swz!=0: XCD-aware (bx,by) remap — all N-tiles sharing one A-row-block land on the
// same XCD (round-robin workgroup->XCD), A-tile hits that XCD's L2 [r9: ~-8us].
// LDS: sB(128x64) | sA(64x64). 16B chunks XOR-swizzled (chunk c of row r at c^(r&7));
// global_load_lds lanes fetch permuted chunks so swizzle is free.
// KAN_H>0: A generated from h (M x KAN_H bf16): cols [0,KAN_H)=silu(h), rest=spline
// via register-packed funnel shift + single b128 write (replaces r4's 5-DS-op
// zero-fill+scatter which carried 3.38M conflict cycles).
// OUT_BF16: bf16 output staged via LDS -> 256B full-cacheline stores (no RMW
// amplification [r5-r8 verified]). split!=0 offsets output by blockIdx.z*M*N.
template<int KAN_H, bool OUT_BF16>
__global__ __launch_bounds__(256, 4)
void gemm64(const void* __restrict__ Asrc, const u16* __restrict__ Bt,
            void* __restrict__ Cout, int M, int N, int K, int ktiles_per_z,
            int split, int swz, const float* __restrict__ bias, const float* __restrict__ R1)
{
  __shared__ __align__(128) u16 smem[12288];  // sB[0..8192) sA[8192..12288)
  u16* const sB = smem;
  u16* const sA = smem + 8192;
  int bx = blockIdx.x, by = blockIdx.y;
  if (swz) {
    const int NX = gridDim.x, NY = gridDim.y;
    int lin = bx + NX*by;
    int k8 = lin & 7, g = lin >> 3;
    by = k8*(NY>>3) + g/NX;
    bx = g%NX;
  }
  const int m0 = by * 64;
  const int n0 = bx * 128;
  const int ktiles = K >> 6;
  int kt0 = blockIdx.z * ktiles_per_z;
  int kt1 = kt0 + ktiles_per_z; if (kt1 > ktiles) kt1 = ktiles;
  const int t = threadIdx.x;
  const int wave = t >> 6, lane = t & 63;
  const int lr = lane & 15, lq = lane >> 4;
  const int lr8 = lane >> 3, lc8 = lane & 7;
  const int swz8 = lc8 ^ lr8;      // swizzled global chunk for this lane (row&7 == lr8)
  f4 acc[4][2];
  f4 z4 = {0.f,0.f,0.f,0.f};
  #pragma unroll
  for (int i=0;i<4;i++){ acc[i][0]=z4; acc[i][1]=z4; }

  for (int kt = kt0; kt < kt1; ++kt) {
    int k0 = kt << 6;
    // stage Bt tile (128 rows) via async global->LDS, swizzled
    {
      const u16* Bp = Bt + (size_t)n0 * K + k0;
      #pragma unroll
      for (int it=0; it<4; ++it) {
        int r = it*32 + wave*8;
        gld16(Bp + (size_t)(r + lr8) * K + swz8*8, &sB[r*64]);
      }
    }
    // stage A tile (64 rows)
    if (KAN_H == 0) {
      const u16* Ap = (const u16*)Asrc + (size_t)m0 * K + k0;
      #pragma unroll
      for (int it=0; it<2; ++it) {
        int r = it*32 + wave*8;
        gld16(Ap + (size_t)(r + lr8) * K + swz8*8, &sA[r*64]);
      }
    } else {
      const u16* hsrc = (const u16*)Asrc;
      if (k0 < KAN_H) {
        // silu region: 64 rows x 64 cols = 512 chunks of 8
        #pragma unroll
        for (int it=0; it<2; ++it) {
          int chunk = t + it*256;
          int r = chunk >> 3, ck = chunk & 7;
          const u16* src = hsrc + (size_t)(m0+r)*KAN_H + k0 + ck*8;
          ushort4 a = *(const ushort4*)src;
          ushort4 b2 = *(const ushort4*)(src+4);
          alignas(16) u16 o[8];
          o[0]=f2bf(silu_f(bf2f(a.x))); o[1]=f2bf(silu_f(bf2f(a.y)));
          o[2]=f2bf(silu_f(bf2f(a.z))); o[3]=f2bf(silu_f(bf2f(a.w)));
          o[4]=f2bf(silu_f(bf2f(b2.x))); o[5]=f2bf(silu_f(bf2f(b2.y)));
          o[6]=f2bf(silu_f(bf2f(b2.z))); o[7]=f2bf(silu_f(bf2f(b2.w)));
          *(float4*)(&sA[r*64 + (ck ^ (r&7))*8]) = *(const float4*)o;
        }
      } else {
        // spline region: (row, feature) -> 8 bases, register-packed, 1 b128 write
        int i0 = (k0 - KAN_H) >> 3;
        #pragma unroll
        for (int it=0; it<2; ++it) {
          int pair = t + it*256;
          int r = pair >> 3, ii = pair & 7;
          float x = bf2f(hsrc[(size_t)(m0+r)*KAN_H + i0 + ii]);
          u64 lo, hi;
          bspline_pack(x, lo, hi);
          alignas(16) u64 o2[2] = {lo, hi};
          *(float4*)(&sA[r*64 + (ii ^ (r&7))*8]) = *(const float4*)o2;
        }
      }
    }
    __syncthreads();
    #pragma unroll
    for (int kk=0; kk<64; kk+=32) {
      const int c0k = kk >> 3;
      bh8 af[4], bfr[2];
      #pragma unroll
      for (int i=0;i<4;i++) {
        int row = i*16 + lr;
        af[i] = *(const bh8*)(&sA[row*64 + ((c0k+lq) ^ (row&7))*8]);
      }
      #pragma unroll
      for (int j=0;j<2;j++) {
        int row = wave*32 + j*16 + lr;
        bfr[j] = *(const bh8*)(&sB[row*64 + ((c0k+lq) ^ (row&7))*8]);
      }
      #pragma unroll
      for (int i=0;i<4;i++)
        #pragma unroll
        for (int j=0;j<2;j++)
          acc[i][j] = __builtin_amdgcn_mfma_f32_16x16x32_bf16(af[i], bfr[j], acc[i][j], 0, 0, 0);
    }
    __syncthreads();
  }
  // epilogue: C/D layout col=lane&15, row=(lane>>4)*4+reg
  if (OUT_BF16) {
    // stage bf16 tile (64 x 128, stride 136) in LDS -> 256B-contiguous stores
    u16* Cb = (u16*)Cout;
    if (split) Cb += (size_t)blockIdx.z * M * N;
    #pragma unroll
    for (int i=0;i<4;i++) {
      #pragma unroll
      for (int j=0;j<2;j++) {
        int col = wave*32 + j*16 + lr;
        float bv = bias ? bias[n0 + col] : 0.f;
        #pragma unroll
        for (int r4=0;r4<4;r4++) {
          int row = i*16 + lq*4 + r4;
          smem[row*136 + col] = f2bf(acc[i][j][r4] + bv);
        }
      }
    }
    __syncthreads();
    #pragma unroll
    for (int it=0; it<4; ++it) {
      int idx = t + it*256;
      int row = idx >> 4, seg = idx & 15;
      *(float4*)(Cb + (size_t)(m0+row)*N + n0 + seg*8) =
          *(const float4*)&smem[row*136 + seg*8];
    }
  } else {
    float* Cf = (float*)Cout;
    if (split) Cf += (size_t)blockIdx.z * M * N;
    #pragma unroll
    for (int i=0;i<4;i++) {
      int row = m0 + i*16 + lq*4;
      #pragma unroll
      for (int j=0;j<2;j++) {
        int col = n0 + wave*32 + j*16 + lr;
        float bv = bias ? bias[col] : 0.f;
        #pragma unroll
        for (int r4=0;r4<4;r4++) {
          size_t idx = (size_t)(row + r4) * N + col;
          float v = acc[i][j][r4] + bv;
          if (R1) v += R1[idx];
          Cf[idx] = v;
        }
      }
    }
  }
}

// ---------------- transpose + LN1: x5d (B,C,N) -> x_t (B,N,C) f32 and ln1_t bf16 ----------------
__global__ __launch_bounds__(256) void k_ln1_trans(const float* __restrict__ x5d,
    float* __restrict__ x_t, u16* __restrict__ ln1_t,
    const float* __restrict__ g, const float* __restrict__ bv)
{
  __shared__ float tile[128*65];
  __shared__ float red_s[256], red_q[256];
  __shared__ float st_mu[64], st_rs[64];
  int b = blockIdx.y, n0 = blockIdx.x * 64;
  int j = threadIdx.x & 63, part = threadIdx.x >> 6;
  for (int cc=0; cc<32; ++cc) {
    int c = part*32 + cc;
    tile[c*65 + j] = x5d[((size_t)b*128 + c)*9216 + n0 + j];
  }
  __syncthreads();
  float s=0.f, s2=0.f;
  for (int cc=0; cc<32; ++cc) {
    float v = tile[(part*32+cc)*65 + j];
    s += v; s2 += v*v;
  }
  red_s[threadIdx.x]=s; red_q[threadIdx.x]=s2;
  __syncthreads();
  if (threadIdx.x < 64) {
    int jj = threadIdx.x;
    float ts = red_s[jj]+red_s[jj+64]+red_s[jj+128]+red_s[jj+192];
    float tq = red_q[jj]+red_q[jj+64]+red_q[jj+128]+red_q[jj+192];
    float mu = ts*(1.f/128.f);
    st_mu[jj]=mu;
    st_rs[jj]=rsqrtf(tq*(1.f/128.f) - mu*mu + 1e-5f);
  }
  __syncthreads();
  for (int it=0; it<32; ++it) {
    int idx = threadIdx.x + it*256;
    int tok = idx >> 7, c = idx & 127;
    float v = tile[c*65 + tok];
    size_t a = ((size_t)b*9216 + n0 + tok)*128 + c;
    x_t[a] = v;
    ln1_t[a] = f2bf((v - st_mu[tok])*st_rs[tok]*g[c] + bv[c]);
  }
}

// ---------------- double LN + KAN expansion: writes A1 (T x 1152 bf16) ----------------
__global__ void k_ln_double_expand(const float* __restrict__ in, u16* __restrict__ A1,
    const float* __restrict__ g1, const float* __restrict__ b1,
    const float* __restrict__ g2, const float* __restrict__ b2)
{
  int tok = blockIdx.x*4 + (threadIdx.x>>6);
  int lane = threadIdx.x & 63;
  const float* row = in + (size_t)tok*128;
  float v0=row[lane], v1=row[lane+64];
  float s=v0+v1, s2=v0*v0+v1*v1;
  #pragma unroll
  for (int o=1;o<64;o<<=1){ s += __shfl_xor(s,o); s2 += __shfl_xor(s2,o); }
  float mu=s*(1.f/128.f);
  float rs=rsqrtf(s2*(1.f/128.f)-mu*mu+1e-5f);
  float y0=(v0-mu)*rs*g1[lane]+b1[lane];
  float y1=(v1-mu)*rs*g1[lane+64]+b1[lane+64];
  s=y0+y1; s2=y0*y0+y1*y1;
  #pragma unroll
  for (int o=1;o<64;o<<=1){ s += __shfl_xor(s,o); s2 += __shfl_xor(s2,o); }
  mu=s*(1.f/128.f);
  rs=rsqrtf(s2*(1.f/128.f)-mu*mu+1e-5f);
  y0=(y0-mu)*rs*g2[lane]+b2[lane];
  y1=(y1-mu)*rs*g2[lane+64]+b2[lane+64];
  u16* arow = A1 + (size_t)tok*1152;
  arow[lane]    = f2bf(silu_f(y0));
  arow[lane+64] = f2bf(silu_f(y1));
  u64 lo, hi;
  bspline_pack(y0, lo, hi);
  alignas(16) u64 o2[2] = {lo, hi};
  *(float4*)(&arow[128 + lane*8]) = *(const float4*)o2;
  bspline_pack(y1, lo, hi);
  alignas(16) u64 o3[2] = {lo, hi};
  *(float4*)(&arow[128 + (lane+64)*8]) = *(const float4*)o3;
}

// ---------------- depthwise 3x3 conv + fused q/k sumsq (normsum) ----------------
__global__ __launch_bounds__(256) void k_dwconv(const u16* __restrict__ qkv_t,
    u16* __restrict__ qkvd, const float* __restrict__ dw_w, const float* __restrict__ dw_b,
    float* __restrict__ ss)
{
  __shared__ float lt[100*68];
  int tile = blockIdx.x; int th=(tile/12)*8, tw=(tile%12)*8;
  int cg = blockIdx.y, b = blockIdx.z;
  int t = threadIdx.x;
  for (int pp=0; pp<7; ++pp) {
    int pos = pp*16 + (t>>4);
    if (pos < 100) {
      int ih = th + pos/10 - 1, iw = tw + pos%10 - 1;
      int c4 = (t & 15)*4;
      float4 v = make_float4(0.f,0.f,0.f,0.f);
      if (ih>=0 && ih<96 && iw>=0 && iw<96) {
        ushort4 raw = *(const ushort4*)&qkv_t[(((size_t)b*9216) + ih*96 + iw)*384 + cg*64 + c4];
        v = make_float4(bf2f(raw.x), bf2f(raw.y), bf2f(raw.z), bf2f(raw.w));
      }
      *(float4*)&lt[pos*68 + c4] = v;
    }
  }
  __syncthreads();
  int ch = t & 63, gch = cg*64 + ch;
  float w[9];
  #pragma unroll
  for (int k=0;k<9;k++) w[k]=dw_w[gch*9+k];
  float bias = dw_b[gch];
  float sq = 0.f;
  for (int pp=0; pp<16; ++pp) {
    int pos = (t>>6) + pp*4;
    int oh = pos>>3, ow = pos&7;
    float acc = bias;
    #pragma unroll
    for (int di=0; di<3; ++di)
      #pragma unroll
      for (int dj=0; dj<3; ++dj)
        acc += lt[((oh+di)*10 + ow+dj)*68 + ch] * w[di*3+dj];
    sq += acc*acc;
    qkvd[(((size_t)b*9216) + (th+oh)*96 + tw+ow)*384 + gch] = f2bf(acc);
  }
  if (cg < 4) {     // q (cg 0,1) and k (cg 2,3) channels need sum-of-squares over n
    __syncthreads();
    lt[(t>>6)*64 + ch] = sq;
    __syncthreads();
    if (t < 64) {
      float s = lt[t] + lt[64+t] + lt[128+t] + lt[192+t];
      atomicAdd(&ss[b*256 + cg*64 + t], s);
    }
  }
}

// ---------------- partial q@k^T with normalization, atomic into S ----------------
__global__ __launch_bounds__(256) void k_qk(const u16* __restrict__ qkvd,
    const float* __restrict__ ss, float* __restrict__ S)
{
  __shared__ float ql[128][32];
  __shared__ float kl[128][32];
  int nc=blockIdx.x, h=blockIdx.y, b=blockIdx.z;
  int t = threadIdx.x;
  int r = t>>1, half = t&1;
  size_t rowa = ((size_t)b*9216 + nc*128 + r)*384 + (half?128:0) + h*32;
  #pragma unroll
  for (int cc=0; cc<32; ++cc) {
    float v = bf2f(qkvd[rowa + cc]);
    if (half) kl[r][cc]=v; else ql[r][cc]=v;
  }
  __syncthreads();
  int i0 = (t>>4)*2, j0 = (t&15)*2;
  float a00=0.f,a01=0.f,a10=0.f,a11=0.f;
  for (int n=0;n<128;++n){
    float2 qv = *(const float2*)&ql[n][i0];
    float2 kv = *(const float2*)&kl[n][j0];
    a00 += qv.x*kv.x; a01 += qv.x*kv.y;
    a10 += qv.y*kv.x; a11 += qv.y*kv.y;
  }
  const float* ssb = ss + b*256;
  float rq0 = 1.f/fmaxf(sqrtf(ssb[h*32+i0]),1e-12f);
  float rq1 = 1.f/fmaxf(sqrtf(ssb[h*32+i0+1]),1e-12f);
  float rk0 = 1.f/fmaxf(sqrtf(ssb[128+h*32+j0]),1e-12f);
  float rk1 = 1.f/fmaxf(sqrtf(ssb[128+h*32+j0+1]),1e-12f);
  float* Sp = S + ((size_t)(b*4+h))*1024;
  atomicAdd(&Sp[i0*32+j0],     a00*rq0*rk0);
  atomicAdd(&Sp[i0*32+j0+1],   a01*rq0*rk1);
  atomicAdd(&Sp[(i0+1)*32+j0], a10*rq1*rk0);
  atomicAdd(&Sp[(i0+1)*32+j0+1], a11*rq1*rk1);
}

// ---------------- softmax over 32 cols per row, with per-head temp ----------------
__global__ void k_softmax(const float* __restrict__ S, float* __restrict__ attnP,
                          const float* __restrict__ temp)
{
  int bh = blockIdx.x; int h = bh & 3;
  int i = threadIdx.x;
  const float* row = S + (size_t)bh*1024 + i*32;
  float tp = temp[h];
  float vals[32]; float mx = -1e30f;
  #pragma unroll
  for (int j=0;j<32;++j){ float v=row[j]*tp; vals[j]=v; mx=fmaxf(mx,v); }
  float sum=0.f;
  #pragma unroll
  for (int j=0;j<32;++j){ vals[j]=__expf(vals[j]-mx); sum+=vals[j]; }
  float inv=1.f/sum;
  float* out = attnP + (size_t)bh*1024 + i*32;
  #pragma unroll
  for (int j=0;j<32;++j) out[j]=vals[j]*inv;
}

// ---------------- out = attn @ v, token-major bf16 out ----------------
__global__ __launch_bounds__(256) void k_av(const u16* __restrict__ qkvd,
    const float* __restrict__ attnP, u16* __restrict__ attnout)
{
  __shared__ float at[1024];
  int b=blockIdx.z, h=blockIdx.y;
  int n = blockIdx.x*256 + threadIdx.x;
  #pragma unroll
  for (int it=0;it<4;++it)
    at[threadIdx.x + it*256] = attnP[((size_t)(b*4+h))*1024 + threadIdx.x + it*256];
  __syncthreads();
  const u16* vrow = &qkvd[((size_t)b*9216 + n)*384 + 256 + h*32];
  float acc[32];
  #pragma unroll
  for (int i=0;i<32;++i) acc[i]=0.f;
  #pragma unroll 4
  for (int j=0;j<32;++j){
    float vj = bf2f(vrow[j]);
    #pragma unroll
    for (int i=0;i<32;++i) acc[i] += at[i*32+j]*vj;
  }
  u16* orow = &attnout[((size_t)b*9216 + n)*128 + h*32];
  #pragma unroll
  for (int i=0;i<32;++i) orow[i] = f2bf(acc[i]);
}

// ---------------- fused: xtr = R1+R2+4 bf16 partials ; xm = LN(xtr) bf16 ----------------
__global__ void k_reduce4_ln(const ushort4* __restrict__ P, const float4* __restrict__ R1,
    const float4* __restrict__ R2, float4* __restrict__ xtr, u16* __restrict__ xm,
    const float* __restrict__ g, const float* __restrict__ bv, int n4)
{
  int i = blockIdx.x*256 + threadIdx.x;
  int q = i & 31;
  ushort4 a=P[i], b=P[i+n4], c=P[i+2*n4], d=P[i+3*n4];
  float4 r=R1[i], s=R2[i];
  float4 v=make_float4(bf2f(a.x)+bf2f(b.x)+bf2f(c.x)+bf2f(d.x)+r.x+s.x,
                       bf2f(a.y)+bf2f(b.y)+bf2f(c.y)+bf2f(d.y)+r.y+s.y,
                       bf2f(a.z)+bf2f(b.z)+bf2f(c.z)+bf2f(d.z)+r.z+s.z,
                       bf2f(a.w)+bf2f(b.w)+bf2f(c.w)+bf2f(d.w)+r.w+s.w);
  xtr[i]=v;
  float s1 = v.x+v.y+v.z+v.w;
  float s2 = v.x*v.x+v.y*v.y+v.z*v.z+v.w*v.w;
  #pragma unroll
  for (int o=1;o<32;o<<=1){ s1 += __shfl_xor(s1,o); s2 += __shfl_xor(s2,o); }
  float mu = s1*(1.f/128.f);
  float rs = rsqrtf(s2*(1.f/128.f)-mu*mu+1e-5f);
  float4 g4 = *(const float4*)(g + q*4);
  float4 b4 = *(const float4*)(bv + q*4);
  ushort4 o4;
  o4.x = f2bf((v.x-mu)*rs*g4.x + b4.x);
  o4.y = f2bf((v.y-mu)*rs*g4.y + b4.y);
  o4.z = f2bf((v.z-mu)*rs*g4.z + b4.z);
  o4.w = f2bf((v.w-mu)*rs*g4.w + b4.w);
  ((ushort4*)xm)[i] = o4;
}

// ---------------- fused final: out(B,C,N) = transpose(R1 + R2 + 4 bf16 partials) ------
__global__ __launch_bounds__(256) void k_reduce4_trans(const ushort4* __restrict__ P,
    const float4* __restrict__ R1, const float4* __restrict__ R2,
    float* __restrict__ out, int n4)
{
  __shared__ float tile[128*65];
  int b=blockIdx.y, n0=blockIdx.x*64;
  for (int it=0; it<8; ++it) {            // 64 tokens x 32 float4 = 2048
    int idx = threadIdx.x + it*256;
    int tok = idx >> 5, c4 = idx & 31;
    int gi = (b*9216 + n0 + tok)*32 + c4;
    ushort4 a=P[gi], bb=P[gi+n4], c=P[gi+2*n4], d=P[gi+3*n4];
    float4 r=R1[gi], s=R2[gi];
    tile[(c4*4+0)*65+tok] = bf2f(a.x)+bf2f(bb.x)+bf2f(c.x)+bf2f(d.x)+r.x+s.x;
    tile[(c4*4+1)*65+tok] = bf2f(a.y)+bf2f(bb.y)+bf2f(c.y)+bf2f(d.y)+r.y+s.y;
    tile[(c4*4+2)*65+tok] = bf2f(a.z)+bf2f(bb.z)+bf2f(c.z)+bf2f(d.z)+r.z+s.z;
    tile[(c4*4+3)*65+tok] = bf2f(a.w)+bf2f(bb.w)+bf2f(c.w)+bf2f(d.w)+r.w+s.w;
  }
  __syncthreads();
  int j = threadIdx.x & 63, part = threadIdx.x>>6;
  for (int cc=0;cc<32;++cc){
    int c = part*32+cc;
    out[((size_t)b*128 + c)*9216 + n0 + j] = tile[c*65 + j];
  }
}

// ---------------- one fused prep kernel: all weight packs + Aneg + zeroing ----------------
__global__ void k_pack_all(
    const float* __restrict__ f1_bw0, const float* __restrict__ f1_sw0, const float* __restrict__ f1_sc0,
    const float* __restrict__ f2_bw0, const float* __restrict__ f2_sw0, const float* __restrict__ f2_sc0,
    const float* __restrict__ f1_bw1, const float* __restrict__ f1_sw1, const float* __restrict__ f1_sc1,
    const float* __restrict__ f2_bw1, const float* __restrict__ f2_sw1, const float* __restrict__ f2_sc1,
    const float* __restrict__ qkv_w, const float* __restrict__ po_w,
    const float* __restrict__ in_w, const float* __restrict__ out_w,
    const float* __restrict__ A_log,
    u16* __restrict__ W1t_a, u16* __restrict__ W1t_b,
    u16* __restrict__ W2t_a, u16* __restrict__ W2t_b,
    u16* __restrict__ qkvw_bf, u16* __restrict__ pow_bf,
    u16* __restrict__ inw_bf, u16* __restrict__ outw_bf,
    float* __restrict__ Aneg, float* __restrict__ zbuf, int nz)
{
  int i = blockIdx.x*256 + threadIdx.x;
  const int NW1 = 512*1152, NW2 = 128*4608;
  if (i < NW1) {
    int o = i/1152, k = i%1152; float v;
    if (k < 128) v = f1_bw0[o*128+k];
    else { int f=(k-128)>>3, c=(k-128)&7; v = f1_sw0[(o*128+f)*8+c]*f1_sc0[o*128+f]; }
    W1t_a[i]=f2bf(v); return;
  }
  i -= NW1;
  if (i < NW1) {
    int o = i/1152, k = i%1152; float v;
    if (k < 128) v = f2_bw0[o*128+k];
    else { int f=(k-128)>>3, c=(k-128)&7; v = f2_sw0[(o*128+f)*8+c]*f2_sc0[o*128+f]; }
    W1t_b[i]=f2bf(v); return;
  }
  i -= NW1;
  if (i < NW2) {
    int o = i/4608, k = i%4608; float v;
    if (k < 512) v = f1_bw1[o*512+k];
    else { int f=(k-512)>>3, c=(k-512)&7; v = f1_sw1[(o*512+f)*8+c]*f1_sc1[o*512+f]; }
    W2t_a[i]=f2bf(v); return;
  }
  i -= NW2;
  if (i < NW2) {
    int o = i/4608, k = i%4608; float v;
    if (k < 512) v = f2_bw1[o*512+k];
    else { int f=(k-512)>>3, c=(k-512)&7; v = f2_sw1[(o*512+f)*8+c]*f2_sc1[o*512+f]; }
    W2t_b[i]=f2bf(v); return;
  }
  i -= NW2;
  if (i < 49152) { qkvw_bf[i] = f2bf(qkv_w[i]); return; }
  i -= 49152;
  if (i < 16384) { pow_bf[i] = f2bf(po_w[i]); return; }
  i -= 16384;
  if (i < 16384) { inw_bf[i] = f2bf(in_w[i]); return; }
  i -= 16384;
  if (i < 16384) { outw_bf[i] = f2bf(out_w[i]); return; }
  i -= 16384;
  if (i < 512) { Aneg[i] = -__expf(A_log[i]); return; }
  i -= 512;
  if (i < nz) zbuf[i] = 0.f;
}

// ---------------- mamba pre: conv1d+silu for x/z, x_proj, delta ----------------
__global__ __launch_bounds__(256) void k_mamba_pre(const float* __restrict__ xz,
    float* __restrict__ xl, float* __restrict__ delta,
    float* __restrict__ Bm, float* __restrict__ Cm, u16* __restrict__ A_out,
    const float* __restrict__ cxw, const float* __restrict__ czw,
    const float* __restrict__ xpw, const float* __restrict__ dtw, const float* __restrict__ dtb)
{
  __shared__ float xls[4][64];
  __shared__ float xds[4][24];
  int w = threadIdx.x>>6;
  int tok = blockIdx.x*4 + w;
  int lane = threadIdx.x & 63;
  int l = tok % 9216;
  size_t base = (size_t)tok*128;
  float xm1 = (l>0)?     xz[base-128+lane]    : 0.f;
  float x0  =            xz[base+lane];
  float xp1 = (l<9215)?  xz[base+128+lane]    : 0.f;
  float zm1 = (l>0)?     xz[base-128+64+lane] : 0.f;
  float z0  =            xz[base+64+lane];
  float zp1 = (l<9215)?  xz[base+128+64+lane] : 0.f;
  float xc = silu_f(cxw[lane*3]*xm1 + cxw[lane*3+1]*x0 + cxw[lane*3+2]*xp1);
  float zc = silu_f(czw[lane*3]*zm1 + czw[lane*3+1]*z0 + czw[lane*3+2]*zp1);
  xl[(size_t)tok*64+lane] = xc;
  A_out[(size_t)tok*128 + 64 + lane] = f2bf(zc);
  xls[w][lane] = xc;
  __syncthreads();
  if (lane < 24) {
    float s=0.f;
    #pragma unroll 8
    for (int c=0;c<64;++c) s += xls[w][c]*xpw[lane*64+c];
    xds[w][lane]=s;
  }
  __syncthreads();
  float dacc = dtb[lane];
  #pragma unroll
  for (int r=0;r<8;++r) dacc += xds[w][r]*dtw[lane*8+r];
  delta[(size_t)tok*64+lane] = (dacc>20.f)? dacc : log1pf(__expf(dacc));
  if (lane<8)       Bm[(size_t)tok*8+lane]   = xds[w][8+lane];
  else if (lane<16) Cm[(size_t)tok*8+lane-8] = xds[w][16+lane-8];
}

// ---------------- chunked scan ----------------
__global__ __launch_bounds__(512) void k_scan1(const float* __restrict__ delta,
    const float* __restrict__ Bm, const float* __restrict__ xl,
    const float* __restrict__ Aneg, float* __restrict__ cP, float* __restrict__ cS)
{
  int b=blockIdx.y, ch=blockIdx.x;
  int t=threadIdx.x; int d=t>>3, n=t&7;
  float An = Aneg[d*8+n];
  float P=1.f, S=0.f;
  int l0 = ch*96;
  #pragma unroll 8
  for (int i=0;i<96;++i){
    size_t s = (size_t)b*9216 + l0+i;
    float del = delta[s*64+d];
    float a = __expf(del*An);
    float dbu = del * Bm[s*8+n] * xl[s*64+d];
    P *= a; S = fmaf(a,S,dbu);
  }
  size_t o = ((size_t)(b*96+ch))*512 + t;
  cP[o]=P; cS[o]=S;
}

__global__ __launch_bounds__(512) void k_scan2(const float* __restrict__ cP,
    const float* __restrict__ cS, float* __restrict__ cI)
{
  int b=blockIdx.x; int t=threadIdx.x;
  float carry=0.f;
  #pragma unroll 4
  for (int c=0;c<96;++c){
    size_t o = ((size_t)(b*96+c))*512 + t;
    cI[o]=carry;
    carry = fmaf(cP[o], carry, cS[o]);
  }
}

__global__ __launch_bounds__(512) void k_scan3(const float* __restrict__ delta,
    const float* __restrict__ Bm, const float* __restrict__ Cm,
    const float* __restrict__ xl, const float* __restrict__ Aneg,
    const float* __restrict__ Dp, const float* __restrict__ cI, u16* __restrict__ A_out)
{
  int b=blockIdx.y, ch=blockIdx.x;
  int t=threadIdx.x; int d=t>>3, n=t&7;
  float An = Aneg[d*8+n];
  float h = cI[((size_t)(b*96+ch))*512 + t];
  float Dd = Dp[d];
  int l0 = ch*96;
  #pragma unroll 4
  for (int i=0;i<96;++i){
    size_t s = (size_t)b*9216 + l0+i;
    float del = delta[s*64+d];
    float a = __expf(del*An);
    float xv = xl[s*64+d];
    h = fmaf(a, h, del * Bm[s*8+n] * xv);
    float contrib = h * Cm[s*8+n];
    contrib += __shfl_xor(contrib,1);
    contrib += __shfl_xor(contrib,2);
    contrib += __shfl_xor(contrib,4);
    if (n==0) A_out[s*128 + d] = f2bf(contrib + xv*Dd);
  }
}

extern "C" void kernel_launch(void* const* d_in, const int* in_sizes, int n_in,
                              void* d_out, int out_size, void* d_ws, size_t ws_size,
                              hipStream_t stream)
{
  (void)in_sizes; (void)n_in; (void)out_size; (void)ws_size;
  const float* x5d   =(const float*)d_in[0];
  const float* ln1_g =(const float*)d_in[1];
  const float* ln1_b =(const float*)d_in[2];
  const float* ln2_g =(const float*)d_in[3];
  const float* ln2_b =(const float*)d_in[4];
  const float* ln3_g =(const float*)d_in[5];
  const float* ln3_b =(const float*)d_in[6];
  const float* ln4_g =(const float*)d_in[7];
  const float* ln4_b =(const float*)d_in[8];
  const float* temp  =(const float*)d_in[9];
  const float* qkv_w =(const float*)d_in[10];
  const float* qkv_b =(const float*)d_in[11];
  const float* dw_w  =(const float*)d_in[12];
  const float* dw_b  =(const float*)d_in[13];
  const float* po_w  =(const float*)d_in[14];
  const float* po_b  =(const float*)d_in[15];
  const float* f1_ng =(const float*)d_in[16];
  const float* f1_nb =(const float*)d_in[17];
  const float* f1_bw0=(const float*)d_in[18];
  const float* f1_sw0=(const float*)d_in[19];
  const float* f1_sc0=(const float*)d_in[20];
  const float* f1_bw1=(const float*)d_in[21];
  const float* f1_sw1=(const float*)d_in[22];
  const float* f1_sc1=(const float*)d_in[23];
  const float* f2_ng =(const float*)d_in[24];
  const float* f2_nb =(const float*)d_in[25];
  const float* f2_bw0=(const float*)d_in[26];
  const float* f2_sw0=(const float*)d_in[27];
  const float* f2_sc0=(const float*)d_in[28];
  const float* f2_bw1=(const float*)d_in[29];
  const float* f2_sw1=(const float*)d_in[30];
  const float* f2_sc1=(const float*)d_in[31];
  const float* in_w  =(const float*)d_in[32];
  const float* xp_w  =(const float*)d_in[33];
  const float* dt_w  =(const float*)d_in[34];
  const float* dt_b  =(const float*)d_in[35];
  const float* A_log =(const float*)d_in[36];
  const float* Dp    =(const float*)d_in[37];
  const float* out_w =(const float*)d_in[38];
  const float* cx_w  =(const float*)d_in[39];
  const float* cz_w  =(const float*)d_in[40];
  float* out = (float*)d_out;

  const size_t T = 18432;   // B*N tokens
  char* wsb = (char*)d_ws;
  size_t off = 0;
  auto alloc = [&](size_t bytes)->void* {
    void* p = wsb + off; off += (bytes + 255) & ~(size_t)255; return p;
  };
  float* x_t    = (float*)alloc(T*128*4);
  char*  scrA   = (char*) alloc(38*1024*1024);   // shared scratch region
  float* ssS    = (float*)alloc((512+8192+8192)*4);
  float* t_t    = (float*)alloc(T*128*4);        // reused as m_t
  u16*   A1     = (u16*)  alloc(T*1152*2);
  u16*   hbuf   = (u16*)  alloc(T*512*2);
  float* xtr    = (float*)alloc(T*128*4);
  u16*   xm     = (u16*)  alloc(T*128*2);
  float* xl     = (float*)alloc(T*64*4);
  float* delta  = (float*)alloc(T*64*4);
  float* Bm     = (float*)alloc(T*8*4);
  float* Cm     = (float*)alloc(T*8*4);
  u16*   A_out  = (u16*)  alloc(T*128*2);
  float* cP     = (float*)alloc(2*96*512*4);
  float* cS     = (float*)alloc(2*96*512*4);
  float* cI     = (float*)alloc(2*96*512*4);
  u16* qkvw_bf  = (u16*)alloc(384*128*2);
  u16* pow_bf   = (u16*)alloc(128*128*2);
  u16* inw_bf   = (u16*)alloc(128*128*2);
  u16* outw_bf  = (u16*)alloc(128*128*2);
  u16* W1t_a    = (u16*)alloc(512*1152*2);
  u16* W2t_a    = (u16*)alloc(128*4608*2);
  u16* W1t_b    = (u16*)alloc(512*1152*2);
  u16* W2t_b    = (u16*)alloc(128*4608*2);
  float* Aneg   = (float*)alloc(512*4);
  float* ss = ssS;
  float* S  = ssS + 512;
  float* attnP = ssS + 512 + 8192;
  // scratch-region sub-allocations (lifetimes disjoint):
  u16*   ln1_t  = (u16*)(scrA);                              // 4.7 MB
  u16*   qkv_tb = (u16*)(scrA + 4718592);                    // 14.2 MB
  u16*   qkvd   = (u16*)(scrA + 4718592 + 14155776);         // 14.2 MB
  u16*   attnout= (u16*)(scrA + 4718592 + 2*14155776);       // 4.7 MB
  u16*   partb  = (u16*)scrA;      // 4 x T*128 bf16 = 18.9 MB (FKAN split-K partials)
  float* xz     = (float*)scrA;    // T*128 f32 (mamba, disjoint from partial use)
  float* m_t    = t_t;
  const int n4 = (int)(T*128/4);

  // ---- all weight prep + zeroing in one kernel ----
  k_pack_all<<<9636,256,0,stream>>>(
      f1_bw0,f1_sw0,f1_sc0, f2_bw0,f2_sw0,f2_sc0,
      f1_bw1,f1_sw1,f1_sc1, f2_bw1,f2_sw1,f2_sc1,
      qkv_w, po_w, in_w, out_w, A_log,
      W1t_a, W1t_b, W2t_a, W2t_b,
      qkvw_bf, pow_bf, inw_bf, outw_bf, Aneg, ssS, 512+8192);

  // ---- attention ----
  k_ln1_trans<<<dim3(144,2),256,0,stream>>>(x5d, x_t, ln1_t, ln1_g, ln1_b);
  gemm64<0,true><<<dim3(3,288,1),256,0,stream>>>(ln1_t, qkvw_bf, qkv_tb,
      18432, 384, 128, 2, 0, 1, qkv_b, nullptr);
  k_dwconv<<<dim3(144,6,2),256,0,stream>>>(qkv_tb, qkvd, dw_w, dw_b, ss);
  k_qk<<<dim3(72,4,2),256,0,stream>>>(qkvd, ss, S);
  k_softmax<<<8,32,0,stream>>>(S, attnP, temp);
  k_av<<<dim3(36,4,2),256,0,stream>>>(qkvd, attnP, attnout);
  gemm64<0,false><<<dim3(1,288,1),256,0,stream>>>(attnout, pow_bf, t_t,
      18432, 128, 128, 2, 0, 0, po_b, x_t);              // t = x + attn(ln1(x))

  // ---- FKAN 1 ----
  k_ln_double_expand<<<4608,256,0,stream>>>(t_t, A1, ln2_g, ln2_b, f1_ng, f1_nb);
  gemm64<0,true><<<dim3(4,288,1),256,0,stream>>>(A1, W1t_a, hbuf,
      18432, 512, 1152, 18, 0, 1, nullptr, nullptr);
  gemm64<512,true><<<dim3(1,288,4),256,0,stream>>>(hbuf, W2t_a, partb,
      18432, 128, 4608, 18, 1, 0, nullptr, nullptr);     // bf16 split-K partials
  k_reduce4_ln<<<2304,256,0,stream>>>((const ushort4*)partb, (const float4*)t_t,
      (const float4*)x_t, (float4*)xtr, xm, ln3_g, ln3_b, n4);
      // x_tr = t + x + kan2 ; xm = LN3(x_tr) bf16

  // ---- Mamba ----
  gemm64<0,false><<<dim3(1,288,1),256,0,stream>>>(xm, inw_bf, xz,
      18432, 128, 128, 2, 0, 0, nullptr, nullptr);
  k_mamba_pre<<<4608,256,0,stream>>>(xz, xl, delta, Bm, Cm, A_out,
      cx_w, cz_w, xp_w, dt_w, dt_b);
  k_scan1<<<dim3(96,2),512,0,stream>>>(delta, Bm, xl, Aneg, cP, cS);
  k_scan2<<<2,512,0,stream>>>(cP, cS, cI);
  k_scan3<<<dim3(96,2),512,0,stream>>>(delta, Bm, Cm, xl, Aneg, Dp, cI, A_out);
  gemm64<0,false><<<dim3(1,288,1),256,0,stream>>>(A_out, outw_bf, m_t,
      18432, 128, 128, 2, 0, 0, nullptr, xtr);           // m = mamba + x_tr

  // ---- FKAN 2 ----
  k_ln_double_expand<<<4608,256,0,stream>>>(m_t, A1, ln4_g, ln4_b, f2_ng, f2_nb);
  gemm64<0,true><<<dim3(4,288,1),256,0,stream>>>(A1, W1t_b, hbuf,
      18432, 512, 1152, 18, 0, 1, nullptr, nullptr);
  gemm64<512,true><<<dim3(1,288,4),256,0,stream>>>(hbuf, W2t_b, partb,
      18432, 128, 4608, 18, 1, 0, nullptr, nullptr);     // bf16 split-K partials
  k_reduce4_trans<<<dim3(144,2),256,0,stream>>>((const ushort4*)partb,
      (const float4*)m_t, (const float4*)xtr, out, n4);  // out = T(m + x_tr + kan2)
}

// Round 11
// 493.655 us; speedup vs baseline: 1.1418x; 1.0084x over previous
//
#include <hip/hip_runtime.h>

typedef unsigned short u16;
typedef unsigned long long u64;
typedef __attribute__((ext_vector_type(8))) short bh8;   // 8 x bf16 (4 VGPRs)
typedef __attribute__((ext_vector_type(4))) float f4;    // MFMA accumulator

#define DI __device__ __forceinline__

DI u16 f2bf(float f){ unsigned u=__float_as_uint(f); u += 0x7fffu + ((u>>16)&1u); return (u16)(u>>16); }
DI float bf2f(u16 u){ return __uint_as_float(((unsigned)u)<<16); }
DI float silu_f(float x){ return x/(1.f+__expf(-x)); }

DI void gld16(const u16* g, u16* l){
  __builtin_amdgcn_global_load_lds((const __attribute__((address_space(1))) void*)g,
                                   (__attribute__((address_space(3))) void*)l, 16, 0, 0);
}

// spline expansion -> packed 8 x bf16 (128-bit) in registers (funnel shift).
// Used ONLY in k_ln_double_expand (HBM-bound A1 materialization) where it beat
// branchless-8 [r10]. In-GEMM LDS staging uses the scatter instead (measured:
// scatter 50.0us < pack 52.7us < branchless 58.4us for the L2-KAN GEMM).
DI void bspline_pack(float x, u64& lo, u64& hi){
  float u = x*2.5f + 5.5f;
  bool valid = (u >= 0.f) & (u < 11.f);
  float uc = fminf(fmaxf(u, 0.f), 10.999f);
  int mi = (int)uc;                  // 0..10
  float tt = uc - (float)mi;
  float omt = 1.f - tt, t2 = tt*tt, t3 = t2*tt;
  float w0 = omt*omt*omt*(1.f/6.f);
  float w3 = t3*(1.f/6.f);
  float w1 = 0.5f*t3 - t2 + (2.f/3.f);
  float w2 = 1.f - w0 - w1 - w3;
  u64 wblk = 0;
  if (valid) {
    unsigned a32 = (unsigned)f2bf(w0) | ((unsigned)f2bf(w1)<<16);
    unsigned b32 = (unsigned)f2bf(w2) | ((unsigned)f2bf(w3)<<16);
    wblk = (u64)a32 | ((u64)b32<<32);
  }
  int sh = (mi-3)*16;                // -48..112
  if (sh >= 0) {
    lo = (sh < 64) ? (wblk << sh) : 0ull;
    hi = (sh == 0) ? 0ull
       : (sh < 64) ? (wblk >> (64 - sh))
                   : (wblk << (sh - 64));
  } else {
    lo = wblk >> (-sh);
    hi = 0ull;
  }
}

// ---------------- GEMM (MRx128 tile, 4 waves): C = A(MxK) * Bt(NxK)^T ----------------
// MR=64 (default): wave w owns rows 0..63 x cols w*32..w*32+31, 4x2 acc [best: r4-r10].
// MR=32: half tile for grid-starved small GEMMs (N=128, grid 288->576 blocks).
// BK=64. lb(256,4) measured best [r4 vs r7].
// swz!=0: XCD-aware (bx,by) remap — N-tiles sharing an A-row-block land on one XCD
// [r9: ~-8us]. LDS: sB(128x64) | sA(MRx64) | dump. 16B chunks XOR-swizzled
// (chunk c of row r at c^(r&7)); global_load_lds lanes fetch permuted chunks.
// KAN_H>0: A generated from h (M x KAN_H bf16): cols [0,KAN_H)=silu(h), rest=spline
// via zero-fill + 4-nonzero-weight scatter (measured best of 3 variants, see above).
// OUT_BF16: bf16 output staged via LDS -> 256B full-cacheline stores (no RMW
// amplification [r5-r8]). split!=0 offsets output by blockIdx.z*M*N.
template<int KAN_H, bool OUT_BF16, int MR>
__global__ __launch_bounds__(256, 4)
void gemm64(const void* __restrict__ Asrc, const u16* __restrict__ Bt,
            void* __restrict__ Cout, int M, int N, int K, int ktiles_per_z,
            int split, int swz, const float* __restrict__ bias, const float* __restrict__ R1)
{
  constexpr int MI  = MR/16;       // acc rows
  constexpr int AIT = MR/32;       // A-staging iterations
  __shared__ __align__(128) u16 smem[8192 + MR*64 + 8];  // sB | sA | dump
  u16* const sB = smem;
  u16* const sA = smem + 8192;
  int bx = blockIdx.x, by = blockIdx.y;
  if (swz) {
    const int NX = gridDim.x, NY = gridDim.y;
    int lin = bx + NX*by;
    int k8 = lin & 7, g = lin >> 3;
    by = k8*(NY>>3) + g/NX;
    bx = g%NX;
  }
  const int m0 = by * MR;
  const int n0 = bx * 128;
  const int ktiles = K >> 6;
  int kt0 = blockIdx.z * ktiles_per_z;
  int kt1 = kt0 + ktiles_per_z; if (kt1 > ktiles) kt1 = ktiles;
  const int t = threadIdx.x;
  const int wave = t >> 6, lane = t & 63;
  const int lr = lane & 15, lq = lane >> 4;
  const int lr8 = lane >> 3, lc8 = lane & 7;
  const int swz8 = lc8 ^ lr8;      // swizzled global chunk for this lane (row&7 == lr8)
  f4 acc[MI][2];
  f4 z4 = {0.f,0.f,0.f,0.f};
  #pragma unroll
  for (int i=0;i<MI;i++){ acc[i][0]=z4; acc[i][1]=z4; }

  for (int kt = kt0; kt < kt1; ++kt) {
    int k0 = kt << 6;
    // stage Bt tile (128 rows) via async global->LDS, swizzled
    {
      const u16* Bp = Bt + (size_t)n0 * K + k0;
      #pragma unroll
      for (int it=0; it<4; ++it) {
        int r = it*32 + wave*8;
        gld16(Bp + (size_t)(r + lr8) * K + swz8*8, &sB[r*64]);
      }
    }
    // stage A tile (MR rows)
    if (KAN_H == 0) {
      const u16* Ap = (const u16*)Asrc + (size_t)m0 * K + k0;
      #pragma unroll
      for (int it=0; it<AIT; ++it) {
        int r = it*32 + wave*8;
        gld16(Ap + (size_t)(r + lr8) * K + swz8*8, &sA[r*64]);
      }
    } else {
      const u16* hsrc = (const u16*)Asrc;
      if (k0 < KAN_H) {
        // silu region: MR rows x 64 cols = MR*8 chunks of 8
        #pragma unroll
        for (int it=0; it<AIT; ++it) {
          int chunk = t + it*256;
          int r = chunk >> 3, ck = chunk & 7;
          const u16* src = hsrc + (size_t)(m0+r)*KAN_H + k0 + ck*8;
          ushort4 a = *(const ushort4*)src;
          ushort4 b2 = *(const ushort4*)(src+4);
          alignas(16) u16 o[8];
          o[0]=f2bf(silu_f(bf2f(a.x))); o[1]=f2bf(silu_f(bf2f(a.y)));
          o[2]=f2bf(silu_f(bf2f(a.z))); o[3]=f2bf(silu_f(bf2f(a.w)));
          o[4]=f2bf(silu_f(bf2f(b2.x))); o[5]=f2bf(silu_f(bf2f(b2.y)));
          o[6]=f2bf(silu_f(bf2f(b2.z))); o[7]=f2bf(silu_f(bf2f(b2.w)));
          *(float4*)(&sA[r*64 + (ck ^ (r&7))*8]) = *(const float4*)o;
        }
      } else {
        // spline region: (row, feature) -> 8 bases, only 4 nonzero: zero-fill + scatter
        int i0 = (k0 - KAN_H) >> 3;
        const float4 zf4 = make_float4(0.f,0.f,0.f,0.f);
        #pragma unroll
        for (int it=0; it<AIT; ++it) {
          int pair = t + it*256;
          int r = pair >> 3, ii = pair & 7;
          int base = r*64 + (ii ^ (r&7))*8;
          *(float4*)(&sA[base]) = zf4;             // zero-fill the 8 bases
          float x = bf2f(hsrc[(size_t)(m0+r)*KAN_H + i0 + ii]);
          float u = x*2.5f + 5.5f;
          bool valid = (u >= 0.f) & (u < 11.f);
          int m = (int)u;                          // out-of-range gated by valid+c-range
          float tt = u - (float)m;
          float omt = 1.f - tt, t2 = tt*tt, t3 = t2*tt;
          float w0 = omt*omt*omt*(1.f/6.f);
          float w3 = t3*(1.f/6.f);
          float w1 = 0.5f*t3 - t2 + (2.f/3.f);
          float w2 = 1.f - w0 - w1 - w3;
          float ws[4] = {w0, w1, w2, w3};
          int c0 = m - 3;
          #pragma unroll
          for (int j=0;j<4;j++){
            int c = c0 + j;
            bool ok = valid & ((unsigned)c < 8u);
            int off = ok ? (base + c) : (MR*64);  // dump slot
            sA[off] = f2bf(ws[j]);
          }
        }
      }
    }
    __syncthreads();
    #pragma unroll
    for (int kk=0; kk<64; kk+=32) {
      const int c0k = kk >> 3;
      bh8 af[MI], bfr[2];
      #pragma unroll
      for (int i=0;i<MI;i++) {
        int row = i*16 + lr;
        af[i] = *(const bh8*)(&sA[row*64 + ((c0k+lq) ^ (row&7))*8]);
      }
      #pragma unroll
      for (int j=0;j<2;j++) {
        int row = wave*32 + j*16 + lr;
        bfr[j] = *(const bh8*)(&sB[row*64 + ((c0k+lq) ^ (row&7))*8]);
      }
      #pragma unroll
      for (int i=0;i<MI;i++)
        #pragma unroll
        for (int j=0;j<2;j++)
          acc[i][j] = __builtin_amdgcn_mfma_f32_16x16x32_bf16(af[i], bfr[j], acc[i][j], 0, 0, 0);
    }
    __syncthreads();
  }
  // epilogue: C/D layout col=lane&15, row=(lane>>4)*4+reg
  if (OUT_BF16) {
    // stage bf16 tile (MR x 128, stride 136) in LDS -> 256B-contiguous stores
    u16* Cb = (u16*)Cout;
    if (split) Cb += (size_t)blockIdx.z * M * N;
    #pragma unroll
    for (int i=0;i<MI;i++) {
      #pragma unroll
      for (int j=0;j<2;j++) {
        int col = wave*32 + j*16 + lr;
        float bv = bias ? bias[n0 + col] : 0.f;
        #pragma unroll
        for (int r4=0;r4<4;r4++) {
          int row = i*16 + lq*4 + r4;
          smem[row*136 + col] = f2bf(acc[i][j][r4] + bv);
        }
      }
    }
    __syncthreads();
    #pragma unroll
    for (int it=0; it<MI; ++it) {
      int idx = t + it*256;
      int row = idx >> 4, seg = idx & 15;
      *(float4*)(Cb + (size_t)(m0+row)*N + n0 + seg*8) =
          *(const float4*)&smem[row*136 + seg*8];
    }
  } else {
    float* Cf = (float*)Cout;
    if (split) Cf += (size_t)blockIdx.z * M * N;
    #pragma unroll
    for (int i=0;i<MI;i++) {
      int row = m0 + i*16 + lq*4;
      #pragma unroll
      for (int j=0;j<2;j++) {
        int col = n0 + wave*32 + j*16 + lr;
        float bv = bias ? bias[col] : 0.f;
        #pragma unroll
        for (int r4=0;r4<4;r4++) {
          size_t idx = (size_t)(row + r4) * N + col;
          float v = acc[i][j][r4] + bv;
          if (R1) v += R1[idx];
          Cf[idx] = v;
        }
      }
    }
  }
}

// ---------------- transpose + LN1: x5d (B,C,N) -> x_t (B,N,C) f32 and ln1_t bf16 ----------------
__global__ __launch_bounds__(256) void k_ln1_trans(const float* __restrict__ x5d,
    float* __restrict__ x_t, u16* __restrict__ ln1_t,
    const float* __restrict__ g, const float* __restrict__ bv)
{
  __shared__ float tile[128*65];
  __shared__ float red_s[256], red_q[256];
  __shared__ float st_mu[64], st_rs[64];
  int b = blockIdx.y, n0 = blockIdx.x * 64;
  int j = threadIdx.x & 63, part = threadIdx.x >> 6;
  for (int cc=0; cc<32; ++cc) {
    int c = part*32 + cc;
    tile[c*65 + j] = x5d[((size_t)b*128 + c)*9216 + n0 + j];
  }
  __syncthreads();
  float s=0.f, s2=0.f;
  for (int cc=0; cc<32; ++cc) {
    float v = tile[(part*32+cc)*65 + j];
    s += v; s2 += v*v;
  }
  red_s[threadIdx.x]=s; red_q[threadIdx.x]=s2;
  __syncthreads();
  if (threadIdx.x < 64) {
    int jj = threadIdx.x;
    float ts = red_s[jj]+red_s[jj+64]+red_s[jj+128]+red_s[jj+192];
    float tq = red_q[jj]+red_q[jj+64]+red_q[jj+128]+red_q[jj+192];
    float mu = ts*(1.f/128.f);
    st_mu[jj]=mu;
    st_rs[jj]=rsqrtf(tq*(1.f/128.f) - mu*mu + 1e-5f);
  }
  __syncthreads();
  for (int it=0; it<32; ++it) {
    int idx = threadIdx.x + it*256;
    int tok = idx >> 7, c = idx & 127;
    float v = tile[c*65 + tok];
    size_t a = ((size_t)b*9216 + n0 + tok)*128 + c;
    x_t[a] = v;
    ln1_t[a] = f2bf((v - st_mu[tok])*st_rs[tok]*g[c] + bv[c]);
  }
}

// ---------------- double LN + KAN expansion: writes A1 (T x 1152 bf16) ----------------
__global__ void k_ln_double_expand(const float* __restrict__ in, u16* __restrict__ A1,
    const float* __restrict__ g1, const float* __restrict__ b1,
    const float* __restrict__ g2, const float* __restrict__ b2)
{
  int tok = blockIdx.x*4 + (threadIdx.x>>6);
  int lane = threadIdx.x & 63;
  const float* row = in + (size_t)tok*128;
  float v0=row[lane], v1=row[lane+64];
  float s=v0+v1, s2=v0*v0+v1*v1;
  #pragma unroll
  for (int o=1;o<64;o<<=1){ s += __shfl_xor(s,o); s2 += __shfl_xor(s2,o); }
  float mu=s*(1.f/128.f);
  float rs=rsqrtf(s2*(1.f/128.f)-mu*mu+1e-5f);
  float y0=(v0-mu)*rs*g1[lane]+b1[lane];
  float y1=(v1-mu)*rs*g1[lane+64]+b1[lane+64];
  s=y0+y1; s2=y0*y0+y1*y1;
  #pragma unroll
  for (int o=1;o<64;o<<=1){ s += __shfl_xor(s,o); s2 += __shfl_xor(s2,o); }
  mu=s*(1.f/128.f);
  rs=rsqrtf(s2*(1.f/128.f)-mu*mu+1e-5f);
  y0=(y0-mu)*rs*g2[lane]+b2[lane];
  y1=(y1-mu)*rs*g2[lane+64]+b2[lane+64];
  u16* arow = A1 + (size_t)tok*1152;
  arow[lane]    = f2bf(silu_f(y0));
  arow[lane+64] = f2bf(silu_f(y1));
  u64 lo, hi;
  bspline_pack(y0, lo, hi);
  alignas(16) u64 o2[2] = {lo, hi};
  *(float4*)(&arow[128 + lane*8]) = *(const float4*)o2;
  bspline_pack(y1, lo, hi);
  alignas(16) u64 o3[2] = {lo, hi};
  *(float4*)(&arow[128 + (lane+64)*8]) = *(const float4*)o3;
}

// ---------------- depthwise 3x3 conv + fused q/k sumsq (normsum) ----------------
__global__ __launch_bounds__(256) void k_dwconv(const u16* __restrict__ qkv_t,
    u16* __restrict__ qkvd, const float* __restrict__ dw_w, const float* __restrict__ dw_b,
    float* __restrict__ ss)
{
  __shared__ float lt[100*68];
  int tile = blockIdx.x; int th=(tile/12)*8, tw=(tile%12)*8;
  int cg = blockIdx.y, b = blockIdx.z;
  int t = threadIdx.x;
  for (int pp=0; pp<7; ++pp) {
    int pos = pp*16 + (t>>4);
    if (pos < 100) {
      int ih = th + pos/10 - 1, iw = tw + pos%10 - 1;
      int c4 = (t & 15)*4;
      float4 v = make_float4(0.f,0.f,0.f,0.f);
      if (ih>=0 && ih<96 && iw>=0 && iw<96) {
        ushort4 raw = *(const ushort4*)&qkv_t[(((size_t)b*9216) + ih*96 + iw)*384 + cg*64 + c4];
        v = make_float4(bf2f(raw.x), bf2f(raw.y), bf2f(raw.z), bf2f(raw.w));
      }
      *(float4*)&lt[pos*68 + c4] = v;
    }
  }
  __syncthreads();
  int ch = t & 63, gch = cg*64 + ch;
  float w[9];
  #pragma unroll
  for (int k=0;k<9;k++) w[k]=dw_w[gch*9+k];
  float bias = dw_b[gch];
  float sq = 0.f;
  for (int pp=0; pp<16; ++pp) {
    int pos = (t>>6) + pp*4;
    int oh = pos>>3, ow = pos&7;
    float acc = bias;
    #pragma unroll
    for (int di=0; di<3; ++di)
      #pragma unroll
      for (int dj=0; dj<3; ++dj)
        acc += lt[((oh+di)*10 + ow+dj)*68 + ch] * w[di*3+dj];
    sq += acc*acc;
    qkvd[(((size_t)b*9216) + (th+oh)*96 + tw+ow)*384 + gch] = f2bf(acc);
  }
  if (cg < 4) {     // q (cg 0,1) and k (cg 2,3) channels need sum-of-squares over n
    __syncthreads();
    lt[(t>>6)*64 + ch] = sq;
    __syncthreads();
    if (t < 64) {
      float s = lt[t] + lt[64+t] + lt[128+t] + lt[192+t];
      atomicAdd(&ss[b*256 + cg*64 + t], s);
    }
  }
}

// ---------------- partial q@k^T with normalization, atomic into S ----------------
__global__ __launch_bounds__(256) void k_qk(const u16* __restrict__ qkvd,
    const float* __restrict__ ss, float* __restrict__ S)
{
  __shared__ float ql[128][32];
  __shared__ float kl[128][32];
  int nc=blockIdx.x, h=blockIdx.y, b=blockIdx.z;
  int t = threadIdx.x;
  int r = t>>1, half = t&1;
  size_t rowa = ((size_t)b*9216 + nc*128 + r)*384 + (half?128:0) + h*32;
  #pragma unroll
  for (int cc=0; cc<32; ++cc) {
    float v = bf2f(qkvd[rowa + cc]);
    if (half) kl[r][cc]=v; else ql[r][cc]=v;
  }
  __syncthreads();
  int i0 = (t>>4)*2, j0 = (t&15)*2;
  float a00=0.f,a01=0.f,a10=0.f,a11=0.f;
  for (int n=0;n<128;++n){
    float2 qv = *(const float2*)&ql[n][i0];
    float2 kv = *(const float2*)&kl[n][j0];
    a00 += qv.x*kv.x; a01 += qv.x*kv.y;
    a10 += qv.y*kv.x; a11 += qv.y*kv.y;
  }
  const float* ssb = ss + b*256;
  float rq0 = 1.f/fmaxf(sqrtf(ssb[h*32+i0]),1e-12f);
  float rq1 = 1.f/fmaxf(sqrtf(ssb[h*32+i0+1]),1e-12f);
  float rk0 = 1.f/fmaxf(sqrtf(ssb[128+h*32+j0]),1e-12f);
  float rk1 = 1.f/fmaxf(sqrtf(ssb[128+h*32+j0+1]),1e-12f);
  float* Sp = S + ((size_t)(b*4+h))*1024;
  atomicAdd(&Sp[i0*32+j0],     a00*rq0*rk0);
  atomicAdd(&Sp[i0*32+j0+1],   a01*rq0*rk1);
  atomicAdd(&Sp[(i0+1)*32+j0], a10*rq1*rk0);
  atomicAdd(&Sp[(i0+1)*32+j0+1], a11*rq1*rk1);
}

// ---------------- softmax over 32 cols per row, with per-head temp ----------------
__global__ void k_softmax(const float* __restrict__ S, float* __restrict__ attnP,
                          const float* __restrict__ temp)
{
  int bh = blockIdx.x; int h = bh & 3;
  int i = threadIdx.x;
  const float* row = S + (size_t)bh*1024 + i*32;
  float tp = temp[h];
  float vals[32]; float mx = -1e30f;
  #pragma unroll
  for (int j=0;j<32;++j){ float v=row[j]*tp; vals[j]=v; mx=fmaxf(mx,v); }
  float sum=0.f;
  #pragma unroll
  for (int j=0;j<32;++j){ vals[j]=__expf(vals[j]-mx); sum+=vals[j]; }
  float inv=1.f/sum;
  float* out = attnP + (size_t)bh*1024 + i*32;
  #pragma unroll
  for (int j=0;j<32;++j) out[j]=vals[j]*inv;
}

// ---------------- out = attn @ v, token-major bf16 out ----------------
__global__ __launch_bounds__(256) void k_av(const u16* __restrict__ qkvd,
    const float* __restrict__ attnP, u16* __restrict__ attnout)
{
  __shared__ float at[1024];
  int b=blockIdx.z, h=blockIdx.y;
  int n = blockIdx.x*256 + threadIdx.x;
  #pragma unroll
  for (int it=0;it<4;++it)
    at[threadIdx.x + it*256] = attnP[((size_t)(b*4+h))*1024 + threadIdx.x + it*256];
  __syncthreads();
  const u16* vrow = &qkvd[((size_t)b*9216 + n)*384 + 256 + h*32];
  float acc[32];
  #pragma unroll
  for (int i=0;i<32;++i) acc[i]=0.f;
  #pragma unroll 4
  for (int j=0;j<32;++j){
    float vj = bf2f(vrow[j]);
    #pragma unroll
    for (int i=0;i<32;++i) acc[i] += at[i*32+j]*vj;
  }
  u16* orow = &attnout[((size_t)b*9216 + n)*128 + h*32];
  #pragma unroll
  for (int i=0;i<32;++i) orow[i] = f2bf(acc[i]);
}

// ---------------- fused: xtr = R1+R2+4 bf16 partials ; xm = LN(xtr) bf16 ----------------
__global__ void k_reduce4_ln(const ushort4* __restrict__ P, const float4* __restrict__ R1,
    const float4* __restrict__ R2, float4* __restrict__ xtr, u16* __restrict__ xm,
    const float* __restrict__ g, const float* __restrict__ bv, int n4)
{
  int i = blockIdx.x*256 + threadIdx.x;
  int q = i & 31;
  ushort4 a=P[i], b=P[i+n4], c=P[i+2*n4], d=P[i+3*n4];
  float4 r=R1[i], s=R2[i];
  float4 v=make_float4(bf2f(a.x)+bf2f(b.x)+bf2f(c.x)+bf2f(d.x)+r.x+s.x,
                       bf2f(a.y)+bf2f(b.y)+bf2f(c.y)+bf2f(d.y)+r.y+s.y,
                       bf2f(a.z)+bf2f(b.z)+bf2f(c.z)+bf2f(d.z)+r.z+s.z,
                       bf2f(a.w)+bf2f(b.w)+bf2f(c.w)+bf2f(d.w)+r.w+s.w);
  xtr[i]=v;
  float s1 = v.x+v.y+v.z+v.w;
  float s2 = v.x*v.x+v.y*v.y+v.z*v.z+v.w*v.w;
  #pragma unroll
  for (int o=1;o<32;o<<=1){ s1 += __shfl_xor(s1,o); s2 += __shfl_xor(s2,o); }
  float mu = s1*(1.f/128.f);
  float rs = rsqrtf(s2*(1.f/128.f)-mu*mu+1e-5f);
  float4 g4 = *(const float4*)(g + q*4);
  float4 b4 = *(const float4*)(bv + q*4);
  ushort4 o4;
  o4.x = f2bf((v.x-mu)*rs*g4.x + b4.x);
  o4.y = f2bf((v.y-mu)*rs*g4.y + b4.y);
  o4.z = f2bf((v.z-mu)*rs*g4.z + b4.z);
  o4.w = f2bf((v.w-mu)*rs*g4.w + b4.w);
  ((ushort4*)xm)[i] = o4;
}

// ---------------- fused final: out(B,C,N) = transpose(R1 + R2 + 4 bf16 partials) ------
__global__ __launch_bounds__(256) void k_reduce4_trans(const ushort4* __restrict__ P,
    const float4* __restrict__ R1, const float4* __restrict__ R2,
    float* __restrict__ out, int n4)
{
  __shared__ float tile[128*65];
  int b=blockIdx.y, n0=blockIdx.x*64;
  for (int it=0; it<8; ++it) {            // 64 tokens x 32 float4 = 2048
    int idx = threadIdx.x + it*256;
    int tok = idx >> 5, c4 = idx & 31;
    int gi = (b*9216 + n0 + tok)*32 + c4;
    ushort4 a=P[gi], bb=P[gi+n4], c=P[gi+2*n4], d=P[gi+3*n4];
    float4 r=R1[gi], s=R2[gi];
    tile[(c4*4+0)*65+tok] = bf2f(a.x)+bf2f(bb.x)+bf2f(c.x)+bf2f(d.x)+r.x+s.x;
    tile[(c4*4+1)*65+tok] = bf2f(a.y)+bf2f(bb.y)+bf2f(c.y)+bf2f(d.y)+r.y+s.y;
    tile[(c4*4+2)*65+tok] = bf2f(a.z)+bf2f(bb.z)+bf2f(c.z)+bf2f(d.z)+r.z+s.z;
    tile[(c4*4+3)*65+tok] = bf2f(a.w)+bf2f(bb.w)+bf2f(c.w)+bf2f(d.w)+r.w+s.w;
  }
  __syncthreads();
  int j = threadIdx.x & 63, part = threadIdx.x>>6;
  for (int cc=0;cc<32;++cc){
    int c = part*32+cc;
    out[((size_t)b*128 + c)*9216 + n0 + j] = tile[c*65 + j];
  }
}

// ---------------- one fused prep kernel: all weight packs + Aneg + zeroing ----------------
__global__ void k_pack_all(
    const float* __restrict__ f1_bw0, const float* __restrict__ f1_sw0, const float* __restrict__ f1_sc0,
    const float* __restrict__ f2_bw0, const float* __restrict__ f2_sw0, const float* __restrict__ f2_sc0,
    const float* __restrict__ f1_bw1, const float* __restrict__ f1_sw1, const float* __restrict__ f1_sc1,
    const float* __restrict__ f2_bw1, const float* __restrict__ f2_sw1, const float* __restrict__ f2_sc1,
    const float* __restrict__ qkv_w, const float* __restrict__ po_w,
    const float* __restrict__ in_w, const float* __restrict__ out_w,
    const float* __restrict__ A_log,
    u16* __restrict__ W1t_a, u16* __restrict__ W1t_b,
    u16* __restrict__ W2t_a, u16* __restrict__ W2t_b,
    u16* __restrict__ qkvw_bf, u16* __restrict__ pow_bf,
    u16* __restrict__ inw_bf, u16* __restrict__ outw_bf,
    float* __restrict__ Aneg, float* __restrict__ zbuf, int nz)
{
  int i = blockIdx.x*256 + threadIdx.x;
  const int NW1 = 512*1152, NW2 = 128*4608;
  if (i < NW1) {
    int o = i/1152, k = i%1152; float v;
    if (k < 128) v = f1_bw0[o*128+k];
    else { int f=(k-128)>>3, c=(k-128)&7; v = f1_sw0[(o*128+f)*8+c]*f1_sc0[o*128+f]; }
    W1t_a[i]=f2bf(v); return;
  }
  i -= NW1;
  if (i < NW1) {
    int o = i/1152, k = i%1152; float v;
    if (k < 128) v = f2_bw0[o*128+k];
    else { int f=(k-128)>>3, c=(k-128)&7; v = f2_sw0[(o*128+f)*8+c]*f2_sc0[o*128+f]; }
    W1t_b[i]=f2bf(v); return;
  }
  i -= NW1;
  if (i < NW2) {
    int o = i/4608, k = i%4608; float v;
    if (k < 512) v = f1_bw1[o*512+k];
    else { int f=(k-512)>>3, c=(k-512)&7; v = f1_sw1[(o*512+f)*8+c]*f1_sc1[o*512+f]; }
    W2t_a[i]=f2bf(v); return;
  }
  i -= NW2;
  if (i < NW2) {
    int o = i/4608, k = i%4608; float v;
    if (k < 512) v = f2_bw1[o*512+k];
    else { int f=(k-512)>>3, c=(k-512)&7; v = f2_sw1[(o*512+f)*8+c]*f2_sc1[o*512+f]; }
    W2t_b[i]=f2bf(v); return;
  }
  i -= NW2;
  if (i < 49152) { qkvw_bf[i] = f2bf(qkv_w[i]); return; }
  i -= 49152;
  if (i < 16384) { pow_bf[i] = f2bf(po_w[i]); return; }
  i -= 16384;
  if (i < 16384) { inw_bf[i] = f2bf(in_w[i]); return; }
  i -= 16384;
  if (i < 16384) { outw_bf[i] = f2bf(out_w[i]); return; }
  i -= 16384;
  if (i < 512) { Aneg[i] = -__expf(A_log[i]); return; }
  i -= 512;
  if (i < nz) zbuf[i] = 0.f;
}

// ---------------- mamba pre: conv1d+silu for x/z, x_proj, delta ----------------
__global__ __launch_bounds__(256) void k_mamba_pre(const float* __restrict__ xz,
    float* __restrict__ xl, float* __restrict__ delta,
    float* __restrict__ Bm, float* __restrict__ Cm, u16* __restrict__ A_out,
    const float* __restrict__ cxw, const float* __restrict__ czw,
    const float* __restrict__ xpw, const float* __restrict__ dtw, const float* __restrict__ dtb)
{
  __shared__ float xls[4][64];
  __shared__ float xds[4][24];
  int w = threadIdx.x>>6;
  int tok = blockIdx.x*4 + w;
  int lane = threadIdx.x & 63;
  int l = tok % 9216;
  size_t base = (size_t)tok*128;
  float xm1 = (l>0)?     xz[base-128+lane]    : 0.f;
  float x0  =            xz[base+lane];
  float xp1 = (l<9215)?  xz[base+128+lane]    : 0.f;
  float zm1 = (l>0)?     xz[base-128+64+lane] : 0.f;
  float z0  =            xz[base+64+lane];
  float zp1 = (l<9215)?  xz[base+128+64+lane] : 0.f;
  float xc = silu_f(cxw[lane*3]*xm1 + cxw[lane*3+1]*x0 + cxw[lane*3+2]*xp1);
  float zc = silu_f(czw[lane*3]*zm1 + czw[lane*3+1]*z0 + czw[lane*3+2]*zp1);
  xl[(size_t)tok*64+lane] = xc;
  A_out[(size_t)tok*128 + 64 + lane] = f2bf(zc);
  xls[w][lane] = xc;
  __syncthreads();
  if (lane < 24) {
    float s=0.f;
    #pragma unroll 8
    for (int c=0;c<64;++c) s += xls[w][c]*xpw[lane*64+c];
    xds[w][lane]=s;
  }
  __syncthreads();
  float dacc = dtb[lane];
  #pragma unroll
  for (int r=0;r<8;++r) dacc += xds[w][r]*dtw[lane*8+r];
  delta[(size_t)tok*64+lane] = (dacc>20.f)? dacc : log1pf(__expf(dacc));
  if (lane<8)       Bm[(size_t)tok*8+lane]   = xds[w][8+lane];
  else if (lane<16) Cm[(size_t)tok*8+lane-8] = xds[w][16+lane-8];
}

// ---------------- chunked scan ----------------
__global__ __launch_bounds__(512) void k_scan1(const float* __restrict__ delta,
    const float* __restrict__ Bm, const float* __restrict__ xl,
    const float* __restrict__ Aneg, float* __restrict__ cP, float* __restrict__ cS)
{
  int b=blockIdx.y, ch=blockIdx.x;
  int t=threadIdx.x; int d=t>>3, n=t&7;
  float An = Aneg[d*8+n];
  float P=1.f, S=0.f;
  int l0 = ch*96;
  #pragma unroll 8
  for (int i=0;i<96;++i){
    size_t s = (size_t)b*9216 + l0+i;
    float del = delta[s*64+d];
    float a = __expf(del*An);
    float dbu = del * Bm[s*8+n] * xl[s*64+d];
    P *= a; S = fmaf(a,S,dbu);
  }
  size_t o = ((size_t)(b*96+ch))*512 + t;
  cP[o]=P; cS[o]=S;
}

__global__ __launch_bounds__(512) void k_scan2(const float* __restrict__ cP,
    const float* __restrict__ cS, float* __restrict__ cI)
{
  int b=blockIdx.x; int t=threadIdx.x;
  float carry=0.f;
  #pragma unroll 4
  for (int c=0;c<96;++c){
    size_t o = ((size_t)(b*96+c))*512 + t;
    cI[o]=carry;
    carry = fmaf(cP[o], carry, cS[o]);
  }
}

__global__ __launch_bounds__(512) void k_scan3(const float* __restrict__ delta,
    const float* __restrict__ Bm, const float* __restrict__ Cm,
    const float* __restrict__ xl, const float* __restrict__ Aneg,
    const float* __restrict__ Dp, const float* __restrict__ cI, u16* __restrict__ A_out)
{
  int b=blockIdx.y, ch=blockIdx.x;
  int t=threadIdx.x; int d=t>>3, n=t&7;
  float An = Aneg[d*8+n];
  float h = cI[((size_t)(b*96+ch))*512 + t];
  float Dd = Dp[d];
  int l0 = ch*96;
  #pragma unroll 4
  for (int i=0;i<96;++i){
    size_t s = (size_t)b*9216 + l0+i;
    float del = delta[s*64+d];
    float a = __expf(del*An);
    float xv = xl[s*64+d];
    h = fmaf(a, h, del * Bm[s*8+n] * xv);
    float contrib = h * Cm[s*8+n];
    contrib += __shfl_xor(contrib,1);
    contrib += __shfl_xor(contrib,2);
    contrib += __shfl_xor(contrib,4);
    if (n==0) A_out[s*128 + d] = f2bf(contrib + xv*Dd);
  }
}

extern "C" void kernel_launch(void* const* d_in, const int* in_sizes, int n_in,
                              void* d_out, int out_size, void* d_ws, size_t ws_size,
                              hipStream_t stream)
{
  (void)in_sizes; (void)n_in; (void)out_size; (void)ws_size;
  const float* x5d   =(const float*)d_in[0];
  const float* ln1_g =(const float*)d_in[1];
  const float* ln1_b =(const float*)d_in[2];
  const float* ln2_g =(const float*)d_in[3];
  const float* ln2_b =(const float*)d_in[4];
  const float* ln3_g =(const float*)d_in[5];
  const float* ln3_b =(const float*)d_in[6];
  const float* ln4_g =(const float*)d_in[7];
  const float* ln4_b =(const float*)d_in[8];
  const float* temp  =(const float*)d_in[9];
  const float* qkv_w =(const float*)d_in[10];
  const float* qkv_b =(const float*)d_in[11];
  const float* dw_w  =(const float*)d_in[12];
  const float* dw_b  =(const float*)d_in[13];
  const float* po_w  =(const float*)d_in[14];
  const float* po_b  =(const float*)d_in[15];
  const float* f1_ng =(const float*)d_in[16];
  const float* f1_nb =(const float*)d_in[17];
  const float* f1_bw0=(const float*)d_in[18];
  const float* f1_sw0=(const float*)d_in[19];
  const float* f1_sc0=(const float*)d_in[20];
  const float* f1_bw1=(const float*)d_in[21];
  const float* f1_sw1=(const float*)d_in[22];
  const float* f1_sc1=(const float*)d_in[23];
  const float* f2_ng =(const float*)d_in[24];
  const float* f2_nb =(const float*)d_in[25];
  const float* f2_bw0=(const float*)d_in[26];
  const float* f2_sw0=(const float*)d_in[27];
  const float* f2_sc0=(const float*)d_in[28];
  const float* f2_bw1=(const float*)d_in[29];
  const float* f2_sw1=(const float*)d_in[30];
  const float* f2_sc1=(const float*)d_in[31];
  const float* in_w  =(const float*)d_in[32];
  const float* xp_w  =(const float*)d_in[33];
  const float* dt_w  =(const float*)d_in[34];
  const float* dt_b  =(const float*)d_in[35];
  const float* A_log =(const float*)d_in[36];
  const float* Dp    =(const float*)d_in[37];
  const float* out_w =(const float*)d_in[38];
  const float* cx_w  =(const float*)d_in[39];
  const float* cz_w  =(const float*)d_in[40];
  float* out = (float*)d_out;

  const size_t T = 18432;   // B*N tokens
  char* wsb = (char*)d_ws;
  size_t off = 0;
  auto alloc = [&](size_t bytes)->void* {
    void* p = wsb + off; off += (bytes + 255) & ~(size_t)255; return p;
  };
  float* x_t    = (float*)alloc(T*128*4);
  char*  scrA   = (char*) alloc(38*1024*1024);   // shared scratch region
  float* ssS    = (float*)alloc((512+8192+8192)*4);
  float* t_t    = (float*)alloc(T*128*4);        // reused as m_t
  u16*   A1     = (u16*)  alloc(T*1152*2);
  u16*   hbuf   = (u16*)  alloc(T*512*2);
  float* xtr    = (float*)alloc(T*128*4);
  u16*   xm     = (u16*)  alloc(T*128*2);
  float* xl     = (float*)alloc(T*64*4);
  float* delta  = (float*)alloc(T*64*4);
  float* Bm     = (float*)alloc(T*8*4);
  float* Cm     = (float*)alloc(T*8*4);
  u16*   A_out  = (u16*)  alloc(T*128*2);
  float* cP     = (float*)alloc(2*96*512*4);
  float* cS     = (float*)alloc(2*96*512*4);
  float* cI     = (float*)alloc(2*96*512*4);
  u16* qkvw_bf  = (u16*)alloc(384*128*2);
  u16* pow_bf   = (u16*)alloc(128*128*2);
  u16* inw_bf   = (u16*)alloc(128*128*2);
  u16* outw_bf  = (u16*)alloc(128*128*2);
  u16* W1t_a    = (u16*)alloc(512*1152*2);
  u16* W2t_a    = (u16*)alloc(128*4608*2);
  u16* W1t_b    = (u16*)alloc(512*1152*2);
  u16* W2t_b    = (u16*)alloc(128*4608*2);
  float* Aneg   = (float*)alloc(512*4);
  float* ss = ssS;
  float* S  = ssS + 512;
  float* attnP = ssS + 512 + 8192;
  // scratch-region sub-allocations (lifetimes disjoint):
  u16*   ln1_t  = (u16*)(scrA);                              // 4.7 MB
  u16*   qkv_tb = (u16*)(scrA + 4718592);                    // 14.2 MB
  u16*   qkvd   = (u16*)(scrA + 4718592 + 14155776);         // 14.2 MB
  u16*   attnout= (u16*)(scrA + 4718592 + 2*14155776);       // 4.7 MB
  u16*   partb  = (u16*)scrA;      // 4 x T*128 bf16 = 18.9 MB (FKAN split-K partials)
  float* xz     = (float*)scrA;    // T*128 f32 (mamba, disjoint from partial use)
  float* m_t    = t_t;
  const int n4 = (int)(T*128/4);

  // ---- all weight prep + zeroing in one kernel ----
  k_pack_all<<<9636,256,0,stream>>>(
      f1_bw0,f1_sw0,f1_sc0, f2_bw0,f2_sw0,f2_sc0,
      f1_bw1,f1_sw1,f1_sc1, f2_bw1,f2_sw1,f2_sc1,
      qkv_w, po_w, in_w, out_w, A_log,
      W1t_a, W1t_b, W2t_a, W2t_b,
      qkvw_bf, pow_bf, inw_bf, outw_bf, Aneg, ssS, 512+8192);

  // ---- attention ----
  k_ln1_trans<<<dim3(144,2),256,0,stream>>>(x5d, x_t, ln1_t, ln1_g, ln1_b);
  gemm64<0,true,64><<<dim3(3,288,1),256,0,stream>>>(ln1_t, qkvw_bf, qkv_tb,
      18432, 384, 128, 2, 0, 1, qkv_b, nullptr);
  k_dwconv<<<dim3(144,6,2),256,0,stream>>>(qkv_tb, qkvd, dw_w, dw_b, ss);
  k_qk<<<dim3(72,4,2),256,0,stream>>>(qkvd, ss, S);
  k_softmax<<<8,32,0,stream>>>(S, attnP, temp);
  k_av<<<dim3(36,4,2),256,0,stream>>>(qkvd, attnP, attnout);
  gemm64<0,false,32><<<dim3(1,576,1),256,0,stream>>>(attnout, pow_bf, t_t,
      18432, 128, 128, 2, 0, 0, po_b, x_t);              // t = x + attn(ln1(x))

  // ---- FKAN 1 ----
  k_ln_double_expand<<<4608,256,0,stream>>>(t_t, A1, ln2_g, ln2_b, f1_ng, f1_nb);
  gemm64<0,true,64><<<dim3(4,288,1),256,0,stream>>>(A1, W1t_a, hbuf,
      18432, 512, 1152, 18, 0, 1, nullptr, nullptr);
  gemm64<512,true,64><<<dim3(1,288,4),256,0,stream>>>(hbuf, W2t_a, partb,
      18432, 128, 4608, 18, 1, 0, nullptr, nullptr);     // bf16 split-K partials
  k_reduce4_ln<<<2304,256,0,stream>>>((const ushort4*)partb, (const float4*)t_t,
      (const float4*)x_t, (float4*)xtr, xm, ln3_g, ln3_b, n4);
      // x_tr = t + x + kan2 ; xm = LN3(x_tr) bf16

  // ---- Mamba ----
  gemm64<0,false,32><<<dim3(1,576,1),256,0,stream>>>(xm, inw_bf, xz,
      18432, 128, 128, 2, 0, 0, nullptr, nullptr);
  k_mamba_pre<<<4608,256,0,stream>>>(xz, xl, delta, Bm, Cm, A_out,
      cx_w, cz_w, xp_w, dt_w, dt_b);
  k_scan1<<<dim3(96,2),512,0,stream>>>(delta, Bm, xl, Aneg, cP, cS);
  k_scan2<<<2,512,0,stream>>>(cP, cS, cI);
  k_scan3<<<dim3(96,2),512,0,stream>>>(delta, Bm, Cm, xl, Aneg, Dp, cI, A_out);
  gemm64<0,false,32><<<dim3(1,576,1),256,0,stream>>>(A_out, outw_bf, m_t,
      18432, 128, 128, 2, 0, 0, nullptr, xtr);           // m = mamba + x_tr

  // ---- FKAN 2 ----
  k_ln_double_expand<<<4608,256,0,stream>>>(m_t, A1, ln4_g, ln4_b, f2_ng, f2_nb);
  gemm64<0,true,64><<<dim3(4,288,1),256,0,stream>>>(A1, W1t_b, hbuf,
      18432, 512, 1152, 18, 0, 1, nullptr, nullptr);
  gemm64<512,true,64><<<dim3(1,288,4),256,0,stream>>>(hbuf, W2t_b, partb,
      18432, 128, 4608, 18, 1, 0, nullptr, nullptr);     // bf16 split-K partials
  k_reduce4_trans<<<dim3(144,2),256,0,stream>>>((const ushort4*)partb,
      (const float4*)m_t, (const float4*)xtr, out, n4);  // out = T(m + x_tr + kan2)
}